// Round 1
// baseline (1779.483 us; speedup 1.0000x reference)
//
#include <hip/hip_runtime.h>
#include <math.h>

typedef unsigned int u32;
typedef unsigned short u16;

#define NN 256
#define CC 128
#define EPSV 1e-5f

__device__ __forceinline__ float b2f(u16 u){ return __uint_as_float(((u32)u)<<16); }
__device__ __forceinline__ u16 f2b(float f){
  u32 x = __float_as_uint(f);
  return (u16)((x + 0x7fffu + ((x>>16)&1u)) >> 16);
}
__device__ __forceinline__ void unpk(u32 u, float&a, float&b){
  a = __uint_as_float(u<<16); b = __uint_as_float(u & 0xffff0000u);
}
__device__ __forceinline__ u32 pk(float a, float b){
  return (u32)f2b(a) | (((u32)f2b(b))<<16);
}

#define UNPK8(U) float pf0,pf1,pf2,pf3,pf4,pf5,pf6,pf7; \
  unpk((U).x,pf0,pf1); unpk((U).y,pf2,pf3); unpk((U).z,pf4,pf5); unpk((U).w,pf6,pf7);

// dynamic LDS layout (bytes)
#define SX_OFF 0          // u16 sx[256][130]      66560  (x rows, later t rows)
#define WB_OFF 66560      // u16 wb[16384]         32768  (per-head Wqkv slice / WoT)
#define KV_OFF 99328      // u16 skv[2][256][32]   32768  (k and v, bf16)
#define SB_OFF 132096     // float sb[256][9]       9216  (bias tiles, padded)
#define SV_OFF 141312     // float sv[128]           512  (row-vector add term)
#define SM_OFF 141824     // float smn[256]         1024
#define SRS_OFF 142848    // float srs[256]         1024
#define SMEM_BYTES 143872

#define PRJB(IDX, ARR, B0) { uint4 u = wr[IDX]; UNPK8(u) \
  ARR[B0+0]+=xv*pf0; ARR[B0+1]+=xv*pf1; ARR[B0+2]+=xv*pf2; ARR[B0+3]+=xv*pf3; \
  ARR[B0+4]+=xv*pf4; ARR[B0+5]+=xv*pf5; ARR[B0+6]+=xv*pf6; ARR[B0+7]+=xv*pf7; }

#define DOTB(IDX, QB, ACC) { uint4 u = kr4[IDX]; UNPK8(u) \
  ACC += qr[QB+0]*pf0+qr[QB+1]*pf1+qr[QB+2]*pf2+qr[QB+3]*pf3+qr[QB+4]*pf4+qr[QB+5]*pf5+qr[QB+6]*pf6+qr[QB+7]*pf7; }

#define PVB(IDX, DB) { uint4 u = vr4[IDX]; UNPK8(u) \
  atth[DB+0]+=p*pf0; atth[DB+1]+=p*pf1; atth[DB+2]+=p*pf2; atth[DB+3]+=p*pf3; \
  atth[DB+4]+=p*pf4; atth[DB+5]+=p*pf5; atth[DB+6]+=p*pf6; atth[DB+7]+=p*pf7; }

#define OPB(IDX, AB, ACC) { uint4 u = wr[IDX]; UNPK8(u) \
  ACC += af[AB+0]*pf0+af[AB+1]*pf1+af[AB+2]*pf2+af[AB+3]*pf3+af[AB+4]*pf4+af[AB+5]*pf5+af[AB+6]*pf6+af[AB+7]*pf7; }

// One fused "pair stage": x = LN(pin + rowvec + colmat); att = rowAttn(x);
// out = LN(x + att @ Wo + bo).  PHASE 0: rowvec = s_out(computed), colmat = single.
// PHASE 1: rowvec = single[i], colmat = s_in, mask transposed.
template<int PHASE>
__launch_bounds__(256)
__global__ void stage_kernel(const float* pin, const float* colmat,
                             const float* singlerow,
                             const int* __restrict__ mask,
                             const float* __restrict__ dist,
                             const float* __restrict__ Wqkv,
                             const float* __restrict__ bqkv,
                             const float* __restrict__ Wo,
                             const float* __restrict__ bo,
                             const float* __restrict__ dscale,
                             const float* __restrict__ lng,
                             const float* __restrict__ lnb,
                             float* outp)
{
  extern __shared__ char smem[];
  u16*  sx  = (u16*)(smem + SX_OFF);
  u16*  wb  = (u16*)(smem + WB_OFF);
  u16*  skv = (u16*)(smem + KV_OFF);
  float* sb = (float*)(smem + SB_OFF);
  float* sv = (float*)(smem + SV_OFF);
  float* smn= (float*)(smem + SM_OFF);
  float* srs= (float*)(smem + SRS_OFF);

  const int i = blockIdx.x;
  const int tid = threadIdx.x;
  const int j = tid;                 // this thread owns attention row j
  const float dsc = dscale[0];
  const float* prow = pin + (size_t)i*NN*CC;
  float* orow = outp + (size_t)i*NN*CC;

  // ---- row-vector term sv[c] ----
  if (PHASE == 0) {
    int c = tid & 127, part = tid >> 7;
    float acc = 0.f;
    for (int k = part; k < i; k += 2) acc += prow[k*CC + c];
    smn[tid] = acc;
    __syncthreads();
    if (tid < CC) sv[tid] = smn[tid] + smn[tid+128];
  } else {
    if (tid < CC) sv[tid] = singlerow[i*CC + tid];
  }
  __syncthreads();

  // ---- x rows + LN1 -> sx (bf16), warp-per-row ----
  {
    int w = tid >> 6, lane = tid & 63;
    for (int r = w; r < NN; r += 4) {
      float t0 = prow[r*CC + lane]      + colmat[r*CC + lane]      + sv[lane];
      float t1 = prow[r*CC + lane + 64] + colmat[r*CC + lane + 64] + sv[lane+64];
      float s = t0 + t1, q2 = t0*t0 + t1*t1;
      #pragma unroll
      for (int mm = 32; mm; mm >>= 1) { s += __shfl_xor(s, mm); q2 += __shfl_xor(q2, mm); }
      float mean = s * (1.f/CC);
      float var  = fmaxf(q2 * (1.f/CC) - mean*mean, 0.f);
      float rstd = rsqrtf(var + EPSV);
      sx[r*130 + lane]      = f2b((t0-mean)*rstd*lng[lane]    + lnb[lane]);
      sx[r*130 + lane + 64] = f2b((t1-mean)*rstd*lng[lane+64] + lnb[lane+64]);
    }
  }
  __syncthreads();

  for (int h = 0; h < 4; ++h) {
    // stage Wqkv head slice -> wb [c][96] bf16  (q|k|v 32 cols each)
    for (int e = tid; e < 128*96; e += 256) {
      int c = e / 96;
      int t = e - c*96;
      int col = (t < 32) ? (h*32 + t) : (t < 64) ? (CC + h*32 + t - 32) : (2*CC + h*32 + t - 64);
      wb[e] = f2b(Wqkv[c*384 + col]);
    }
    __syncthreads();

    // per-thread projection of own row j
    float qr[32], kreg[32], vreg[32];
    #pragma unroll
    for (int d = 0; d < 32; ++d) {
      qr[d]   = bqkv[h*32 + d];
      kreg[d] = bqkv[CC + h*32 + d];
      vreg[d] = bqkv[2*CC + h*32 + d];
    }
    {
      const u32* xrow = (const u32*)(sx + j*130);
      for (int c2 = 0; c2 < 64; ++c2) {
        float x0, x1; unpk(xrow[c2], x0, x1);
        {
          const uint4* wr = (const uint4*)(wb + (2*c2)*96);
          float xv = x0;
          PRJB(0,qr,0) PRJB(1,qr,8) PRJB(2,qr,16) PRJB(3,qr,24)
          PRJB(4,kreg,0) PRJB(5,kreg,8) PRJB(6,kreg,16) PRJB(7,kreg,24)
          PRJB(8,vreg,0) PRJB(9,vreg,8) PRJB(10,vreg,16) PRJB(11,vreg,24)
        }
        {
          const uint4* wr = (const uint4*)(wb + (2*c2+1)*96);
          float xv = x1;
          PRJB(0,qr,0) PRJB(1,qr,8) PRJB(2,qr,16) PRJB(3,qr,24)
          PRJB(4,kreg,0) PRJB(5,kreg,8) PRJB(6,kreg,16) PRJB(7,kreg,24)
          PRJB(8,vreg,0) PRJB(9,vreg,8) PRJB(10,vreg,16) PRJB(11,vreg,24)
        }
      }
    }
    #pragma unroll
    for (int d = 0; d < 32; ++d) qr[d] *= 0.17677669529663687f;  // 1/sqrt(32), incl. bias

    {
      uint4* kd = (uint4*)(skv + j*32);
      uint4* vd = (uint4*)(skv + 8192 + j*32);
      #pragma unroll
      for (int p4 = 0; p4 < 4; ++p4) {
        kd[p4] = make_uint4(pk(kreg[8*p4],kreg[8*p4+1]), pk(kreg[8*p4+2],kreg[8*p4+3]),
                            pk(kreg[8*p4+4],kreg[8*p4+5]), pk(kreg[8*p4+6],kreg[8*p4+7]));
        vd[p4] = make_uint4(pk(vreg[8*p4],vreg[8*p4+1]), pk(vreg[8*p4+2],vreg[8*p4+3]),
                            pk(vreg[8*p4+4],vreg[8*p4+5]), pk(vreg[8*p4+6],vreg[8*p4+7]));
      }
    }
    __syncthreads();

    // online-softmax attention, thread = query row j
    float atth[32];
    #pragma unroll
    for (int d = 0; d < 32; ++d) atth[d] = 0.f;
    float mrun = -INFINITY, lrun = 0.f;

    for (int k0 = 0; k0 < NN; k0 += 8) {
      {
        const float4* dp = (const float4*)(dist + j*NN + k0);
        float4 d0 = dp[0], d1 = dp[1];
        float* brow = sb + j*9;
        if (PHASE == 0) {
          const int4* mp = (const int4*)(mask + j*NN + k0);
          int4 m0 = mp[0], m1 = mp[1];
          brow[0] = m0.x ? -1e30f : dsc*d0.x;
          brow[1] = m0.y ? -1e30f : dsc*d0.y;
          brow[2] = m0.z ? -1e30f : dsc*d0.z;
          brow[3] = m0.w ? -1e30f : dsc*d0.w;
          brow[4] = m1.x ? -1e30f : dsc*d1.x;
          brow[5] = m1.y ? -1e30f : dsc*d1.y;
          brow[6] = m1.z ? -1e30f : dsc*d1.z;
          brow[7] = m1.w ? -1e30f : dsc*d1.w;
        } else {
          int m0 = mask[(k0+0)*NN + j];
          int m1 = mask[(k0+1)*NN + j];
          int m2 = mask[(k0+2)*NN + j];
          int m3 = mask[(k0+3)*NN + j];
          int m4 = mask[(k0+4)*NN + j];
          int m5 = mask[(k0+5)*NN + j];
          int m6 = mask[(k0+6)*NN + j];
          int m7 = mask[(k0+7)*NN + j];
          brow[0] = m0 ? -1e30f : dsc*d0.x;
          brow[1] = m1 ? -1e30f : dsc*d0.y;
          brow[2] = m2 ? -1e30f : dsc*d0.z;
          brow[3] = m3 ? -1e30f : dsc*d0.w;
          brow[4] = m4 ? -1e30f : dsc*d1.x;
          brow[5] = m5 ? -1e30f : dsc*d1.y;
          brow[6] = m6 ? -1e30f : dsc*d1.z;
          brow[7] = m7 ? -1e30f : dsc*d1.w;
        }
      }
      __syncthreads();
      #pragma unroll
      for (int t8 = 0; t8 < 8; ++t8) {
        int k = k0 + t8;
        float s = sb[j*9 + t8];
        const uint4* kr4 = (const uint4*)(skv + k*32);
        float dot0=0.f, dot1=0.f, dot2=0.f, dot3=0.f;
        DOTB(0,0,dot0) DOTB(1,8,dot1) DOTB(2,16,dot2) DOTB(3,24,dot3)
        s += (dot0+dot1)+(dot2+dot3);
        float mn = fmaxf(mrun, s);
        if (mn > mrun) {
          float corr = __expf(mrun - mn);
          lrun *= corr;
          #pragma unroll
          for (int d = 0; d < 32; ++d) atth[d] *= corr;
          mrun = mn;
        }
        float p = __expf(s - mrun);
        lrun += p;
        const uint4* vr4 = (const uint4*)(skv + 8192 + k*32);
        PVB(0,0) PVB(1,8) PVB(2,16) PVB(3,24)
      }
      __syncthreads();
    }
    // park att head output (bf16) in our own output row (rewritten later)
    {
      float invl = 1.f / lrun;
      uint4* aw = (uint4*)((u32*)(orow + j*CC) + h*16);
      #pragma unroll
      for (int p4 = 0; p4 < 4; ++p4) {
        aw[p4] = make_uint4(pk(atth[8*p4+0]*invl, atth[8*p4+1]*invl),
                            pk(atth[8*p4+2]*invl, atth[8*p4+3]*invl),
                            pk(atth[8*p4+4]*invl, atth[8*p4+5]*invl),
                            pk(atth[8*p4+6]*invl, atth[8*p4+7]*invl));
      }
    }
  } // heads

  __syncthreads();
  // stage Wo transposed: wb[cp*128 + hd] = Wo[hd*128 + cp]  (coalesced global reads)
  for (int e = tid; e < 128*128; e += 256) {
    int hd = e >> 7, cp = e & 127;
    wb[cp*128 + hd] = f2b(Wo[e]);
  }
  __syncthreads();

  // out-proj + residual + LN2 stats (per-thread own row)
  {
    float af[128];
    const uint4* arow = (const uint4*)(orow + j*CC);
    #pragma unroll
    for (int p4 = 0; p4 < 16; ++p4) {
      uint4 u = arow[p4];
      unpk(u.x, af[8*p4+0], af[8*p4+1]);
      unpk(u.y, af[8*p4+2], af[8*p4+3]);
      unpk(u.z, af[8*p4+4], af[8*p4+5]);
      unpk(u.w, af[8*p4+6], af[8*p4+7]);
    }
    float ssum = 0.f, ssq = 0.f;
    for (int cp = 0; cp < 128; ++cp) {
      float oc0 = bo[cp], oc1 = 0.f, oc2 = 0.f, oc3 = 0.f;
      const uint4* wr = (const uint4*)(wb + cp*128);
      OPB(0,0,oc0) OPB(1,8,oc1) OPB(2,16,oc2) OPB(3,24,oc3)
      OPB(4,32,oc0) OPB(5,40,oc1) OPB(6,48,oc2) OPB(7,56,oc3)
      OPB(8,64,oc0) OPB(9,72,oc1) OPB(10,80,oc2) OPB(11,88,oc3)
      OPB(12,96,oc0) OPB(13,104,oc1) OPB(14,112,oc2) OPB(15,120,oc3)
      float oc = (oc0+oc1)+(oc2+oc3);
      float xv = b2f(sx[j*130 + cp]);
      float t = xv + oc;
      ssum += t; ssq += t*t;
      sx[j*130 + cp] = f2b(t);
    }
    float mean = ssum * (1.f/CC);
    float var  = fmaxf(ssq * (1.f/CC) - mean*mean, 0.f);
    smn[j] = mean;
    srs[j] = rsqrtf(var + EPSV);
  }
  __syncthreads();

  // coalesced final write
  for (int e = tid; e < NN*CC; e += 256) {
    int rr = e >> 7, cc2 = e & 127;
    float t = b2f(sx[rr*130 + cc2]);
    orow[e] = (t - smn[rr]) * srs[rr] * lng[cc2] + lnb[cc2];
  }
}

// s_in[j][c] = sum_{k<j} pr[k][j][c]
__global__ void colprefix_kernel(const float* __restrict__ pr, float* __restrict__ s_in) {
  int jcol = blockIdx.x;
  int c = threadIdx.x;  // 128
  float acc = 0.f;
  for (int k = 0; k < jcol; ++k) acc += pr[(size_t)k*NN*CC + jcol*CC + c];
  s_in[jcol*CC + c] = acc;
}

// single path: relu(relu(s@W1+b1)@W2+b2); LN(s + h)
__launch_bounds__(128)
__global__ void single_kernel(const float* __restrict__ single,
                              const float* __restrict__ W1, const float* __restrict__ b1,
                              const float* __restrict__ W2, const float* __restrict__ b2,
                              const float* __restrict__ g, const float* __restrict__ bb,
                              float* __restrict__ sr) {
  __shared__ float srow[128];
  __shared__ float sh1[256];
  __shared__ float red[4];
  int jr = blockIdx.x, t = threadIdx.x;
  srow[t] = single[jr*CC + t];
  __syncthreads();
  float a0 = b1[t], a1 = b1[t+128];
  for (int c = 0; c < 128; ++c) {
    float s = srow[c];
    a0 += s * W1[c*256 + t];
    a1 += s * W1[c*256 + t + 128];
  }
  sh1[t] = fmaxf(a0, 0.f);
  sh1[t+128] = fmaxf(a1, 0.f);
  __syncthreads();
  float acc = b2[t];
  for (int o = 0; o < 256; ++o) acc += sh1[o] * W2[o*CC + t];
  acc = fmaxf(acc, 0.f);
  float tv = srow[t] + acc;
  float s = tv, q = tv*tv;
  #pragma unroll
  for (int mm = 32; mm; mm >>= 1) { s += __shfl_xor(s, mm); q += __shfl_xor(q, mm); }
  int w = t >> 6;
  if ((t & 63) == 0) { red[w] = s; red[2+w] = q; }
  __syncthreads();
  float S = red[0] + red[1], Q = red[2] + red[3];
  float mean = S * (1.f/CC);
  float var = fmaxf(Q * (1.f/CC) - mean*mean, 0.f);
  float rs = rsqrtf(var + EPSV);
  sr[jr*CC + t] = (tv - mean) * rs * g[t] + bb[t];
}

extern "C" void kernel_launch(void* const* d_in, const int* in_sizes, int n_in,
                              void* d_out, int out_size, void* d_ws, size_t ws_size,
                              hipStream_t stream) {
  const float* pair   = (const float*)d_in[0];
  const float* single = (const float*)d_in[1];
  const int*   mask   = (const int*)d_in[2];
  const float* dist   = (const float*)d_in[3];
  const float* rWqkv  = (const float*)d_in[4];
  const float* rbqkv  = (const float*)d_in[5];
  const float* rWo    = (const float*)d_in[6];
  const float* rbo    = (const float*)d_in[7];
  const float* rdsc   = (const float*)d_in[8];
  const float* cWqkv  = (const float*)d_in[9];
  const float* cbqkv  = (const float*)d_in[10];
  const float* cWo    = (const float*)d_in[11];
  const float* cbo    = (const float*)d_in[12];
  const float* cdsc   = (const float*)d_in[13];
  const float* pnr_g  = (const float*)d_in[14];
  const float* pnr_b  = (const float*)d_in[15];
  const float* pnc_g  = (const float*)d_in[16];
  const float* pnc_b  = (const float*)d_in[17];
  const float* sn_g   = (const float*)d_in[18];
  const float* sn_b   = (const float*)d_in[19];
  const float* W1     = (const float*)d_in[20];
  const float* b1     = (const float*)d_in[21];
  const float* W2     = (const float*)d_in[22];
  const float* b2     = (const float*)d_in[23];

  float* outp = (float*)d_out;
  float* pr   = outp;                        // [256*256*128]
  float* srr  = outp + (size_t)NN*NN*CC;     // [256*128]: s_in staging, then final sr

  (void)hipFuncSetAttribute(reinterpret_cast<const void*>(stage_kernel<0>),
                            hipFuncAttributeMaxDynamicSharedMemorySize, SMEM_BYTES);
  (void)hipFuncSetAttribute(reinterpret_cast<const void*>(stage_kernel<1>),
                            hipFuncAttributeMaxDynamicSharedMemorySize, SMEM_BYTES);

  // rows stage: pr1 = LN(pr0 + rowAttn(pr0)), pr0 = LN(pair + single[j] + s_out[i])
  stage_kernel<0><<<256, 256, SMEM_BYTES, stream>>>(pair, single, nullptr, mask, dist,
      rWqkv, rbqkv, rWo, rbo, rdsc, pnr_g, pnr_b, pr);
  // column exclusive prefix of pr1 -> s_in (staged in the sr slice)
  colprefix_kernel<<<256, 128, 0, stream>>>(pr, srr);
  // cols stage: pr3 = LN(pr2 + rowAttn2(pr2)), pr2 = LN(pr1 + single[i] + s_in[j]), mask.T
  stage_kernel<1><<<256, 256, SMEM_BYTES, stream>>>(pr, srr, single, mask, dist,
      cWqkv, cbqkv, cWo, cbo, cdsc, pnc_g, pnc_b, pr);
  // single-rep MLP + LN (overwrites the s_in staging with the real sr output)
  single_kernel<<<256, 128, 0, stream>>>(single, W1, b1, W2, b2, sn_g, sn_b, srr);
}

// Round 2
// 394.804 us; speedup vs baseline: 4.5073x; 4.5073x over previous
//
#include <hip/hip_runtime.h>
#include <math.h>

typedef unsigned int u32;
typedef unsigned short u16;
typedef __attribute__((ext_vector_type(8))) short short8;   // 8 bf16 in 4 VGPRs
typedef __attribute__((ext_vector_type(4))) float f32x4;

#define NN 256
#define CC 128
#define EPSV 1e-5f
#define QSCALE 0.17677669529663687f   // 1/sqrt(32)
#define NEGBIG -1e30f

#define MFMA(a,b,c) __builtin_amdgcn_mfma_f32_16x16x32_bf16(a,b,c,0,0,0)

__device__ __forceinline__ float b2f(u16 u){ return __uint_as_float(((u32)u)<<16); }
__device__ __forceinline__ u16 f2b(float f){
  u32 x = __float_as_uint(f);
  return (u16)((x + 0x7fffu + ((x>>16)&1u)) >> 16);
}

// ---- LDS layout (bytes) ----
#define XS_OFF   0        // bf16 X[256][128], 16B-chunk XOR-swizzled   (65536)
#define WT_OFF   65536    // bf16 Wt[96][128] (W^T slice), swizzled     (24576)
#define WO_OFF   90112    // bf16 Woh[128][40]                          (10240)
#define KB_OFF   100352   // bf16 K[256][40]                            (20480)
#define VT_OFF   120832   // bf16 Vt[32][280]                           (17920)
#define PB_OFF   138752   // bf16 pb[8 waves][32][40]                   (20480)
#define SV_OFF   159232   // f32 sv[128]                                (512)
#define GB_OFF   159744   // f32 g[128], b[128], bo[128]                (1536)
#define RED_OFF  161280   // f32 red[512]                               (2048)
#define SMEM_BYTES 163328

// swizzled byte offset of scalar element (r,c) in X-style [*][128] bf16 buffer
#define XBYTE(r,c) ((r)*256 + (((((c)>>3)) ^ ((r)&7))<<4) + ((c)&7)*2)

// bias precompute: b0[j][k] for phase0, b1[j][k] = mask^T variant for phase1
__global__ void bias_kernel(const int* __restrict__ mask, const float* __restrict__ dist,
                            const float* __restrict__ rd, const float* __restrict__ cd,
                            u16* __restrict__ b0, u16* __restrict__ b1){
  int j = blockIdx.x, k = threadIdx.x;
  float dv = dist[j*NN + k];
  int m0 = mask[j*NN + k];
  int m1 = mask[k*NN + j];
  b0[j*NN + k] = m0 ? f2b(NEGBIG) : f2b(rd[0]*dv);
  b1[j*NN + k] = m1 ? f2b(NEGBIG) : f2b(cd[0]*dv);
}

// One fused pair stage. PHASE 0: rowvec = s_out(prefix of pin row i), colmat = single.
// PHASE 1: rowvec = single[i], colmat = s_in, mask transposed (via bias1 / direct).
template<int PHASE, int BIASWS>
__launch_bounds__(512, 2)
__global__ void stage_kernel(const float* __restrict__ pin, const float* __restrict__ colmat,
                             const float* __restrict__ singlerow,
                             const int* __restrict__ mask, const float* __restrict__ dist,
                             const u16* __restrict__ biasbuf,
                             const float* __restrict__ Wqkv, const float* __restrict__ bqkv,
                             const float* __restrict__ Wo, const float* __restrict__ bo,
                             const float* __restrict__ dscale,
                             const float* __restrict__ lng, const float* __restrict__ lnb,
                             float* __restrict__ outp)
{
  extern __shared__ char smem[];
  char* Xs  = smem + XS_OFF;
  char* WTs = smem + WT_OFF;
  char* WOs = smem + WO_OFF;
  char* KBs = smem + KB_OFF;
  char* VTs = smem + VT_OFF;
  float* SVs = (float*)(smem + SV_OFF);
  float* GBs = (float*)(smem + GB_OFF);
  float* REDs= (float*)(smem + RED_OFF);

  const int i = blockIdx.x;
  const int tid = threadIdx.x;
  const int lid = tid & 63;
  const int w = tid >> 6;            // wave 0..7
  const int l15 = lid & 15;
  const int l4  = lid >> 4;          // quadrant 0..3
  char* pbB = smem + PB_OFF + w*2560; // per-wave 32x40 bf16 bounce buffer
  const float dsc = dscale[0];
  const float* prow = pin + (size_t)i*NN*CC;
  float* orow = outp + (size_t)i*NN*CC;

  // ---- stage LN params + row-vector term sv[c] ----
  if (tid < CC){ GBs[tid] = lng[tid]; GBs[CC+tid] = lnb[tid]; GBs[2*CC+tid] = bo[tid]; }
  if (PHASE == 0) {
    int c = tid & 127, part = tid >> 7;
    float acc = 0.f;
    for (int k = part; k < i; k += 4) acc += prow[k*CC + c];
    REDs[tid] = acc;
    __syncthreads();
    if (tid < CC) SVs[tid] = REDs[tid] + REDs[CC+tid] + REDs[2*CC+tid] + REDs[3*CC+tid];
  } else {
    if (tid < CC) SVs[tid] = singlerow[i*CC + tid];
  }
  __syncthreads();

  // ---- x rows + LN1 -> X (bf16, swizzled), wave-per-row ----
  for (int r = w; r < NN; r += 8){
    float t0 = prow[r*CC + lid]      + colmat[r*CC + lid]      + SVs[lid];
    float t1 = prow[r*CC + 64 + lid] + colmat[r*CC + 64 + lid] + SVs[64 + lid];
    float s = t0 + t1, q2 = t0*t0 + t1*t1;
    #pragma unroll
    for (int mset = 1; mset < 64; mset <<= 1){ s += __shfl_xor(s, mset); q2 += __shfl_xor(q2, mset); }
    float mean = s*(1.f/CC);
    float var  = fmaxf(q2*(1.f/CC) - mean*mean, 0.f);
    float rstd = rsqrtf(var + EPSV);
    *(u16*)(Xs + XBYTE(r, lid))      = f2b((t0-mean)*rstd*GBs[lid]    + GBs[CC+lid]);
    *(u16*)(Xs + XBYTE(r, 64+lid))   = f2b((t1-mean)*rstd*GBs[64+lid] + GBs[CC+64+lid]);
  }

  // persistent out-projection accumulator: rows w*32..w*32+31, cols 0..127
  f32x4 pa[2][8];
  #pragma unroll
  for (int qt=0;qt<2;++qt)
    #pragma unroll
    for (int ct=0;ct<8;++ct) pa[qt][ct] = f32x4{0.f,0.f,0.f,0.f};

  for (int h = 0; h < 4; ++h){
    __syncthreads();   // prior-head LDS reads done; (iter 0: LN1 X writes done)

    // ---- stage Wt = W^T head slice [96][128] (rows: 0-31 Q,32-63 K,64-95 V), swizzled ----
    for (int e = tid; e < 96*128; e += 512){
      int c = e / 96, t = e - c*96;
      int col = (t < 32) ? (h*32 + t) : (t < 64) ? (CC + h*32 + (t-32)) : (2*CC + h*32 + (t-64));
      *(u16*)(WTs + t*256 + ((((c>>3) ^ (t&7)))<<4) + (c&7)*2) = f2b(Wqkv[c*384 + col]);
    }
    // ---- stage Woh[o][d] = Wo[h*32+d][o] ----
    for (int e = tid; e < 128*32; e += 512){
      int d = e >> 7, o = e & 127;
      *(u16*)(WOs + (o*40 + d)*2) = f2b(Wo[(h*32 + d)*128 + o]);
    }
    __syncthreads();

    // ---- QKV GEMM (+ V^T via swapped operands) ----
    f32x4 qa[2][2], kaa[2][2], va[2][2];
    {
      float bq0 = bqkv[h*32 + l15],      bq1 = bqkv[h*32 + 16 + l15];
      float bk0 = bqkv[CC + h*32 + l15], bk1 = bqkv[CC + h*32 + 16 + l15];
      qa[0][0] = f32x4{bq0,bq0,bq0,bq0}; qa[1][0] = qa[0][0];
      qa[0][1] = f32x4{bq1,bq1,bq1,bq1}; qa[1][1] = qa[0][1];
      kaa[0][0] = f32x4{bk0,bk0,bk0,bk0}; kaa[1][0] = kaa[0][0];
      kaa[0][1] = f32x4{bk1,bk1,bk1,bk1}; kaa[1][1] = kaa[0][1];
      #pragma unroll
      for (int dt=0;dt<2;++dt)
        #pragma unroll
        for (int v=0;v<4;++v){
          float bv = bqkv[2*CC + h*32 + dt*16 + l4*4 + v];
          va[dt][0][v] = bv; va[dt][1][v] = bv;
        }
    }
    #pragma unroll
    for (int ks = 0; ks < 4; ++ks){
      int swb = (((ks*4 + l4) ^ (l15 & 7)) << 4);
      short8 a0  = *(const short8*)(Xs  + (w*32 + l15)*256 + swb);
      short8 a1  = *(const short8*)(Xs  + (w*32 + 16 + l15)*256 + swb);
      short8 wq0 = *(const short8*)(WTs + (l15)*256 + swb);
      short8 wq1 = *(const short8*)(WTs + (16 + l15)*256 + swb);
      short8 wk0 = *(const short8*)(WTs + (32 + l15)*256 + swb);
      short8 wk1 = *(const short8*)(WTs + (48 + l15)*256 + swb);
      short8 wv0 = *(const short8*)(WTs + (64 + l15)*256 + swb);
      short8 wv1 = *(const short8*)(WTs + (80 + l15)*256 + swb);
      qa[0][0]=MFMA(a0,wq0,qa[0][0]); qa[0][1]=MFMA(a0,wq1,qa[0][1]);
      qa[1][0]=MFMA(a1,wq0,qa[1][0]); qa[1][1]=MFMA(a1,wq1,qa[1][1]);
      kaa[0][0]=MFMA(a0,wk0,kaa[0][0]); kaa[0][1]=MFMA(a0,wk1,kaa[0][1]);
      kaa[1][0]=MFMA(a1,wk0,kaa[1][0]); kaa[1][1]=MFMA(a1,wk1,kaa[1][1]);
      va[0][0]=MFMA(wv0,a0,va[0][0]); va[0][1]=MFMA(wv0,a1,va[0][1]);
      va[1][0]=MFMA(wv1,a0,va[1][0]); va[1][1]=MFMA(wv1,a1,va[1][1]);
    }
    // write K [256][40], Vt [32][280], Q->pb (scaled)
    #pragma unroll
    for (int qt=0;qt<2;++qt)
      #pragma unroll
      for (int ct=0;ct<2;++ct)
        #pragma unroll
        for (int v=0;v<4;++v){
          *(u16*)(KBs + ((w*32 + qt*16 + l4*4 + v)*40 + ct*16 + l15)*2) = f2b(kaa[qt][ct][v]);
          *(u16*)(pbB + ((qt*16 + l4*4 + v)*40 + ct*16 + l15)*2) = f2b(qa[qt][ct][v]*QSCALE);
          *(u16*)(VTs + ((ct*16 + l4*4 + v)*280 + w*32 + qt*16 + l15)*2) = f2b(va[ct][qt][v]);
        }
    asm volatile("s_waitcnt lgkmcnt(0)" ::: "memory");
    short8 qf0 = *(const short8*)(pbB + (l15)*80 + l4*16);
    short8 qf1 = *(const short8*)(pbB + (16 + l15)*80 + l4*16);
    __syncthreads();   // K, Vt visible to all waves

    // ---- flash attention over 8 chunks of 32 keys ----
    float mrow[2][4], lrow[2][4];
    f32x4 oacc[2][2];
    #pragma unroll
    for (int qt=0;qt<2;++qt){
      #pragma unroll
      for (int v=0;v<4;++v){ mrow[qt][v] = -3e38f; lrow[qt][v] = 0.f; }
      oacc[qt][0] = f32x4{0.f,0.f,0.f,0.f}; oacc[qt][1] = oacc[qt][0];
    }
    const int rowg = w*32 + l4*4;

    for (int ch = 0; ch < 8; ++ch){
      const int kbase = ch*32;
      // bias tile (16 values per lane)
      float bia[2][2][4];
      #pragma unroll
      for (int qt=0;qt<2;++qt)
        #pragma unroll
        for (int kt=0;kt<2;++kt)
          #pragma unroll
          for (int v=0;v<4;++v){
            int qg = rowg + qt*16 + v;
            int ky = kbase + kt*16 + l15;
            if (BIASWS){
              bia[qt][kt][v] = b2f(biasbuf[qg*NN + ky]);
            } else {
              int mq = (PHASE==0) ? mask[qg*NN + ky] : mask[ky*NN + qg];
              bia[qt][kt][v] = mq ? NEGBIG : dsc*dist[qg*NN + ky];
            }
          }
      short8 kf0 = *(const short8*)(KBs + (kbase + l15)*80 + l4*16);
      short8 kf1 = *(const short8*)(KBs + (kbase + 16 + l15)*80 + l4*16);
      f32x4 z4 = f32x4{0.f,0.f,0.f,0.f};
      f32x4 sa[2][2];
      sa[0][0] = MFMA(qf0, kf0, z4); sa[0][1] = MFMA(qf0, kf1, z4);
      sa[1][0] = MFMA(qf1, kf0, z4); sa[1][1] = MFMA(qf1, kf1, z4);

      float p[2][2][4];
      #pragma unroll
      for (int qt=0;qt<2;++qt){
        float rm[4];
        #pragma unroll
        for (int v=0;v<4;++v){
          float s0 = sa[qt][0][v] + bia[qt][0][v];
          float s1 = sa[qt][1][v] + bia[qt][1][v];
          p[qt][0][v] = s0; p[qt][1][v] = s1;
          rm[v] = fmaxf(s0, s1);
        }
        #pragma unroll
        for (int v=0;v<4;++v){
          #pragma unroll
          for (int mset=1; mset<16; mset<<=1) rm[v] = fmaxf(rm[v], __shfl_xor(rm[v], mset));
          float mn = fmaxf(mrow[qt][v], rm[v]);
          float corr = __expf(mrow[qt][v] - mn);
          mrow[qt][v] = mn;
          float p0 = __expf(p[qt][0][v] - mn);
          float p1 = __expf(p[qt][1][v] - mn);
          p[qt][0][v] = p0; p[qt][1][v] = p1;
          float rs = p0 + p1;
          #pragma unroll
          for (int mset=1; mset<16; mset<<=1) rs += __shfl_xor(rs, mset);
          lrow[qt][v] = lrow[qt][v]*corr + rs;
          oacc[qt][0][v] *= corr; oacc[qt][1][v] *= corr;
        }
      }
      // P bounce (wave-private)
      #pragma unroll
      for (int qt=0;qt<2;++qt)
        #pragma unroll
        for (int kt=0;kt<2;++kt)
          #pragma unroll
          for (int v=0;v<4;++v)
            *(u16*)(pbB + ((qt*16 + l4*4 + v)*40 + kt*16 + l15)*2) = f2b(p[qt][kt][v]);
      asm volatile("s_waitcnt lgkmcnt(0)" ::: "memory");
      short8 pA0 = *(const short8*)(pbB + (l15)*80 + l4*16);
      short8 pA1 = *(const short8*)(pbB + (16 + l15)*80 + l4*16);
      short8 vB0 = *(const short8*)(VTs + (l15)*560 + ch*64 + l4*16);
      short8 vB1 = *(const short8*)(VTs + (16 + l15)*560 + ch*64 + l4*16);
      oacc[0][0] = MFMA(pA0, vB0, oacc[0][0]);
      oacc[0][1] = MFMA(pA0, vB1, oacc[0][1]);
      oacc[1][0] = MFMA(pA1, vB0, oacc[1][0]);
      oacc[1][1] = MFMA(pA1, vB1, oacc[1][1]);
    }

    // ---- normalize O, bounce, fuse O_h @ Wo_h into pa ----
    #pragma unroll
    for (int qt=0;qt<2;++qt){
      float inv[4];
      #pragma unroll
      for (int v=0;v<4;++v) inv[v] = 1.f / lrow[qt][v];
      #pragma unroll
      for (int dt=0;dt<2;++dt)
        #pragma unroll
        for (int v=0;v<4;++v)
          *(u16*)(pbB + ((qt*16 + l4*4 + v)*40 + dt*16 + l15)*2) = f2b(oacc[qt][dt][v]*inv[v]);
    }
    asm volatile("s_waitcnt lgkmcnt(0)" ::: "memory");
    short8 oA0 = *(const short8*)(pbB + (l15)*80 + l4*16);
    short8 oA1 = *(const short8*)(pbB + (16 + l15)*80 + l4*16);
    #pragma unroll
    for (int ct=0; ct<8; ++ct){
      short8 wB = *(const short8*)(WOs + (ct*16 + l15)*80 + l4*16);
      pa[0][ct] = MFMA(oA0, wB, pa[0][ct]);
      pa[1][ct] = MFMA(oA1, wB, pa[1][ct]);
    }
  } // heads

  // ---- epilogue: residual + bo + LN2 + write ----
  float mrs[2][4], mrq[2][4];
  #pragma unroll
  for (int qt=0;qt<2;++qt)
    #pragma unroll
    for (int v=0;v<4;++v){ mrs[qt][v] = 0.f; mrq[qt][v] = 0.f; }
  #pragma unroll
  for (int qt=0;qt<2;++qt)
    #pragma unroll
    for (int ct=0;ct<8;++ct)
      #pragma unroll
      for (int v=0;v<4;++v){
        int o = ct*16 + l15;
        int r = w*32 + qt*16 + l4*4 + v;
        float xv = b2f(*(const u16*)(Xs + XBYTE(r, o)));
        float t = pa[qt][ct][v] + GBs[2*CC + o] + xv;
        pa[qt][ct][v] = t;
        mrs[qt][v] += t; mrq[qt][v] += t*t;
      }
  #pragma unroll
  for (int qt=0;qt<2;++qt)
    #pragma unroll
    for (int v=0;v<4;++v){
      #pragma unroll
      for (int mset=1; mset<16; mset<<=1){
        mrs[qt][v] += __shfl_xor(mrs[qt][v], mset);
        mrq[qt][v] += __shfl_xor(mrq[qt][v], mset);
      }
      float mean = mrs[qt][v]*(1.f/CC);
      float var  = fmaxf(mrq[qt][v]*(1.f/CC) - mean*mean, 0.f);
      mrs[qt][v] = mean;
      mrq[qt][v] = rsqrtf(var + EPSV);
    }
  #pragma unroll
  for (int qt=0;qt<2;++qt)
    #pragma unroll
    for (int ct=0;ct<8;++ct)
      #pragma unroll
      for (int v=0;v<4;++v){
        int o = ct*16 + l15;
        int r = w*32 + qt*16 + l4*4 + v;
        orow[r*CC + o] = (pa[qt][ct][v] - mrs[qt][v])*mrq[qt][v]*GBs[o] + GBs[CC+o];
      }
}

// s_in[j][c] = sum_{k<j} pr[k][j][c]
__global__ void colprefix_kernel(const float* __restrict__ pr, float* __restrict__ s_in){
  int jcol = blockIdx.x;
  int c = threadIdx.x;  // 128
  float acc = 0.f;
  for (int k = 0; k < jcol; ++k) acc += pr[(size_t)k*NN*CC + jcol*CC + c];
  s_in[jcol*CC + c] = acc;
}

// single path: relu(relu(s@W1+b1)@W2+b2); LN(s + h)
__launch_bounds__(128)
__global__ void single_kernel(const float* __restrict__ single,
                              const float* __restrict__ W1, const float* __restrict__ b1,
                              const float* __restrict__ W2, const float* __restrict__ b2,
                              const float* __restrict__ g, const float* __restrict__ bb,
                              float* __restrict__ sr){
  __shared__ float srow[128];
  __shared__ float sh1[256];
  __shared__ float red[4];
  int jr = blockIdx.x, t = threadIdx.x;
  srow[t] = single[jr*CC + t];
  __syncthreads();
  float a0 = b1[t], a1 = b1[t+128];
  for (int c = 0; c < 128; ++c){
    float s = srow[c];
    a0 += s * W1[c*256 + t];
    a1 += s * W1[c*256 + t + 128];
  }
  sh1[t] = fmaxf(a0, 0.f);
  sh1[t+128] = fmaxf(a1, 0.f);
  __syncthreads();
  float acc = b2[t];
  for (int o = 0; o < 256; ++o) acc += sh1[o] * W2[o*CC + t];
  acc = fmaxf(acc, 0.f);
  float tv = srow[t] + acc;
  float s = tv, q = tv*tv;
  #pragma unroll
  for (int mm = 32; mm; mm >>= 1){ s += __shfl_xor(s, mm); q += __shfl_xor(q, mm); }
  int w = t >> 6;
  if ((t & 63) == 0){ red[w] = s; red[2+w] = q; }
  __syncthreads();
  float S = red[0] + red[1], Q = red[2] + red[3];
  float mean = S*(1.f/CC);
  float var = fmaxf(Q*(1.f/CC) - mean*mean, 0.f);
  float rs = rsqrtf(var + EPSV);
  sr[jr*CC + t] = (tv - mean)*rs*g[t] + bb[t];
}

extern "C" void kernel_launch(void* const* d_in, const int* in_sizes, int n_in,
                              void* d_out, int out_size, void* d_ws, size_t ws_size,
                              hipStream_t stream) {
  const float* pair   = (const float*)d_in[0];
  const float* single = (const float*)d_in[1];
  const int*   mask   = (const int*)d_in[2];
  const float* dist   = (const float*)d_in[3];
  const float* rWqkv  = (const float*)d_in[4];
  const float* rbqkv  = (const float*)d_in[5];
  const float* rWo    = (const float*)d_in[6];
  const float* rbo    = (const float*)d_in[7];
  const float* rdsc   = (const float*)d_in[8];
  const float* cWqkv  = (const float*)d_in[9];
  const float* cbqkv  = (const float*)d_in[10];
  const float* cWo    = (const float*)d_in[11];
  const float* cbo    = (const float*)d_in[12];
  const float* cdsc   = (const float*)d_in[13];
  const float* pnr_g  = (const float*)d_in[14];
  const float* pnr_b  = (const float*)d_in[15];
  const float* pnc_g  = (const float*)d_in[16];
  const float* pnc_b  = (const float*)d_in[17];
  const float* sn_g   = (const float*)d_in[18];
  const float* sn_b   = (const float*)d_in[19];
  const float* W1     = (const float*)d_in[20];
  const float* b1     = (const float*)d_in[21];
  const float* W2     = (const float*)d_in[22];
  const float* b2     = (const float*)d_in[23];

  float* outp = (float*)d_out;
  float* pr   = outp;                        // [256*256*128]
  float* srr  = outp + (size_t)NN*NN*CC;     // [256*128]

  const size_t ws_need = (size_t)NN*NN*2*2 + (size_t)NN*CC*4;  // bias0+bias1 (bf16) + s_in (f32)
  const bool usews = ws_size >= ws_need;
  u16* bias0 = (u16*)d_ws;
  u16* bias1 = bias0 + NN*NN;
  float* s_in = usews ? (float*)((char*)d_ws + (size_t)NN*NN*4) : srr;

  if (usews){
    (void)hipFuncSetAttribute(reinterpret_cast<const void*>(stage_kernel<0,1>),
                              hipFuncAttributeMaxDynamicSharedMemorySize, SMEM_BYTES);
    (void)hipFuncSetAttribute(reinterpret_cast<const void*>(stage_kernel<1,1>),
                              hipFuncAttributeMaxDynamicSharedMemorySize, SMEM_BYTES);
    bias_kernel<<<NN, NN, 0, stream>>>(mask, dist, rdsc, cdsc, bias0, bias1);
    stage_kernel<0,1><<<NN, 512, SMEM_BYTES, stream>>>(pair, single, single, mask, dist, bias0,
        rWqkv, rbqkv, rWo, rbo, rdsc, pnr_g, pnr_b, pr);
    colprefix_kernel<<<NN, CC, 0, stream>>>(pr, s_in);
    stage_kernel<1,1><<<NN, 512, SMEM_BYTES, stream>>>(pr, s_in, single, mask, dist, bias1,
        cWqkv, cbqkv, cWo, cbo, cdsc, pnc_g, pnc_b, pr);
  } else {
    (void)hipFuncSetAttribute(reinterpret_cast<const void*>(stage_kernel<0,0>),
                              hipFuncAttributeMaxDynamicSharedMemorySize, SMEM_BYTES);
    (void)hipFuncSetAttribute(reinterpret_cast<const void*>(stage_kernel<1,0>),
                              hipFuncAttributeMaxDynamicSharedMemorySize, SMEM_BYTES);
    stage_kernel<0,0><<<NN, 512, SMEM_BYTES, stream>>>(pair, single, single, mask, dist, nullptr,
        rWqkv, rbqkv, rWo, rbo, rdsc, pnr_g, pnr_b, pr);
    colprefix_kernel<<<NN, CC, 0, stream>>>(pr, s_in);
    stage_kernel<1,0><<<NN, 512, SMEM_BYTES, stream>>>(pr, s_in, single, mask, dist, nullptr,
        cWqkv, cbqkv, cWo, cbo, cdsc, pnc_g, pnc_b, pr);
  }
  single_kernel<<<NN, CC, 0, stream>>>(single, W1, b1, W2, b2, sn_g, sn_b, srr);
}

// Round 3
// 293.371 us; speedup vs baseline: 6.0656x; 1.3458x over previous
//
#include <hip/hip_runtime.h>
#include <math.h>

typedef unsigned int u32;
typedef unsigned short u16;
typedef __attribute__((ext_vector_type(8))) short short8;   // 8 bf16 in 4 VGPRs
typedef __attribute__((ext_vector_type(4))) float f32x4;
typedef __attribute__((ext_vector_type(2))) u32 u32x2;

#define NN 256
#define CC 128
#define EPSV 1e-5f
#define LOG2E 1.44269504088896f
#define QSCL (0.17677669529663687f * 1.44269504088896f)   // 1/sqrt(32) * log2(e)
#define NEGBIG -1e30f

#define MFMA(a,b,c) __builtin_amdgcn_mfma_f32_16x16x32_bf16(a,b,c,0,0,0)
#define EXP2(x) __builtin_amdgcn_exp2f(x)

__device__ __forceinline__ float b2f(u16 u){ return __uint_as_float(((u32)u)<<16); }
__device__ __forceinline__ u16 f2b(float f){
  u32 x = __float_as_uint(f);
  return (u16)((x + 0x7fffu + ((x>>16)&1u)) >> 16);
}
__device__ __forceinline__ void unpk(u32 u, float&a, float&b){
  a = __uint_as_float(u<<16); b = __uint_as_float(u & 0xffff0000u);
}
__device__ __forceinline__ u32 cvtpk(float lo, float hi){
  u32 r;
  asm("v_cvt_pk_bf16_f32 %0, %1, %2" : "=v"(r) : "v"(lo), "v"(hi));
  return r;
}

// ---- LDS layout (bytes) ----
#define XS_OFF   0        // bf16 X[256][128], 16B-chunk XOR-swizzled   (65536)
#define WT_OFF   65536    // bf16 Wt[96][128] (W^T slice), swizzled     (24576)
#define WO_OFF   90112    // bf16 Woh[128][40]                          (10240)
#define KB_OFF   100352   // bf16 K[256][40]                            (20480)
#define VT_OFF   120832   // bf16 Vt[32][280]                           (17920)
#define PB_OFF   138752   // bf16 pb[16 waves][16][40]                  (20480)  (also f32 scratch pre-heads)
#define SV_OFF   159232   // f32 sv[128]                                (512)
#define GB_OFF   159744   // f32 g[128], b[128], bo[128]                (1536)
#define SMEM_BYTES 161280

// swizzled byte offset of scalar element (r,c) in X-style [*][128] bf16 buffer
#define XBYTE(r,c) ((r)*256 + (((((c)>>3)) ^ ((r)&7))<<4) + ((c)&7)*2)

// bias precompute (q-major, log2e-scaled): b0 for phase0, b1 uses mask^T
__global__ void bias_kernel(const int* __restrict__ mask, const float* __restrict__ dist,
                            const float* __restrict__ rd, const float* __restrict__ cd,
                            u16* __restrict__ b0, u16* __restrict__ b1){
  int j = blockIdx.x, k = threadIdx.x;
  float dv = dist[j*NN + k];
  b0[j*NN + k] = mask[j*NN + k] ? f2b(NEGBIG) : f2b(rd[0]*LOG2E*dv);
  b1[j*NN + k] = mask[k*NN + j] ? f2b(NEGBIG) : f2b(cd[0]*LOG2E*dv);
}

// One fused pair stage. PHASE 0: rowvec = s_out(prefix of pin row i), colmat = single.
// PHASE 1: rowvec = single[i], colmat = s_in, mask transposed.
template<int PHASE, int BIASWS>
__launch_bounds__(1024, 4)
__global__ void stage_kernel(const float* __restrict__ pin, const float* __restrict__ colmat,
                             const float* __restrict__ singlerow,
                             const int* __restrict__ mask, const float* __restrict__ dist,
                             const u16* __restrict__ biasbuf,
                             const float* __restrict__ Wqkv, const float* __restrict__ bqkv,
                             const float* __restrict__ Wo, const float* __restrict__ bo,
                             const float* __restrict__ dscale,
                             const float* __restrict__ lng, const float* __restrict__ lnb,
                             float* __restrict__ outp)
{
  extern __shared__ char smem[];
  char* Xs  = smem + XS_OFF;
  char* WTs = smem + WT_OFF;
  char* WOs = smem + WO_OFF;
  char* KBs = smem + KB_OFF;
  char* VTs = smem + VT_OFF;
  float* SVs = (float*)(smem + SV_OFF);
  float* GBs = (float*)(smem + GB_OFF);

  const int i = blockIdx.x;
  const int tid = threadIdx.x;
  const int lid = tid & 63;
  const int w = tid >> 6;            // wave 0..15; owns query rows w*16..w*16+15
  const int l15 = lid & 15;
  const int l4  = lid >> 4;          // quadrant 0..3
  char* pbB = smem + PB_OFF + w*1280; // per-wave 16x40 bf16 bounce buffer
  const float dsc = dscale[0] * LOG2E;
  const float* prow = pin + (size_t)i*NN*CC;
  float* orow = outp + (size_t)i*NN*CC;
  const int qglob = w*16 + l15;      // this lane's query row for softmax state

  // ---- LN params + row-vector term sv[c] ----
  if (tid < CC){ GBs[tid] = lng[tid]; GBs[CC+tid] = lnb[tid]; GBs[2*CC+tid] = bo[tid]; }
  if (PHASE == 0) {
    float* REDp = (float*)(smem + PB_OFF);   // scratch (pre-head phase)
    int c = tid & 127, part = tid >> 7;      // 8 partials
    float acc = 0.f;
    for (int k = part; k < i; k += 8) acc += prow[k*CC + c];
    REDp[tid] = acc;
    __syncthreads();
    if (tid < CC){
      float s = 0.f;
      #pragma unroll
      for (int p = 0; p < 8; ++p) s += REDp[p*CC + tid];
      SVs[tid] = s;
    }
  } else {
    if (tid < CC) SVs[tid] = singlerow[i*CC + tid];
  }
  __syncthreads();

  // ---- x rows + LN1 -> X (bf16, swizzled), wave-per-row ----
  for (int r = w; r < NN; r += 16){
    float t0 = prow[r*CC + lid]      + colmat[r*CC + lid]      + SVs[lid];
    float t1 = prow[r*CC + 64 + lid] + colmat[r*CC + 64 + lid] + SVs[64 + lid];
    float s = t0 + t1, q2 = t0*t0 + t1*t1;
    #pragma unroll
    for (int ms = 1; ms < 64; ms <<= 1){ s += __shfl_xor(s, ms); q2 += __shfl_xor(q2, ms); }
    float mean = s*(1.f/CC);
    float var  = fmaxf(q2*(1.f/CC) - mean*mean, 0.f);
    float rstd = rsqrtf(var + EPSV);
    *(u16*)(Xs + XBYTE(r, lid))    = f2b((t0-mean)*rstd*GBs[lid]    + GBs[CC+lid]);
    *(u16*)(Xs + XBYTE(r, 64+lid)) = f2b((t1-mean)*rstd*GBs[64+lid] + GBs[CC+64+lid]);
  }

  // persistent out-projection accumulator: wave's 16 rows x 128 cols
  f32x4 pa[8];
  #pragma unroll
  for (int ct=0;ct<8;++ct) pa[ct] = f32x4{0.f,0.f,0.f,0.f};

  for (int h = 0; h < 4; ++h){
    __syncthreads();   // prior-head K/V/Wo reads complete (iter 0: LN1 X writes done)

    // ---- stage Wt = W^T head slice [t=0..95][c], swizzled; c-fast (conflict-free writes) ----
    #pragma unroll
    for (int it = 0; it < 12; ++it){
      int e = tid + it*1024;              // e < 12288
      int c = e & 127, t = e >> 7;        // t < 96
      int col = (t < 32) ? (h*32 + t) : (t < 64) ? (CC + h*32 + (t-32)) : (2*CC + h*32 + (t-64));
      *(u16*)(WTs + t*256 + ((((c>>3) ^ (t&7)))<<4) + (c&7)*2) = f2b(Wqkv[c*384 + col]);
    }
    // ---- stage Woh[o][d] = Wo[h*32+d][o] ----
    #pragma unroll
    for (int it = 0; it < 4; ++it){
      int e = tid + it*1024;              // e < 4096
      int d = e >> 7, o = e & 127;
      *(u16*)(WOs + (o*40 + d)*2) = f2b(Wo[(h*32 + d)*128 + o]);
    }
    __syncthreads();

    // ---- QKV GEMM (16 rows/wave); V^T via swapped operands ----
    f32x4 qa[2], ka[2], va[2];
    {
      float bq0 = bqkv[h*32 + l15],      bq1 = bqkv[h*32 + 16 + l15];
      float bk0 = bqkv[CC + h*32 + l15], bk1 = bqkv[CC + h*32 + 16 + l15];
      qa[0] = f32x4{bq0,bq0,bq0,bq0}; qa[1] = f32x4{bq1,bq1,bq1,bq1};
      ka[0] = f32x4{bk0,bk0,bk0,bk0}; ka[1] = f32x4{bk1,bk1,bk1,bk1};
      #pragma unroll
      for (int dt=0;dt<2;++dt)
        #pragma unroll
        for (int v=0;v<4;++v) va[dt][v] = bqkv[2*CC + h*32 + dt*16 + l4*4 + v];
    }
    #pragma unroll
    for (int ks = 0; ks < 4; ++ks){
      int swb = (((ks*4 + l4) ^ (l15 & 7)) << 4);
      short8 a0  = *(const short8*)(Xs  + (w*16 + l15)*256 + swb);
      short8 wq0 = *(const short8*)(WTs + (l15)*256 + swb);
      short8 wq1 = *(const short8*)(WTs + (16 + l15)*256 + swb);
      short8 wk0 = *(const short8*)(WTs + (32 + l15)*256 + swb);
      short8 wk1 = *(const short8*)(WTs + (48 + l15)*256 + swb);
      short8 wv0 = *(const short8*)(WTs + (64 + l15)*256 + swb);
      short8 wv1 = *(const short8*)(WTs + (80 + l15)*256 + swb);
      qa[0]=MFMA(a0,wq0,qa[0]); qa[1]=MFMA(a0,wq1,qa[1]);
      ka[0]=MFMA(a0,wk0,ka[0]); ka[1]=MFMA(a0,wk1,ka[1]);
      va[0]=MFMA(wv0,a0,va[0]); va[1]=MFMA(wv1,a0,va[1]);
    }
    // write K [256][40], Vt [32][280], Q->pb (scaled into exp2 domain)
    #pragma unroll
    for (int ct=0;ct<2;++ct)
      #pragma unroll
      for (int v=0;v<4;++v){
        *(u16*)(KBs + ((w*16 + l4*4 + v)*40 + ct*16 + l15)*2) = f2b(ka[ct][v]);
        *(u16*)(pbB + ((l4*4 + v)*40 + ct*16 + l15)*2) = f2b(qa[ct][v]*QSCL);
        *(u16*)(VTs + ((ct*16 + l4*4 + v)*280 + w*16 + l15)*2) = f2b(va[ct][v]);
      }
    asm volatile("s_waitcnt lgkmcnt(0)" ::: "memory");
    short8 qf = *(const short8*)(pbB + (l15)*80 + l4*16);
    __syncthreads();   // K, Vt visible to all waves

    // ---- flash attention, swapped S^T = mfma(K,Q): lane owns query qglob ----
    float m = -3e38f, l = 0.f;
    f32x4 oacc[2];
    oacc[0] = f32x4{0.f,0.f,0.f,0.f}; oacc[1] = oacc[0];

    #pragma unroll
    for (int ch = 0; ch < 8; ++ch){
      const int kbase = ch*32;
      float bia[2][4];
      if (BIASWS){
        u32x2 bw0 = *(const u32x2*)(biasbuf + qglob*NN + kbase + l4*4);
        u32x2 bw1 = *(const u32x2*)(biasbuf + qglob*NN + kbase + 16 + l4*4);
        unpk(bw0.x, bia[0][0], bia[0][1]); unpk(bw0.y, bia[0][2], bia[0][3]);
        unpk(bw1.x, bia[1][0], bia[1][1]); unpk(bw1.y, bia[1][2], bia[1][3]);
      } else {
        #pragma unroll
        for (int kt=0;kt<2;++kt)
          #pragma unroll
          for (int v=0;v<4;++v){
            int ky = kbase + kt*16 + l4*4 + v;
            int mq = (PHASE==0) ? mask[qglob*NN + ky] : mask[ky*NN + qglob];
            bia[kt][v] = mq ? NEGBIG : dsc*dist[qglob*NN + ky];
          }
      }
      short8 kf0 = *(const short8*)(KBs + (kbase + l15)*80 + l4*16);
      short8 kf1 = *(const short8*)(KBs + (kbase + 16 + l15)*80 + l4*16);
      f32x4 z = f32x4{0.f,0.f,0.f,0.f};
      f32x4 s0 = MFMA(kf0, qf, z);   // S^T: col=q(l15), rows=keys l4*4+v
      f32x4 s1 = MFMA(kf1, qf, z);
      float sv0 = s0[0]+bia[0][0], sv1 = s0[1]+bia[0][1], sv2 = s0[2]+bia[0][2], sv3 = s0[3]+bia[0][3];
      float sv4 = s1[0]+bia[1][0], sv5 = s1[1]+bia[1][1], sv6 = s1[2]+bia[1][2], sv7 = s1[3]+bia[1][3];
      float mx = fmaxf(fmaxf(fmaxf(sv0,sv1),fmaxf(sv2,sv3)), fmaxf(fmaxf(sv4,sv5),fmaxf(sv6,sv7)));
      mx = fmaxf(mx, __shfl_xor(mx, 16));
      mx = fmaxf(mx, __shfl_xor(mx, 32));
      float mn = fmaxf(m, mx);
      float corr = EXP2(m - mn);
      m = mn;
      float p00 = EXP2(sv0 - m), p01 = EXP2(sv1 - m), p02 = EXP2(sv2 - m), p03 = EXP2(sv3 - m);
      float p10 = EXP2(sv4 - m), p11 = EXP2(sv5 - m), p12 = EXP2(sv6 - m), p13 = EXP2(sv7 - m);
      float ps = ((p00+p01)+(p02+p03)) + ((p10+p11)+(p12+p13));
      ps += __shfl_xor(ps, 16);
      ps += __shfl_xor(ps, 32);
      l = l*corr + ps;
      #pragma unroll
      for (int v=0;v<4;++v){ oacc[0][v] *= corr; oacc[1][v] *= corr; }
      // pack P^T and redistribute into PV B-fragment (keys l4*8..l4*8+7 for query l15)
      u32 A0 = cvtpk(p00,p01), A1 = cvtpk(p02,p03);
      u32 B0 = cvtpk(p10,p11), B1 = cvtpk(p12,p13);
      asm volatile("v_permlane32_swap_b32 %0, %1" : "+v"(A0), "+v"(B0));
      asm volatile("v_permlane32_swap_b32 %0, %1" : "+v"(A1), "+v"(B1));
      u32 sA0 = __shfl_xor(A0, 16), sA1 = __shfl_xor(A1, 16);
      u32 sB0 = __shfl_xor(B0, 16), sB1 = __shfl_xor(B1, 16);
      bool eg = ((l4 & 1) == 0);
      union { u32 u[4]; short8 s; } pu;
      pu.u[0] = eg ? A0 : sB0;
      pu.u[1] = eg ? A1 : sB1;
      pu.u[2] = eg ? sA0 : B0;
      pu.u[3] = eg ? sA1 : B1;
      short8 pf = pu.s;
      short8 vt0 = *(const short8*)(VTs + (l15)*560      + (kbase + l4*8)*2);
      short8 vt1 = *(const short8*)(VTs + (16 + l15)*560 + (kbase + l4*8)*2);
      oacc[0] = MFMA(vt0, pf, oacc[0]);   // O^T: col=q(l15), rows=d
      oacc[1] = MFMA(vt1, pf, oacc[1]);
    }

    // ---- normalize O^T, bounce to [q][d], fuse O_h @ Wo_h into pa ----
    {
      float inv = 1.f / l;
      #pragma unroll
      for (int dt=0;dt<2;++dt)
        #pragma unroll
        for (int v=0;v<4;++v)
          *(u16*)(pbB + (l15*40 + dt*16 + l4*4 + v)*2) = f2b(oacc[dt][v]*inv);
      asm volatile("s_waitcnt lgkmcnt(0)" ::: "memory");
      short8 oA = *(const short8*)(pbB + (l15)*80 + l4*16);
      #pragma unroll
      for (int ct=0; ct<8; ++ct){
        short8 wB = *(const short8*)(WOs + (ct*16 + l15)*80 + l4*16);
        pa[ct] = MFMA(oA, wB, pa[ct]);
      }
    }
  } // heads

  // ---- epilogue: residual + bo + LN2 + write ----
  float mrs[4], mrq[4];
  #pragma unroll
  for (int v=0;v<4;++v){ mrs[v] = 0.f; mrq[v] = 0.f; }
  #pragma unroll
  for (int ct=0;ct<8;++ct)
    #pragma unroll
    for (int v=0;v<4;++v){
      int o = ct*16 + l15;
      int r = w*16 + l4*4 + v;
      float xv = b2f(*(const u16*)(Xs + XBYTE(r, o)));
      float t = pa[ct][v] + GBs[2*CC + o] + xv;
      pa[ct][v] = t;
      mrs[v] += t; mrq[v] += t*t;
    }
  #pragma unroll
  for (int v=0;v<4;++v){
    #pragma unroll
    for (int ms=1; ms<16; ms<<=1){
      mrs[v] += __shfl_xor(mrs[v], ms);
      mrq[v] += __shfl_xor(mrq[v], ms);
    }
    float mean = mrs[v]*(1.f/CC);
    float var  = fmaxf(mrq[v]*(1.f/CC) - mean*mean, 0.f);
    mrs[v] = mean;
    mrq[v] = rsqrtf(var + EPSV);
  }
  #pragma unroll
  for (int ct=0;ct<8;++ct)
    #pragma unroll
    for (int v=0;v<4;++v){
      int o = ct*16 + l15;
      int r = w*16 + l4*4 + v;
      orow[r*CC + o] = (pa[ct][v] - mrs[v])*mrq[v]*GBs[o] + GBs[CC+o];
    }
}

// s_in[j][c] = sum_{k<j} pr[k][j][c]
__launch_bounds__(512)
__global__ void colprefix_kernel(const float* __restrict__ pr, float* __restrict__ s_in){
  __shared__ float red[512];
  int j = blockIdx.x;
  int c = threadIdx.x & 127, part = threadIdx.x >> 7;
  float acc = 0.f;
  for (int k = part; k < j; k += 4) acc += pr[(size_t)k*NN*CC + j*CC + c];
  red[threadIdx.x] = acc;
  __syncthreads();
  if (threadIdx.x < 128)
    s_in[j*CC + threadIdx.x] = red[threadIdx.x] + red[128+threadIdx.x]
                             + red[256+threadIdx.x] + red[384+threadIdx.x];
}

// single path: relu(relu(s@W1+b1)@W2+b2); LN(s + h)
__launch_bounds__(128)
__global__ void single_kernel(const float* __restrict__ single,
                              const float* __restrict__ W1, const float* __restrict__ b1,
                              const float* __restrict__ W2, const float* __restrict__ b2,
                              const float* __restrict__ g, const float* __restrict__ bb,
                              float* __restrict__ sr){
  __shared__ float srow[128];
  __shared__ float sh1[256];
  __shared__ float red[4];
  int jr = blockIdx.x, t = threadIdx.x;
  srow[t] = single[jr*CC + t];
  __syncthreads();
  float a0 = b1[t], a1 = b1[t+128];
  for (int c = 0; c < 128; ++c){
    float s = srow[c];
    a0 += s * W1[c*256 + t];
    a1 += s * W1[c*256 + t + 128];
  }
  sh1[t] = fmaxf(a0, 0.f);
  sh1[t+128] = fmaxf(a1, 0.f);
  __syncthreads();
  float acc = b2[t];
  for (int o = 0; o < 256; ++o) acc += sh1[o] * W2[o*CC + t];
  acc = fmaxf(acc, 0.f);
  float tv = srow[t] + acc;
  float s = tv, q = tv*tv;
  #pragma unroll
  for (int mm = 32; mm; mm >>= 1){ s += __shfl_xor(s, mm); q += __shfl_xor(q, mm); }
  int w = t >> 6;
  if ((t & 63) == 0){ red[w] = s; red[2+w] = q; }
  __syncthreads();
  float S = red[0] + red[1], Q = red[2] + red[3];
  float mean = S*(1.f/CC);
  float var = fmaxf(Q*(1.f/CC) - mean*mean, 0.f);
  float rs = rsqrtf(var + EPSV);
  sr[jr*CC + t] = (tv - mean)*rs*g[t] + bb[t];
}

extern "C" void kernel_launch(void* const* d_in, const int* in_sizes, int n_in,
                              void* d_out, int out_size, void* d_ws, size_t ws_size,
                              hipStream_t stream) {
  const float* pair   = (const float*)d_in[0];
  const float* single = (const float*)d_in[1];
  const int*   mask   = (const int*)d_in[2];
  const float* dist   = (const float*)d_in[3];
  const float* rWqkv  = (const float*)d_in[4];
  const float* rbqkv  = (const float*)d_in[5];
  const float* rWo    = (const float*)d_in[6];
  const float* rbo    = (const float*)d_in[7];
  const float* rdsc   = (const float*)d_in[8];
  const float* cWqkv  = (const float*)d_in[9];
  const float* cbqkv  = (const float*)d_in[10];
  const float* cWo    = (const float*)d_in[11];
  const float* cbo    = (const float*)d_in[12];
  const float* cdsc   = (const float*)d_in[13];
  const float* pnr_g  = (const float*)d_in[14];
  const float* pnr_b  = (const float*)d_in[15];
  const float* pnc_g  = (const float*)d_in[16];
  const float* pnc_b  = (const float*)d_in[17];
  const float* sn_g   = (const float*)d_in[18];
  const float* sn_b   = (const float*)d_in[19];
  const float* W1     = (const float*)d_in[20];
  const float* b1     = (const float*)d_in[21];
  const float* W2     = (const float*)d_in[22];
  const float* b2     = (const float*)d_in[23];

  float* outp = (float*)d_out;
  float* pr   = outp;                        // [256*256*128]
  float* srr  = outp + (size_t)NN*NN*CC;     // [256*128]

  const size_t ws_need = (size_t)NN*NN*2*2 + (size_t)NN*CC*4;  // bias0+bias1 (bf16) + s_in (f32)
  const bool usews = ws_size >= ws_need;
  u16* bias0 = (u16*)d_ws;
  u16* bias1 = bias0 + NN*NN;
  float* s_in = usews ? (float*)((char*)d_ws + (size_t)NN*NN*4) : srr;

  if (usews){
    (void)hipFuncSetAttribute(reinterpret_cast<const void*>(stage_kernel<0,1>),
                              hipFuncAttributeMaxDynamicSharedMemorySize, SMEM_BYTES);
    (void)hipFuncSetAttribute(reinterpret_cast<const void*>(stage_kernel<1,1>),
                              hipFuncAttributeMaxDynamicSharedMemorySize, SMEM_BYTES);
    bias_kernel<<<NN, NN, 0, stream>>>(mask, dist, rdsc, cdsc, bias0, bias1);
    stage_kernel<0,1><<<NN, 1024, SMEM_BYTES, stream>>>(pair, single, single, mask, dist, bias0,
        rWqkv, rbqkv, rWo, rbo, rdsc, pnr_g, pnr_b, pr);
    colprefix_kernel<<<NN, 512, 0, stream>>>(pr, s_in);
    stage_kernel<1,1><<<NN, 1024, SMEM_BYTES, stream>>>(pr, s_in, single, mask, dist, bias1,
        cWqkv, cbqkv, cWo, cbo, cdsc, pnc_g, pnc_b, pr);
  } else {
    (void)hipFuncSetAttribute(reinterpret_cast<const void*>(stage_kernel<0,0>),
                              hipFuncAttributeMaxDynamicSharedMemorySize, SMEM_BYTES);
    (void)hipFuncSetAttribute(reinterpret_cast<const void*>(stage_kernel<1,0>),
                              hipFuncAttributeMaxDynamicSharedMemorySize, SMEM_BYTES);
    stage_kernel<0,0><<<NN, 1024, SMEM_BYTES, stream>>>(pair, single, single, mask, dist, nullptr,
        rWqkv, rbqkv, rWo, rbo, rdsc, pnr_g, pnr_b, pr);
    colprefix_kernel<<<NN, 512, 0, stream>>>(pr, s_in);
    stage_kernel<1,0><<<NN, 1024, SMEM_BYTES, stream>>>(pr, s_in, single, mask, dist, nullptr,
        cWqkv, cbqkv, cWo, cbo, cdsc, pnc_g, pnc_b, pr);
  }
  single_kernel<<<NN, CC, 0, stream>>>(single, W1, b1, W2, b2, sn_g, sn_b, srr);
}

// Round 4
// 282.559 us; speedup vs baseline: 6.2977x; 1.0383x over previous
//
#include <hip/hip_runtime.h>
#include <math.h>

typedef unsigned int u32;
typedef unsigned short u16;
typedef __attribute__((ext_vector_type(8))) short short8;   // 8 bf16 in 4 VGPRs
typedef __attribute__((ext_vector_type(4))) float f32x4;
typedef __attribute__((ext_vector_type(2))) u32 u32x2;

#define NN 256
#define CC 128
#define EPSV 1e-5f
#define LOG2E 1.44269504088896f
#define QSCL (0.17677669529663687f * 1.44269504088896f)   // 1/sqrt(32) * log2(e)
#define NEGBIG -1e30f

#define MFMA(a,b,c) __builtin_amdgcn_mfma_f32_16x16x32_bf16(a,b,c,0,0,0)
#define EXP2(x) __builtin_amdgcn_exp2f(x)

__device__ __forceinline__ float b2f(u16 u){ return __uint_as_float(((u32)u)<<16); }
__device__ __forceinline__ u16 f2b(float f){
  u32 x = __float_as_uint(f);
  return (u16)((x + 0x7fffu + ((x>>16)&1u)) >> 16);
}
__device__ __forceinline__ void unpk(u32 u, float&a, float&b){
  a = __uint_as_float(u<<16); b = __uint_as_float(u & 0xffff0000u);
}
__device__ __forceinline__ u32 cvtpk(float lo, float hi){
  u32 r;
  asm("v_cvt_pk_bf16_f32 %0, %1, %2" : "=v"(r) : "v"(lo), "v"(hi));
  return r;
}
__device__ __forceinline__ void gload16(const void* g, void* l){
  __builtin_amdgcn_global_load_lds((const __attribute__((address_space(1))) u32*)g,
                                   (__attribute__((address_space(3))) u32*)l, 16, 0, 0);
}

// redistribute 8 values (2 f32x4 tiles, idx = tile*16 + l4*4 + v at col l15) into
// A/B-frag short8 (lane l4 gets idx l4*8..l4*8+7 for its l15). Verified P-path algebra.
__device__ __forceinline__ short8 redist(f32x4 t0, f32x4 t1, int l4){
  u32 A0 = cvtpk(t0[0], t0[1]), A1 = cvtpk(t0[2], t0[3]);
  u32 B0 = cvtpk(t1[0], t1[1]), B1 = cvtpk(t1[2], t1[3]);
  asm volatile("v_permlane32_swap_b32 %0, %1" : "+v"(A0), "+v"(B0));
  asm volatile("v_permlane32_swap_b32 %0, %1" : "+v"(A1), "+v"(B1));
  u32 sA0 = __shfl_xor(A0, 16), sA1 = __shfl_xor(A1, 16);
  u32 sB0 = __shfl_xor(B0, 16), sB1 = __shfl_xor(B1, 16);
  bool eg = ((l4 & 1) == 0);
  union { u32 u[4]; short8 s; } pu;
  pu.u[0] = eg ? A0 : sB0;
  pu.u[1] = eg ? A1 : sB1;
  pu.u[2] = eg ? sA0 : B0;
  pu.u[3] = eg ? sA1 : B1;
  return pu.s;
}

// ---- LDS layout (bytes) ----
#define XS_OFF   0        // bf16 X[256][128] swizzled                  (65536)
#define WT_OFF   65536    // bf16 Wt[96][128] head slice, swizzled      (24576)
#define WO_OFF   90112    // bf16 Woh dbuf [2][128][40]                 (20480)
#define KB_OFF   110592   // bf16 K[256][40]                            (20480)
#define VT_OFF   131072   // bf16 Vt[32][264]                           (16896)
#define SV_OFF   147968   // f32 sv[128]                                (512)
#define GB_OFF   148480   // f32 g[128], b[128], bo[128]                (1536)
#define BQ_OFF   150016   // f32 bqkv[384]                              (1536)
#define RS_OFF   151552   // f32 red[16][128] (phase-0 scratch)         (8192)
#define SMEM_BYTES 159744

#define XBYTE(r,c) ((r)*256 + (((((c)>>3)) ^ ((r)&7))<<4) + ((c)&7)*2)

// ws layout (bytes)
#define WS_B0   0          // bias img phase0 (131072)
#define WS_B1   131072     // bias img phase1 (131072)
#define WS_W0   262144     // W img stage0 (139264 = 4 heads x (24576 WT + 10240 WO))
#define WS_W1   401408     // W img stage1 (139264)
#define WS_SIN  540672     // s_in f32 (131072)
#define WS_NEED 671744

// bias image, per-lane-consumed layout: u16 addr = q*256 + l4*64 + ch*8 + kt*4 + v
__global__ void prep_bias(const int* __restrict__ mask, const float* __restrict__ dist,
                          const float* __restrict__ rd, const float* __restrict__ cd,
                          u16* __restrict__ b0, u16* __restrict__ b1){
  int q = blockIdx.x, k = threadIdx.x;
  int l4 = (k >> 2) & 3, v = k & 3, kt = (k >> 4) & 1, ch = k >> 5;
  int addr = q*256 + l4*64 + ch*8 + kt*4 + v;
  float dv = dist[q*NN + k];
  b0[addr] = mask[q*NN + k] ? f2b(NEGBIG) : f2b(rd[0]*LOG2E*dv);
  b1[addr] = mask[k*NN + q] ? f2b(NEGBIG) : f2b(cd[0]*LOG2E*dv);
}

// weight images: byte-exact copies of the LDS layouts (WT swizzled, WO padded)
__global__ void prep_wimg(const float* __restrict__ rWqkv, const float* __restrict__ rWo,
                          const float* __restrict__ cWqkv, const float* __restrict__ cWo,
                          u16* __restrict__ img0, u16* __restrict__ img1){
  int h = blockIdx.x & 3, s = blockIdx.x >> 2;
  const float* Wq = s ? cWqkv : rWqkv;
  const float* Wom = s ? cWo : rWo;
  char* base = (char*)(s ? img1 : img0) + h*34816;
  for (int e = threadIdx.x; e < 96*128; e += 256){
    int t = e >> 7, c = e & 127;
    int col = (t < 32) ? (h*32 + t) : (t < 64) ? (CC + h*32 + (t-32)) : (2*CC + h*32 + (t-64));
    *(u16*)(base + t*256 + ((((c>>3) ^ (t&7)))<<4) + (c&7)*2) = f2b(Wq[c*384 + col]);
  }
  for (int e = threadIdx.x; e < 128*40; e += 256){
    int o = e / 40, d = e - o*40;
    *(u16*)(base + 24576 + (o*40 + d)*2) = (d < 32) ? f2b(Wom[(h*32 + d)*128 + o]) : (u16)0;
  }
}

template<int PHASE, int WSOK>
__launch_bounds__(1024, 4)
__global__ void stage_kernel(const float* __restrict__ pin, const float* __restrict__ colmat,
                             const float* __restrict__ singlerow,
                             const int* __restrict__ mask, const float* __restrict__ dist,
                             const u16* __restrict__ biasimg,
                             const u16* __restrict__ wimg,
                             const float* __restrict__ Wqkv, const float* __restrict__ bqkv,
                             const float* __restrict__ Wo, const float* __restrict__ bo,
                             const float* __restrict__ dscale,
                             const float* __restrict__ lng, const float* __restrict__ lnb,
                             float* __restrict__ outp)
{
  extern __shared__ char smem[];
  char* Xs  = smem + XS_OFF;
  char* WTs = smem + WT_OFF;
  char* WOs = smem + WO_OFF;
  char* KBs = smem + KB_OFF;
  char* VTs = smem + VT_OFF;
  float* SVs = (float*)(smem + SV_OFF);
  float* GBs = (float*)(smem + GB_OFF);
  float* BQs = (float*)(smem + BQ_OFF);
  float* RSs = (float*)(smem + RS_OFF);

  const int i = blockIdx.x;
  const int tid = threadIdx.x;
  const int lid = tid & 63;
  const int w = tid >> 6;            // 16 waves; wave owns query rows w*16..w*16+15
  const int l15 = lid & 15;
  const int l4  = lid >> 4;
  const int h32 = lid >> 5;
  const int c4  = (lid & 31) * 4;
  const float* prow = pin + (size_t)i*NN*CC;
  float* orow = outp + (size_t)i*NN*CC;
  const int qglob = w*16 + l15;
  const float dsc = dscale[0] * LOG2E;

  // issue W(head 0) staging immediately (lands during LN phase)
  if (WSOK){
    const char* wb = (const char*)wimg;
    gload16(wb + tid*16, WTs + tid*16);
    if (tid < 512) gload16(wb + 16384 + tid*16, WTs + 16384 + tid*16);
    if (tid < 640) gload16(wb + 24576 + tid*16, WOs + tid*16);
  }
  if (tid < 128){ GBs[tid] = lng[tid]; GBs[128+tid] = lnb[tid]; GBs[256+tid] = bo[tid]; }
  if (tid >= 512 && tid < 896) BQs[tid-512] = bqkv[tid-512];

  // ---- LN1 -> X (bf16 swizzled); phase 0 fuses the s_out prefix ----
  if (PHASE == 0){
    f32x4 svp = {0.f,0.f,0.f,0.f};
    #pragma unroll 4
    for (int p = 0; p < 8; ++p){
      int r = w*16 + p*2 + h32;
      f32x4 pr4 = __builtin_nontemporal_load((const f32x4*)(prow + r*CC + c4));
      f32x4 sg4 = *(const f32x4*)(colmat + r*CC + c4);
      f32x4 t = pr4 + sg4;
      u32x2 pk2; pk2.x = cvtpk(t[0], t[1]); pk2.y = cvtpk(t[2], t[3]);
      *(u32x2*)(Xs + XBYTE(r, c4)) = pk2;
      if (r < i) svp += pr4;
    }
    #pragma unroll
    for (int q = 0; q < 4; ++q) svp[q] += __shfl_xor(svp[q], 32);
    if (h32 == 0) *(f32x4*)(RSs + w*128 + c4) = svp;
    __syncthreads();
    if (tid < 128){
      float s = 0.f;
      #pragma unroll
      for (int ww = 0; ww < 16; ++ww) s += RSs[ww*128 + tid];
      SVs[tid] = s;
    }
    __syncthreads();
    f32x4 sv4 = *(const f32x4*)(SVs + c4);
    f32x4 g4  = *(const f32x4*)(GBs + c4);
    f32x4 b4  = *(const f32x4*)(GBs + 128 + c4);
    #pragma unroll 2
    for (int p = 0; p < 8; ++p){
      int r = w*16 + p*2 + h32;
      u32x2 st = *(const u32x2*)(Xs + XBYTE(r, c4));
      float t0,t1,t2,t3;
      unpk(st.x, t0, t1); unpk(st.y, t2, t3);
      t0 += sv4[0]; t1 += sv4[1]; t2 += sv4[2]; t3 += sv4[3];
      float s = (t0+t1)+(t2+t3);
      float q2 = (t0*t0+t1*t1)+(t2*t2+t3*t3);
      #pragma unroll
      for (int ms = 1; ms < 32; ms <<= 1){ s += __shfl_xor(s, ms); q2 += __shfl_xor(q2, ms); }
      float mean = s*(1.f/CC);
      float var  = fmaxf(q2*(1.f/CC) - mean*mean, 0.f);
      float rstd = rsqrtf(var + EPSV);
      float y0 = (t0-mean)*rstd*g4[0] + b4[0];
      float y1 = (t1-mean)*rstd*g4[1] + b4[1];
      float y2 = (t2-mean)*rstd*g4[2] + b4[2];
      float y3 = (t3-mean)*rstd*g4[3] + b4[3];
      u32x2 pk2; pk2.x = cvtpk(y0, y1); pk2.y = cvtpk(y2, y3);
      *(u32x2*)(Xs + XBYTE(r, c4)) = pk2;
    }
  } else {
    if (tid < 128) SVs[tid] = singlerow[i*CC + tid];
    __syncthreads();
    f32x4 sv4 = *(const f32x4*)(SVs + c4);
    f32x4 g4  = *(const f32x4*)(GBs + c4);
    f32x4 b4  = *(const f32x4*)(GBs + 128 + c4);
    #pragma unroll 4
    for (int p = 0; p < 8; ++p){
      int r = w*16 + p*2 + h32;
      f32x4 pr4 = __builtin_nontemporal_load((const f32x4*)(prow + r*CC + c4));
      f32x4 cm4 = *(const f32x4*)(colmat + r*CC + c4);
      float t0 = pr4[0]+cm4[0]+sv4[0], t1 = pr4[1]+cm4[1]+sv4[1];
      float t2 = pr4[2]+cm4[2]+sv4[2], t3 = pr4[3]+cm4[3]+sv4[3];
      float s = (t0+t1)+(t2+t3);
      float q2 = (t0*t0+t1*t1)+(t2*t2+t3*t3);
      #pragma unroll
      for (int ms = 1; ms < 32; ms <<= 1){ s += __shfl_xor(s, ms); q2 += __shfl_xor(q2, ms); }
      float mean = s*(1.f/CC);
      float var  = fmaxf(q2*(1.f/CC) - mean*mean, 0.f);
      float rstd = rsqrtf(var + EPSV);
      float y0 = (t0-mean)*rstd*g4[0] + b4[0];
      float y1 = (t1-mean)*rstd*g4[1] + b4[1];
      float y2 = (t2-mean)*rstd*g4[2] + b4[2];
      float y3 = (t3-mean)*rstd*g4[3] + b4[3];
      u32x2 pk2; pk2.x = cvtpk(y0, y1); pk2.y = cvtpk(y2, y3);
      *(u32x2*)(Xs + XBYTE(r, c4)) = pk2;
    }
  }
  if (WSOK) asm volatile("s_waitcnt vmcnt(0)" ::: "memory");
  __syncthreads();   // X ready; W(0) staged

  f32x4 pa[8];
  #pragma unroll
  for (int ct = 0; ct < 8; ++ct) pa[ct] = f32x4{0.f,0.f,0.f,0.f};

  for (int h = 0; h < 4; ++h){
    if (!WSOK){
      #pragma unroll
      for (int it = 0; it < 12; ++it){
        int e = tid + it*1024;
        int c = e & 127, t = e >> 7;
        int col = (t < 32) ? (h*32 + t) : (t < 64) ? (CC + h*32 + (t-32)) : (2*CC + h*32 + (t-64));
        *(u16*)(WTs + t*256 + ((((c>>3) ^ (t&7)))<<4) + (c&7)*2) = f2b(Wqkv[c*384 + col]);
      }
      #pragma unroll
      for (int it = 0; it < 4; ++it){
        int e = tid + it*1024;
        int d = e >> 7, o = e & 127;
        *(u16*)(WOs + (h&1)*10240 + (o*40 + d)*2) = (d < 32) ? f2b(Wo[(h*32 + d)*128 + o]) : (u16)0;
      }
      __syncthreads();
    }

    // ---- QKV GEMM: Q^T and V^T via W-as-A; K direct ----
    f32x4 qa[2], ka[2], va[2];
    #pragma unroll
    for (int dt = 0; dt < 2; ++dt)
      #pragma unroll
      for (int v = 0; v < 4; ++v){
        qa[dt][v] = BQs[h*32 + dt*16 + l4*4 + v];
        va[dt][v] = BQs[256 + h*32 + dt*16 + l4*4 + v];
      }
    {
      float bk0 = BQs[128 + h*32 + l15], bk1 = BQs[128 + h*32 + 16 + l15];
      ka[0] = f32x4{bk0,bk0,bk0,bk0}; ka[1] = f32x4{bk1,bk1,bk1,bk1};
    }
    #pragma unroll
    for (int ks = 0; ks < 4; ++ks){
      int swb = (((ks*4 + l4) ^ (l15 & 7)) << 4);
      short8 a0  = *(const short8*)(Xs  + (w*16 + l15)*256 + swb);
      short8 wq0 = *(const short8*)(WTs + (l15)*256 + swb);
      short8 wq1 = *(const short8*)(WTs + (16 + l15)*256 + swb);
      short8 wk0 = *(const short8*)(WTs + (32 + l15)*256 + swb);
      short8 wk1 = *(const short8*)(WTs + (48 + l15)*256 + swb);
      short8 wv0 = *(const short8*)(WTs + (64 + l15)*256 + swb);
      short8 wv1 = *(const short8*)(WTs + (80 + l15)*256 + swb);
      qa[0] = MFMA(wq0, a0, qa[0]); qa[1] = MFMA(wq1, a0, qa[1]);
      ka[0] = MFMA(a0, wk0, ka[0]); ka[1] = MFMA(a0, wk1, ka[1]);
      va[0] = MFMA(wv0, a0, va[0]); va[1] = MFMA(wv1, a0, va[1]);
    }
    short8 qf = redist(qa[0]*QSCL, qa[1]*QSCL, l4);
    #pragma unroll
    for (int kt = 0; kt < 2; ++kt)
      #pragma unroll
      for (int v = 0; v < 4; ++v)
        *(u16*)(KBs + ((w*16 + l4*4 + v)*40 + kt*16 + l15)*2) = (u16)cvtpk(ka[kt][v], ka[kt][v]);
    #pragma unroll
    for (int dt = 0; dt < 2; ++dt)
      #pragma unroll
      for (int v = 0; v < 4; ++v)
        *(u16*)(VTs + ((dt*16 + l4*4 + v)*264 + w*16 + l15)*2) = (u16)cvtpk(va[dt][v], va[dt][v]);
    __syncthreads();   // K/VT visible; all WT reads done

    if (WSOK && h < 3){  // prefetch next head's weights under the flash phase
      const char* wb = (const char*)wimg + (h+1)*34816;
      gload16(wb + tid*16, WTs + tid*16);
      if (tid < 512) gload16(wb + 16384 + tid*16, WTs + 16384 + tid*16);
      if (tid < 640) gload16(wb + 24576 + tid*16, WOs + ((h+1)&1)*10240 + tid*16);
    }

    // ---- attention: full-row softmax in 2 halves of 128 keys ----
    float m = -3e38f, l = 0.f;
    f32x4 oacc0 = {0.f,0.f,0.f,0.f}, oacc1 = {0.f,0.f,0.f,0.f};
    #pragma unroll
    for (int hl = 0; hl < 2; ++hl){
      f32x4 sS[4][2];
      #pragma unroll
      for (int ci = 0; ci < 4; ++ci){
        int ch = hl*4 + ci;
        short8 kf0 = *(const short8*)(KBs + (ch*32 + l15)*80 + l4*16);
        short8 kf1 = *(const short8*)(KBs + (ch*32 + 16 + l15)*80 + l4*16);
        f32x4 z = {0.f,0.f,0.f,0.f};
        sS[ci][0] = MFMA(kf0, qf, z);
        sS[ci][1] = MFMA(kf1, qf, z);
      }
      if (WSOK){
        const u16* bb = biasimg + qglob*256 + l4*64 + hl*32;
        #pragma unroll
        for (int ci = 0; ci < 4; ++ci){
          uint4 bw = *(const uint4*)(bb + ci*8);
          float b00,b01,b02,b03,b10,b11,b12,b13;
          unpk(bw.x, b00, b01); unpk(bw.y, b02, b03);
          unpk(bw.z, b10, b11); unpk(bw.w, b12, b13);
          sS[ci][0][0]+=b00; sS[ci][0][1]+=b01; sS[ci][0][2]+=b02; sS[ci][0][3]+=b03;
          sS[ci][1][0]+=b10; sS[ci][1][1]+=b11; sS[ci][1][2]+=b12; sS[ci][1][3]+=b13;
        }
      } else {
        #pragma unroll
        for (int ci = 0; ci < 4; ++ci)
          #pragma unroll
          for (int kt = 0; kt < 2; ++kt)
            #pragma unroll
            for (int v = 0; v < 4; ++v){
              int key = (hl*4 + ci)*32 + kt*16 + l4*4 + v;
              int mq = (PHASE==0) ? mask[qglob*NN + key] : mask[key*NN + qglob];
              sS[ci][kt][v] += mq ? NEGBIG : dsc*dist[qglob*NN + key];
            }
      }
      float mc0 = fmaxf(fmaxf(fmaxf(sS[0][0][0],sS[0][0][1]),fmaxf(sS[0][0][2],sS[0][0][3])),
                        fmaxf(fmaxf(sS[0][1][0],sS[0][1][1]),fmaxf(sS[0][1][2],sS[0][1][3])));
      float mc1 = fmaxf(fmaxf(fmaxf(sS[1][0][0],sS[1][0][1]),fmaxf(sS[1][0][2],sS[1][0][3])),
                        fmaxf(fmaxf(sS[1][1][0],sS[1][1][1]),fmaxf(sS[1][1][2],sS[1][1][3])));
      float mc2 = fmaxf(fmaxf(fmaxf(sS[2][0][0],sS[2][0][1]),fmaxf(sS[2][0][2],sS[2][0][3])),
                        fmaxf(fmaxf(sS[2][1][0],sS[2][1][1]),fmaxf(sS[2][1][2],sS[2][1][3])));
      float mc3 = fmaxf(fmaxf(fmaxf(sS[3][0][0],sS[3][0][1]),fmaxf(sS[3][0][2],sS[3][0][3])),
                        fmaxf(fmaxf(sS[3][1][0],sS[3][1][1]),fmaxf(sS[3][1][2],sS[3][1][3])));
      float mx = fmaxf(fmaxf(mc0,mc1), fmaxf(mc2,mc3));
      mx = fmaxf(mx, __shfl_xor(mx, 16));
      mx = fmaxf(mx, __shfl_xor(mx, 32));
      float mn = fmaxf(m, mx);
      float corr = EXP2(m - mn);
      m = mn;
      float ps = 0.f;
      #pragma unroll
      for (int ci = 0; ci < 4; ++ci){
        float p0=0.f, p1=0.f;
        #pragma unroll
        for (int v = 0; v < 4; ++v){
          sS[ci][0][v] = EXP2(sS[ci][0][v] - m); p0 += sS[ci][0][v];
          sS[ci][1][v] = EXP2(sS[ci][1][v] - m); p1 += sS[ci][1][v];
        }
        ps += p0 + p1;
      }
      ps += __shfl_xor(ps, 16);
      ps += __shfl_xor(ps, 32);
      l = l*corr + ps;
      oacc0 *= corr; oacc1 *= corr;
      #pragma unroll
      for (int ci = 0; ci < 4; ++ci){
        int ch = hl*4 + ci;
        short8 pf = redist(sS[ci][0], sS[ci][1], l4);
        short8 vt0 = *(const short8*)(VTs + (l15)*528 + ch*64 + l4*16);
        short8 vt1 = *(const short8*)(VTs + (16 + l15)*528 + ch*64 + l4*16);
        oacc0 = MFMA(vt0, pf, oacc0);
        oacc1 = MFMA(vt1, pf, oacc1);
      }
    }
    // ---- O normalize + in-reg redistribute + fuse O_h @ Wo_h ----
    {
      float inv = 1.f / l;
      short8 oA = redist(oacc0*inv, oacc1*inv, l4);
      const char* wob = WOs + (h&1)*10240;
      #pragma unroll
      for (int ct = 0; ct < 8; ++ct){
        short8 wB = *(const short8*)(wob + (ct*16 + l15)*80 + l4*16);
        pa[ct] = MFMA(oA, wB, pa[ct]);
      }
    }
    if (WSOK && h < 3) asm volatile("s_waitcnt vmcnt(0)" ::: "memory");
    __syncthreads();   // flash reads of K/VT done; W(h+1) landed in all waves
  }

  // ---- epilogue: residual + bo + LN2 + NT write ----
  float mrs[4], mrq[4];
  #pragma unroll
  for (int v = 0; v < 4; ++v){ mrs[v] = 0.f; mrq[v] = 0.f; }
  #pragma unroll
  for (int ct = 0; ct < 8; ++ct)
    #pragma unroll
    for (int v = 0; v < 4; ++v){
      int o = ct*16 + l15;
      int r = w*16 + l4*4 + v;
      float xv = b2f(*(const u16*)(Xs + XBYTE(r, o)));
      float t = pa[ct][v] + GBs[256 + o] + xv;
      pa[ct][v] = t;
      mrs[v] += t; mrq[v] += t*t;
    }
  #pragma unroll
  for (int v = 0; v < 4; ++v){
    #pragma unroll
    for (int ms = 1; ms < 16; ms <<= 1){
      mrs[v] += __shfl_xor(mrs[v], ms);
      mrq[v] += __shfl_xor(mrq[v], ms);
    }
    float mean = mrs[v]*(1.f/CC);
    float var  = fmaxf(mrq[v]*(1.f/CC) - mean*mean, 0.f);
    mrs[v] = mean;
    mrq[v] = rsqrtf(var + EPSV);
  }
  #pragma unroll
  for (int ct = 0; ct < 8; ++ct)
    #pragma unroll
    for (int v = 0; v < 4; ++v){
      int o = ct*16 + l15;
      int r = w*16 + l4*4 + v;
      __builtin_nontemporal_store((pa[ct][v] - mrs[v])*mrq[v]*GBs[o] + GBs[128+o],
                                  orow + r*CC + o);
    }
}

// s_in[j][c] = sum_{k<j} pr[k][j][c]
__launch_bounds__(1024)
__global__ void colprefix_kernel(const float* __restrict__ pr, float* __restrict__ s_in){
  __shared__ float red[1024];
  int j = blockIdx.x;
  int c = threadIdx.x & 127, part = threadIdx.x >> 7;
  float acc = 0.f;
  for (int k = part; k < j; k += 8)
    acc += __builtin_nontemporal_load(pr + (size_t)k*NN*CC + j*CC + c);
  red[threadIdx.x] = acc;
  __syncthreads();
  if (threadIdx.x < 128){
    float s = 0.f;
    #pragma unroll
    for (int p = 0; p < 8; ++p) s += red[p*128 + threadIdx.x];
    s_in[j*CC + threadIdx.x] = s;
  }
}

__launch_bounds__(128)
__global__ void single_kernel(const float* __restrict__ single,
                              const float* __restrict__ W1, const float* __restrict__ b1,
                              const float* __restrict__ W2, const float* __restrict__ b2,
                              const float* __restrict__ g, const float* __restrict__ bb,
                              float* __restrict__ sr){
  __shared__ float srow[128];
  __shared__ float sh1[256];
  __shared__ float red[4];
  int jr = blockIdx.x, t = threadIdx.x;
  srow[t] = single[jr*CC + t];
  __syncthreads();
  float a0 = b1[t], a1 = b1[t+128];
  for (int c = 0; c < 128; ++c){
    float s = srow[c];
    a0 += s * W1[c*256 + t];
    a1 += s * W1[c*256 + t + 128];
  }
  sh1[t] = fmaxf(a0, 0.f);
  sh1[t+128] = fmaxf(a1, 0.f);
  __syncthreads();
  float acc = b2[t];
  for (int o = 0; o < 256; ++o) acc += sh1[o] * W2[o*CC + t];
  acc = fmaxf(acc, 0.f);
  float tv = srow[t] + acc;
  float s = tv, q = tv*tv;
  #pragma unroll
  for (int mm = 32; mm; mm >>= 1){ s += __shfl_xor(s, mm); q += __shfl_xor(q, mm); }
  int w = t >> 6;
  if ((t & 63) == 0){ red[w] = s; red[2+w] = q; }
  __syncthreads();
  float S = red[0] + red[1], Q = red[2] + red[3];
  float mean = S*(1.f/CC);
  float var = fmaxf(Q*(1.f/CC) - mean*mean, 0.f);
  float rs = rsqrtf(var + EPSV);
  sr[jr*CC + t] = (tv - mean)*rs*g[t] + bb[t];
}

extern "C" void kernel_launch(void* const* d_in, const int* in_sizes, int n_in,
                              void* d_out, int out_size, void* d_ws, size_t ws_size,
                              hipStream_t stream) {
  const float* pair   = (const float*)d_in[0];
  const float* single = (const float*)d_in[1];
  const int*   mask   = (const int*)d_in[2];
  const float* dist   = (const float*)d_in[3];
  const float* rWqkv  = (const float*)d_in[4];
  const float* rbqkv  = (const float*)d_in[5];
  const float* rWo    = (const float*)d_in[6];
  const float* rbo    = (const float*)d_in[7];
  const float* rdsc   = (const float*)d_in[8];
  const float* cWqkv  = (const float*)d_in[9];
  const float* cbqkv  = (const float*)d_in[10];
  const float* cWo    = (const float*)d_in[11];
  const float* cbo    = (const float*)d_in[12];
  const float* cdsc   = (const float*)d_in[13];
  const float* pnr_g  = (const float*)d_in[14];
  const float* pnr_b  = (const float*)d_in[15];
  const float* pnc_g  = (const float*)d_in[16];
  const float* pnc_b  = (const float*)d_in[17];
  const float* sn_g   = (const float*)d_in[18];
  const float* sn_b   = (const float*)d_in[19];
  const float* W1     = (const float*)d_in[20];
  const float* b1     = (const float*)d_in[21];
  const float* W2     = (const float*)d_in[22];
  const float* b2     = (const float*)d_in[23];

  float* outp = (float*)d_out;
  float* pr   = outp;
  float* srr  = outp + (size_t)NN*NN*CC;

  const bool usews = ws_size >= (size_t)WS_NEED;
  char* wsb = (char*)d_ws;
  u16* bias0 = (u16*)(wsb + WS_B0);
  u16* bias1 = (u16*)(wsb + WS_B1);
  u16* wimg0 = (u16*)(wsb + WS_W0);
  u16* wimg1 = (u16*)(wsb + WS_W1);
  float* s_in = usews ? (float*)(wsb + WS_SIN) : srr;

  if (usews){
    (void)hipFuncSetAttribute(reinterpret_cast<const void*>(stage_kernel<0,1>),
                              hipFuncAttributeMaxDynamicSharedMemorySize, SMEM_BYTES);
    (void)hipFuncSetAttribute(reinterpret_cast<const void*>(stage_kernel<1,1>),
                              hipFuncAttributeMaxDynamicSharedMemorySize, SMEM_BYTES);
    prep_bias<<<NN, NN, 0, stream>>>(mask, dist, rdsc, cdsc, bias0, bias1);
    prep_wimg<<<8, 256, 0, stream>>>(rWqkv, rWo, cWqkv, cWo, wimg0, wimg1);
    stage_kernel<0,1><<<NN, 1024, SMEM_BYTES, stream>>>(pair, single, single, mask, dist,
        bias0, wimg0, rWqkv, rbqkv, rWo, rbo, rdsc, pnr_g, pnr_b, pr);
    colprefix_kernel<<<NN, 1024, 0, stream>>>(pr, s_in);
    stage_kernel<1,1><<<NN, 1024, SMEM_BYTES, stream>>>(pr, s_in, single, mask, dist,
        bias1, wimg1, cWqkv, cbqkv, cWo, cbo, cdsc, pnc_g, pnc_b, pr);
  } else {
    (void)hipFuncSetAttribute(reinterpret_cast<const void*>(stage_kernel<0,0>),
                              hipFuncAttributeMaxDynamicSharedMemorySize, SMEM_BYTES);
    (void)hipFuncSetAttribute(reinterpret_cast<const void*>(stage_kernel<1,0>),
                              hipFuncAttributeMaxDynamicSharedMemorySize, SMEM_BYTES);
    stage_kernel<0,0><<<NN, 1024, SMEM_BYTES, stream>>>(pair, single, single, mask, dist,
        nullptr, nullptr, rWqkv, rbqkv, rWo, rbo, rdsc, pnr_g, pnr_b, pr);
    colprefix_kernel<<<NN, 1024, 0, stream>>>(pr, s_in);
    stage_kernel<1,0><<<NN, 1024, SMEM_BYTES, stream>>>(pr, s_in, single, mask, dist,
        nullptr, nullptr, cWqkv, cbqkv, cWo, cbo, cdsc, pnc_g, pnc_b, pr);
  }
  single_kernel<<<NN, CC, 0, stream>>>(single, W1, b1, W2, b2, sn_g, sn_b, srr);
}

// Round 7
// 275.104 us; speedup vs baseline: 6.4684x; 1.0271x over previous
//
#include <hip/hip_runtime.h>
#include <math.h>

typedef unsigned int u32;
typedef unsigned short u16;
typedef __attribute__((ext_vector_type(8))) short short8;   // 8 bf16 in 4 VGPRs
typedef __attribute__((ext_vector_type(4))) float f32x4;
typedef __attribute__((ext_vector_type(2))) u32 u32x2;

#define NN 256
#define CC 128
#define EPSV 1e-5f
#define LOG2E 1.44269504088896f
#define QSCL (0.17677669529663687f * 1.44269504088896f)   // 1/sqrt(32) * log2(e)
#define NEGBIG -1e30f

#define MFMA(a,b,c) __builtin_amdgcn_mfma_f32_16x16x32_bf16(a,b,c,0,0,0)
#define EXP2(x) __builtin_amdgcn_exp2f(x)

__device__ __forceinline__ float b2f(u16 u){ return __uint_as_float(((u32)u)<<16); }
__device__ __forceinline__ u16 f2b(float f){
  u32 x = __float_as_uint(f);
  return (u16)((x + 0x7fffu + ((x>>16)&1u)) >> 16);
}
__device__ __forceinline__ void unpk(u32 u, float&a, float&b){
  a = __uint_as_float(u<<16); b = __uint_as_float(u & 0xffff0000u);
}
__device__ __forceinline__ u32 cvtpk(float lo, float hi){
  u32 r;
  asm("v_cvt_pk_bf16_f32 %0, %1, %2" : "=v"(r) : "v"(lo), "v"(hi));
  return r;
}
__device__ __forceinline__ void gload16(const void* g, void* l){
  __builtin_amdgcn_global_load_lds((const __attribute__((address_space(1))) u32*)g,
                                   (__attribute__((address_space(3))) u32*)l, 16, 0, 0);
}

// redistribute 8 values (2 f32x4 tiles, idx = tile*16 + l4*4 + v at col l15) into
// A/B-frag short8 (lane l4 gets idx l4*8..l4*8+7 for its l15). Verified P-path algebra.
__device__ __forceinline__ short8 redist(f32x4 t0, f32x4 t1, int l4){
  u32 A0 = cvtpk(t0[0], t0[1]), A1 = cvtpk(t0[2], t0[3]);
  u32 B0 = cvtpk(t1[0], t1[1]), B1 = cvtpk(t1[2], t1[3]);
  asm volatile("v_permlane32_swap_b32 %0, %1" : "+v"(A0), "+v"(B0));
  asm volatile("v_permlane32_swap_b32 %0, %1" : "+v"(A1), "+v"(B1));
  u32 sA0 = __shfl_xor(A0, 16), sA1 = __shfl_xor(A1, 16);
  u32 sB0 = __shfl_xor(B0, 16), sB1 = __shfl_xor(B1, 16);
  bool eg = ((l4 & 1) == 0);
  union { u32 u[4]; short8 s; } pu;
  pu.u[0] = eg ? A0 : sB0;
  pu.u[1] = eg ? A1 : sB1;
  pu.u[2] = eg ? sA0 : B0;
  pu.u[3] = eg ? sA1 : B1;
  return pu.s;
}

// ---- LDS layout (bytes) ----
#define XS_OFF   0        // bf16 X[256][128] swizzled                  (65536)
#define WT_OFF   65536    // bf16 Wt[96][128] head slice, swizzled      (24576)
#define WO_OFF   90112    // bf16 Woh dbuf [2][128][40]                 (20480)
#define KB_OFF   110592   // bf16 K[256][40]                            (20480)
#define VT_OFF   131072   // bf16 Vt[32][264]                           (16896)
#define SV_OFF   147968   // f32 sv[128]                                (512)
#define GB_OFF   148480   // f32 g[128], b[128], bo[128]                (1536)
#define BQ_OFF   150016   // f32 bqkv[384]                              (1536)
#define RS_OFF   151552   // f32 red[16][128] (phase-0 scratch)         (8192)
#define SMEM_BYTES 159744

#define XBYTE(r,c) ((r)*256 + (((((c)>>3)) ^ ((r)&7))<<4) + ((c)&7)*2)

// ws layout (bytes)
#define WS_B0   0          // bias img phase0 (131072)
#define WS_B1   131072     // bias img phase1 (131072)
#define WS_W0   262144     // W img stage0 (139264 = 4 heads x (24576 WT + 10240 WO))
#define WS_W1   401408     // W img stage1 (139264)
#define WS_SIN  540672     // s_in f32 (131072)
#define WS_NEED 671744

// bias image, per-lane-consumed layout: u16 addr = q*256 + l4*64 + ch*8 + kt*4 + v
__global__ void prep_bias(const int* __restrict__ mask, const float* __restrict__ dist,
                          const float* __restrict__ rd, const float* __restrict__ cd,
                          u16* __restrict__ b0, u16* __restrict__ b1){
  int q = blockIdx.x, k = threadIdx.x;
  int l4 = (k >> 2) & 3, v = k & 3, kt = (k >> 4) & 1, ch = k >> 5;
  int addr = q*256 + l4*64 + ch*8 + kt*4 + v;
  float dv = dist[q*NN + k];
  b0[addr] = mask[q*NN + k] ? f2b(NEGBIG) : f2b(rd[0]*LOG2E*dv);
  b1[addr] = mask[k*NN + q] ? f2b(NEGBIG) : f2b(cd[0]*LOG2E*dv);
}

// weight images: byte-exact copies of the LDS layouts (WT swizzled, WO padded)
__global__ void prep_wimg(const float* __restrict__ rWqkv, const float* __restrict__ rWo,
                          const float* __restrict__ cWqkv, const float* __restrict__ cWo,
                          u16* __restrict__ img0, u16* __restrict__ img1){
  int h = blockIdx.x & 3, s = blockIdx.x >> 2;
  const float* Wq = s ? cWqkv : rWqkv;
  const float* Wom = s ? cWo : rWo;
  char* base = (char*)(s ? img1 : img0) + h*34816;
  for (int e = threadIdx.x; e < 96*128; e += 256){
    int t = e >> 7, c = e & 127;
    int col = (t < 32) ? (h*32 + t) : (t < 64) ? (CC + h*32 + (t-32)) : (2*CC + h*32 + (t-64));
    *(u16*)(base + t*256 + ((((c>>3) ^ (t&7)))<<4) + (c&7)*2) = f2b(Wq[c*384 + col]);
  }
  for (int e = threadIdx.x; e < 128*40; e += 256){
    int o = e / 40, d = e - o*40;
    *(u16*)(base + 24576 + (o*40 + d)*2) = (d < 32) ? f2b(Wom[(h*32 + d)*128 + o]) : (u16)0;
  }
}

template<int PHASE, int WSOK>
__launch_bounds__(1024, 4)
__global__ void stage_kernel(const float* __restrict__ pin, const float* __restrict__ colmat,
                             const float* __restrict__ singlerow,
                             const int* __restrict__ mask, const float* __restrict__ dist,
                             const u16* __restrict__ biasimg,
                             const u16* __restrict__ wimg,
                             const float* __restrict__ Wqkv, const float* __restrict__ bqkv,
                             const float* __restrict__ Wo, const float* __restrict__ bo,
                             const float* __restrict__ dscale,
                             const float* __restrict__ lng, const float* __restrict__ lnb,
                             float* __restrict__ outp)
{
  extern __shared__ char smem[];
  char* Xs  = smem + XS_OFF;
  char* WTs = smem + WT_OFF;
  char* WOs = smem + WO_OFF;
  char* KBs = smem + KB_OFF;
  char* VTs = smem + VT_OFF;
  float* SVs = (float*)(smem + SV_OFF);
  float* GBs = (float*)(smem + GB_OFF);
  float* BQs = (float*)(smem + BQ_OFF);
  float* RSs = (float*)(smem + RS_OFF);

  const int i = blockIdx.x;
  const int tid = threadIdx.x;
  const int lid = tid & 63;
  const int w = tid >> 6;            // 16 waves; wave owns query rows w*16..w*16+15
  const int l15 = lid & 15;
  const int l4  = lid >> 4;
  const int h32 = lid >> 5;
  const int c4  = (lid & 31) * 4;
  const float* prow = pin + (size_t)i*NN*CC;
  float* orow = outp + (size_t)i*NN*CC;
  const int qglob = w*16 + l15;
  const float dsc = dscale[0] * LOG2E;

  // issue W(head 0) staging immediately (lands during LN phase)
  if (WSOK){
    const char* wb = (const char*)wimg;
    gload16(wb + tid*16, WTs + tid*16);
    if (tid < 512) gload16(wb + 16384 + tid*16, WTs + 16384 + tid*16);
    if (tid < 640) gload16(wb + 24576 + tid*16, WOs + tid*16);
  }
  if (tid < 128){ GBs[tid] = lng[tid]; GBs[128+tid] = lnb[tid]; GBs[256+tid] = bo[tid]; }
  if (tid >= 512 && tid < 896) BQs[tid-512] = bqkv[tid-512];

  // ---- LN1 -> X (bf16 swizzled); phase 0 fuses the s_out prefix ----
  if (PHASE == 0){
    f32x4 svp = {0.f,0.f,0.f,0.f};
    #pragma unroll 4
    for (int p = 0; p < 8; ++p){
      int r = w*16 + p*2 + h32;
      f32x4 pr4 = __builtin_nontemporal_load((const f32x4*)(prow + r*CC + c4));
      f32x4 sg4 = *(const f32x4*)(colmat + r*CC + c4);
      f32x4 t = pr4 + sg4;
      u32x2 pk2; pk2.x = cvtpk(t[0], t[1]); pk2.y = cvtpk(t[2], t[3]);
      *(u32x2*)(Xs + XBYTE(r, c4)) = pk2;
      if (r < i) svp += pr4;
    }
    #pragma unroll
    for (int q = 0; q < 4; ++q) svp[q] += __shfl_xor(svp[q], 32);
    if (h32 == 0) *(f32x4*)(RSs + w*128 + c4) = svp;
    __syncthreads();
    if (tid < 128){
      float s = 0.f;
      #pragma unroll
      for (int ww = 0; ww < 16; ++ww) s += RSs[ww*128 + tid];
      SVs[tid] = s;
    }
    __syncthreads();
    f32x4 sv4 = *(const f32x4*)(SVs + c4);
    f32x4 g4  = *(const f32x4*)(GBs + c4);
    f32x4 b4  = *(const f32x4*)(GBs + 128 + c4);
    #pragma unroll 2
    for (int p = 0; p < 8; ++p){
      int r = w*16 + p*2 + h32;
      u32x2 st = *(const u32x2*)(Xs + XBYTE(r, c4));
      float t0,t1,t2,t3;
      unpk(st.x, t0, t1); unpk(st.y, t2, t3);
      t0 += sv4[0]; t1 += sv4[1]; t2 += sv4[2]; t3 += sv4[3];
      float s = (t0+t1)+(t2+t3);
      float q2 = (t0*t0+t1*t1)+(t2*t2+t3*t3);
      #pragma unroll
      for (int ms = 1; ms < 32; ms <<= 1){ s += __shfl_xor(s, ms); q2 += __shfl_xor(q2, ms); }
      float mean = s*(1.f/CC);
      float var  = fmaxf(q2*(1.f/CC) - mean*mean, 0.f);
      float rstd = rsqrtf(var + EPSV);
      float y0 = (t0-mean)*rstd*g4[0] + b4[0];
      float y1 = (t1-mean)*rstd*g4[1] + b4[1];
      float y2 = (t2-mean)*rstd*g4[2] + b4[2];
      float y3 = (t3-mean)*rstd*g4[3] + b4[3];
      u32x2 pk2; pk2.x = cvtpk(y0, y1); pk2.y = cvtpk(y2, y3);
      *(u32x2*)(Xs + XBYTE(r, c4)) = pk2;
    }
  } else {
    if (tid < 128) SVs[tid] = singlerow[i*CC + tid];
    __syncthreads();
    f32x4 sv4 = *(const f32x4*)(SVs + c4);
    f32x4 g4  = *(const f32x4*)(GBs + c4);
    f32x4 b4  = *(const f32x4*)(GBs + 128 + c4);
    #pragma unroll 4
    for (int p = 0; p < 8; ++p){
      int r = w*16 + p*2 + h32;
      f32x4 pr4 = __builtin_nontemporal_load((const f32x4*)(prow + r*CC + c4));
      f32x4 cm4 = *(const f32x4*)(colmat + r*CC + c4);
      float t0 = pr4[0]+cm4[0]+sv4[0], t1 = pr4[1]+cm4[1]+sv4[1];
      float t2 = pr4[2]+cm4[2]+sv4[2], t3 = pr4[3]+cm4[3]+sv4[3];
      float s = (t0+t1)+(t2+t3);
      float q2 = (t0*t0+t1*t1)+(t2*t2+t3*t3);
      #pragma unroll
      for (int ms = 1; ms < 32; ms <<= 1){ s += __shfl_xor(s, ms); q2 += __shfl_xor(q2, ms); }
      float mean = s*(1.f/CC);
      float var  = fmaxf(q2*(1.f/CC) - mean*mean, 0.f);
      float rstd = rsqrtf(var + EPSV);
      float y0 = (t0-mean)*rstd*g4[0] + b4[0];
      float y1 = (t1-mean)*rstd*g4[1] + b4[1];
      float y2 = (t2-mean)*rstd*g4[2] + b4[2];
      float y3 = (t3-mean)*rstd*g4[3] + b4[3];
      u32x2 pk2; pk2.x = cvtpk(y0, y1); pk2.y = cvtpk(y2, y3);
      *(u32x2*)(Xs + XBYTE(r, c4)) = pk2;
    }
  }
  if (WSOK) asm volatile("s_waitcnt vmcnt(0)" ::: "memory");
  __syncthreads();   // X ready; W(0) staged

  f32x4 pa[8];
  #pragma unroll
  for (int ct = 0; ct < 8; ++ct) pa[ct] = f32x4{0.f,0.f,0.f,0.f};

  for (int h = 0; h < 4; ++h){
    if (!WSOK){
      #pragma unroll
      for (int it = 0; it < 12; ++it){
        int e = tid + it*1024;
        int c = e & 127, t = e >> 7;
        int col = (t < 32) ? (h*32 + t) : (t < 64) ? (CC + h*32 + (t-32)) : (2*CC + h*32 + (t-64));
        *(u16*)(WTs + t*256 + ((((c>>3) ^ (t&7)))<<4) + (c&7)*2) = f2b(Wqkv[c*384 + col]);
      }
      #pragma unroll
      for (int it = 0; it < 4; ++it){
        int e = tid + it*1024;
        int d = e >> 7, o = e & 127;
        *(u16*)(WOs + (h&1)*10240 + (o*40 + d)*2) = (d < 32) ? f2b(Wo[(h*32 + d)*128 + o]) : (u16)0;
      }
      __syncthreads();
    }

    // ---- QKV GEMM: Q^T and V^T via W-as-A (swapped); K direct ----
    f32x4 qa[2], ka[2], va[2];
    #pragma unroll
    for (int dt = 0; dt < 2; ++dt)
      #pragma unroll
      for (int v = 0; v < 4; ++v){
        qa[dt][v] = BQs[h*32 + dt*16 + l4*4 + v];
        va[dt][v] = BQs[256 + h*32 + dt*16 + l4*4 + v];
      }
    {
      float bk0 = BQs[128 + h*32 + l15], bk1 = BQs[128 + h*32 + 16 + l15];
      ka[0] = f32x4{bk0,bk0,bk0,bk0}; ka[1] = f32x4{bk1,bk1,bk1,bk1};
    }
    #pragma unroll
    for (int ks = 0; ks < 4; ++ks){
      int swb = (((ks*4 + l4) ^ (l15 & 7)) << 4);
      short8 a0  = *(const short8*)(Xs  + (w*16 + l15)*256 + swb);
      short8 wq0 = *(const short8*)(WTs + (l15)*256 + swb);
      short8 wq1 = *(const short8*)(WTs + (16 + l15)*256 + swb);
      short8 wk0 = *(const short8*)(WTs + (32 + l15)*256 + swb);
      short8 wk1 = *(const short8*)(WTs + (48 + l15)*256 + swb);
      short8 wv0 = *(const short8*)(WTs + (64 + l15)*256 + swb);
      short8 wv1 = *(const short8*)(WTs + (80 + l15)*256 + swb);
      qa[0] = MFMA(wq0, a0, qa[0]); qa[1] = MFMA(wq1, a0, qa[1]);
      ka[0] = MFMA(a0, wk0, ka[0]); ka[1] = MFMA(a0, wk1, ka[1]);
      va[0] = MFMA(wv0, a0, va[0]); va[1] = MFMA(wv1, a0, va[1]);
    }
    short8 qf = redist(qa[0]*QSCL, qa[1]*QSCL, l4);
    #pragma unroll
    for (int kt = 0; kt < 2; ++kt)
      #pragma unroll
      for (int v = 0; v < 4; ++v)
        *(u16*)(KBs + ((w*16 + l4*4 + v)*40 + kt*16 + l15)*2) = (u16)cvtpk(ka[kt][v], ka[kt][v]);
    #pragma unroll
    for (int dt = 0; dt < 2; ++dt)
      #pragma unroll
      for (int v = 0; v < 4; ++v)
        *(u16*)(VTs + ((dt*16 + l4*4 + v)*264 + w*16 + l15)*2) = (u16)cvtpk(va[dt][v], va[dt][v]);
    __syncthreads();   // K/VT visible; all WT reads done

    if (WSOK && h < 3){  // prefetch next head's weights under the flash phase
      const char* wb = (const char*)wimg + (h+1)*34816;
      gload16(wb + tid*16, WTs + tid*16);
      if (tid < 512) gload16(wb + 16384 + tid*16, WTs + 16384 + tid*16);
      if (tid < 640) gload16(wb + 24576 + tid*16, WOs + ((h+1)&1)*10240 + tid*16);
    }

    // ---- attention: full-row softmax in 2 halves of 128 keys ----
    float m = -3e38f, l = 0.f;
    f32x4 oacc0 = {0.f,0.f,0.f,0.f}, oacc1 = {0.f,0.f,0.f,0.f};
    #pragma unroll
    for (int hl = 0; hl < 2; ++hl){
      f32x4 sS[4][2];
      #pragma unroll
      for (int ci = 0; ci < 4; ++ci){
        int ch = hl*4 + ci;
        short8 kf0 = *(const short8*)(KBs + (ch*32 + l15)*80 + l4*16);
        short8 kf1 = *(const short8*)(KBs + (ch*32 + 16 + l15)*80 + l4*16);
        f32x4 z = {0.f,0.f,0.f,0.f};
        sS[ci][0] = MFMA(kf0, qf, z);
        sS[ci][1] = MFMA(kf1, qf, z);
      }
      if (WSOK){
        const u16* bb = biasimg + qglob*256 + l4*64 + hl*32;
        #pragma unroll
        for (int ci = 0; ci < 4; ++ci){
          uint4 bw = *(const uint4*)(bb + ci*8);
          float b00,b01,b02,b03,b10,b11,b12,b13;
          unpk(bw.x, b00, b01); unpk(bw.y, b02, b03);
          unpk(bw.z, b10, b11); unpk(bw.w, b12, b13);
          sS[ci][0][0]+=b00; sS[ci][0][1]+=b01; sS[ci][0][2]+=b02; sS[ci][0][3]+=b03;
          sS[ci][1][0]+=b10; sS[ci][1][1]+=b11; sS[ci][1][2]+=b12; sS[ci][1][3]+=b13;
        }
      } else {
        #pragma unroll
        for (int ci = 0; ci < 4; ++ci)
          #pragma unroll
          for (int kt = 0; kt < 2; ++kt)
            #pragma unroll
            for (int v = 0; v < 4; ++v){
              int key = (hl*4 + ci)*32 + kt*16 + l4*4 + v;
              int mq = (PHASE==0) ? mask[qglob*NN + key] : mask[key*NN + qglob];
              sS[ci][kt][v] += mq ? NEGBIG : dsc*dist[qglob*NN + key];
            }
      }
      float mc0 = fmaxf(fmaxf(fmaxf(sS[0][0][0],sS[0][0][1]),fmaxf(sS[0][0][2],sS[0][0][3])),
                        fmaxf(fmaxf(sS[0][1][0],sS[0][1][1]),fmaxf(sS[0][1][2],sS[0][1][3])));
      float mc1 = fmaxf(fmaxf(fmaxf(sS[1][0][0],sS[1][0][1]),fmaxf(sS[1][0][2],sS[1][0][3])),
                        fmaxf(fmaxf(sS[1][1][0],sS[1][1][1]),fmaxf(sS[1][1][2],sS[1][1][3])));
      float mc2 = fmaxf(fmaxf(fmaxf(sS[2][0][0],sS[2][0][1]),fmaxf(sS[2][0][2],sS[2][0][3])),
                        fmaxf(fmaxf(sS[2][1][0],sS[2][1][1]),fmaxf(sS[2][1][2],sS[2][1][3])));
      float mc3 = fmaxf(fmaxf(fmaxf(sS[3][0][0],sS[3][0][1]),fmaxf(sS[3][0][2],sS[3][0][3])),
                        fmaxf(fmaxf(sS[3][1][0],sS[3][1][1]),fmaxf(sS[3][1][2],sS[3][1][3])));
      float mx = fmaxf(fmaxf(mc0,mc1), fmaxf(mc2,mc3));
      mx = fmaxf(mx, __shfl_xor(mx, 16));
      mx = fmaxf(mx, __shfl_xor(mx, 32));
      float mn = fmaxf(m, mx);
      float corr = EXP2(m - mn);
      m = mn;
      float ps = 0.f;
      #pragma unroll
      for (int ci = 0; ci < 4; ++ci){
        float p0=0.f, p1=0.f;
        #pragma unroll
        for (int v = 0; v < 4; ++v){
          sS[ci][0][v] = EXP2(sS[ci][0][v] - m); p0 += sS[ci][0][v];
          sS[ci][1][v] = EXP2(sS[ci][1][v] - m); p1 += sS[ci][1][v];
        }
        ps += p0 + p1;
      }
      ps += __shfl_xor(ps, 16);
      ps += __shfl_xor(ps, 32);
      l = l*corr + ps;
      oacc0 *= corr; oacc1 *= corr;
      #pragma unroll
      for (int ci = 0; ci < 4; ++ci){
        int ch = hl*4 + ci;
        short8 pf = redist(sS[ci][0], sS[ci][1], l4);
        short8 vt0 = *(const short8*)(VTs + (l15)*528 + ch*64 + l4*16);
        short8 vt1 = *(const short8*)(VTs + (16 + l15)*528 + ch*64 + l4*16);
        oacc0 = MFMA(vt0, pf, oacc0);
        oacc1 = MFMA(vt1, pf, oacc1);
      }
    }
    // ---- O normalize + in-reg redistribute + fuse O_h @ Wo_h ----
    {
      float inv = 1.f / l;
      short8 oA = redist(oacc0*inv, oacc1*inv, l4);
      const char* wob = WOs + (h&1)*10240;
      #pragma unroll
      for (int ct = 0; ct < 8; ++ct){
        short8 wB = *(const short8*)(wob + (ct*16 + l15)*80 + l4*16);
        pa[ct] = MFMA(oA, wB, pa[ct]);
      }
    }
    if (WSOK && h < 3) asm volatile("s_waitcnt vmcnt(0)" ::: "memory");
    __syncthreads();   // flash reads of K/VT done; W(h+1) landed in all waves
  }

  // ---- epilogue: residual + bo + LN2 + plain coalesced write ----
  float mrs[4], mrq[4];
  #pragma unroll
  for (int v = 0; v < 4; ++v){ mrs[v] = 0.f; mrq[v] = 0.f; }
  #pragma unroll
  for (int ct = 0; ct < 8; ++ct)
    #pragma unroll
    for (int v = 0; v < 4; ++v){
      int o = ct*16 + l15;
      int r = w*16 + l4*4 + v;
      float xv = b2f(*(const u16*)(Xs + XBYTE(r, o)));
      float t = pa[ct][v] + GBs[256 + o] + xv;
      pa[ct][v] = t;
      mrs[v] += t; mrq[v] += t*t;
    }
  #pragma unroll
  for (int v = 0; v < 4; ++v){
    #pragma unroll
    for (int ms = 1; ms < 16; ms <<= 1){
      mrs[v] += __shfl_xor(mrs[v], ms);
      mrq[v] += __shfl_xor(mrq[v], ms);
    }
    float mean = mrs[v]*(1.f/CC);
    float var  = fmaxf(mrq[v]*(1.f/CC) - mean*mean, 0.f);
    mrs[v] = mean;
    mrq[v] = rsqrtf(var + EPSV);
  }
  #pragma unroll
  for (int ct = 0; ct < 8; ++ct)
    #pragma unroll
    for (int v = 0; v < 4; ++v){
      int o = ct*16 + l15;
      int r = w*16 + l4*4 + v;
      orow[r*CC + o] = (pa[ct][v] - mrs[v])*mrq[v]*GBs[o] + GBs[128+o];
    }
}

// s_in[j][c] = sum_{k<j} pr[k][j][c]
__launch_bounds__(1024)
__global__ void colprefix_kernel(const float* __restrict__ pr, float* __restrict__ s_in){
  __shared__ float red[1024];
  int j = blockIdx.x;
  int c = threadIdx.x & 127, part = threadIdx.x >> 7;
  float acc = 0.f;
  for (int k = part; k < j; k += 8)
    acc += __builtin_nontemporal_load(pr + (size_t)k*NN*CC + j*CC + c);
  red[threadIdx.x] = acc;
  __syncthreads();
  if (threadIdx.x < 128){
    float s = 0.f;
    #pragma unroll
    for (int p = 0; p < 8; ++p) s += red[p*128 + threadIdx.x];
    s_in[j*CC + threadIdx.x] = s;
  }
}

__launch_bounds__(128)
__global__ void single_kernel(const float* __restrict__ single,
                              const float* __restrict__ W1, const float* __restrict__ b1,
                              const float* __restrict__ W2, const float* __restrict__ b2,
                              const float* __restrict__ g, const float* __restrict__ bb,
                              float* __restrict__ sr){
  __shared__ float srow[128];
  __shared__ float sh1[256];
  __shared__ float red[4];
  int jr = blockIdx.x, t = threadIdx.x;
  srow[t] = single[jr*CC + t];
  __syncthreads();
  float a0 = b1[t], a1 = b1[t+128];
  for (int c = 0; c < 128; ++c){
    float s = srow[c];
    a0 += s * W1[c*256 + t];
    a1 += s * W1[c*256 + t + 128];
  }
  sh1[t] = fmaxf(a0, 0.f);
  sh1[t+128] = fmaxf(a1, 0.f);
  __syncthreads();
  float acc = b2[t];
  for (int o = 0; o < 256; ++o) acc += sh1[o] * W2[o*CC + t];
  acc = fmaxf(acc, 0.f);
  float tv = srow[t] + acc;
  float s = tv, q = tv*tv;
  #pragma unroll
  for (int mm = 32; mm; mm >>= 1){ s += __shfl_xor(s, mm); q += __shfl_xor(q, mm); }
  int w = t >> 6;
  if ((t & 63) == 0){ red[w] = s; red[2+w] = q; }
  __syncthreads();
  float S = red[0] + red[1], Q = red[2] + red[3];
  float mean = S*(1.f/CC);
  float var = fmaxf(Q*(1.f/CC) - mean*mean, 0.f);
  float rs = rsqrtf(var + EPSV);
  sr[jr*CC + t] = (tv - mean)*rs*g[t] + bb[t];
}

extern "C" void kernel_launch(void* const* d_in, const int* in_sizes, int n_in,
                              void* d_out, int out_size, void* d_ws, size_t ws_size,
                              hipStream_t stream) {
  const float* pair   = (const float*)d_in[0];
  const float* single = (const float*)d_in[1];
  const int*   mask   = (const int*)d_in[2];
  const float* dist   = (const float*)d_in[3];
  const float* rWqkv  = (const float*)d_in[4];
  const float* rbqkv  = (const float*)d_in[5];
  const float* rWo    = (const float*)d_in[6];
  const float* rbo    = (const float*)d_in[7];
  const float* rdsc   = (const float*)d_in[8];
  const float* cWqkv  = (const float*)d_in[9];
  const float* cbqkv  = (const float*)d_in[10];
  const float* cWo    = (const float*)d_in[11];
  const float* cbo    = (const float*)d_in[12];
  const float* cdsc   = (const float*)d_in[13];
  const float* pnr_g  = (const float*)d_in[14];
  const float* pnr_b  = (const float*)d_in[15];
  const float* pnc_g  = (const float*)d_in[16];
  const float* pnc_b  = (const float*)d_in[17];
  const float* sn_g   = (const float*)d_in[18];
  const float* sn_b   = (const float*)d_in[19];
  const float* W1     = (const float*)d_in[20];
  const float* b1     = (const float*)d_in[21];
  const float* W2     = (const float*)d_in[22];
  const float* b2     = (const float*)d_in[23];

  float* outp = (float*)d_out;
  float* pr   = outp;
  float* srr  = outp + (size_t)NN*NN*CC;

  const bool usews = ws_size >= (size_t)WS_NEED;
  char* wsb = (char*)d_ws;
  u16* bias0 = (u16*)(wsb + WS_B0);
  u16* bias1 = (u16*)(wsb + WS_B1);
  u16* wimg0 = (u16*)(wsb + WS_W0);
  u16* wimg1 = (u16*)(wsb + WS_W1);
  float* s_in = usews ? (float*)(wsb + WS_SIN) : srr;

  if (usews){
    (void)hipFuncSetAttribute(reinterpret_cast<const void*>(stage_kernel<0,1>),
                              hipFuncAttributeMaxDynamicSharedMemorySize, SMEM_BYTES);
    (void)hipFuncSetAttribute(reinterpret_cast<const void*>(stage_kernel<1,1>),
                              hipFuncAttributeMaxDynamicSharedMemorySize, SMEM_BYTES);
    prep_bias<<<NN, NN, 0, stream>>>(mask, dist, rdsc, cdsc, bias0, bias1);
    prep_wimg<<<8, 256, 0, stream>>>(rWqkv, rWo, cWqkv, cWo, wimg0, wimg1);
    stage_kernel<0,1><<<NN, 1024, SMEM_BYTES, stream>>>(pair, single, single, mask, dist,
        bias0, wimg0, rWqkv, rbqkv, rWo, rbo, rdsc, pnr_g, pnr_b, pr);
    colprefix_kernel<<<NN, 1024, 0, stream>>>(pr, s_in);
    stage_kernel<1,1><<<NN, 1024, SMEM_BYTES, stream>>>(pr, s_in, single, mask, dist,
        bias1, wimg1, cWqkv, cbqkv, cWo, cbo, cdsc, pnc_g, pnc_b, pr);
  } else {
    (void)hipFuncSetAttribute(reinterpret_cast<const void*>(stage_kernel<0,0>),
                              hipFuncAttributeMaxDynamicSharedMemorySize, SMEM_BYTES);
    (void)hipFuncSetAttribute(reinterpret_cast<const void*>(stage_kernel<1,0>),
                              hipFuncAttributeMaxDynamicSharedMemorySize, SMEM_BYTES);
    stage_kernel<0,0><<<NN, 1024, SMEM_BYTES, stream>>>(pair, single, single, mask, dist,
        nullptr, nullptr, rWqkv, rbqkv, rWo, rbo, rdsc, pnr_g, pnr_b, pr);
    colprefix_kernel<<<NN, 1024, 0, stream>>>(pr, s_in);
    stage_kernel<1,0><<<NN, 1024, SMEM_BYTES, stream>>>(pr, s_in, single, mask, dist,
        nullptr, nullptr, cWqkv, cbqkv, cWo, cbo, cdsc, pnc_g, pnc_b, pr);
  }
  single_kernel<<<NN, CC, 0, stream>>>(single, W1, b1, W2, b2, sn_g, sn_b, srr);
}

// Round 8
// 275.101 us; speedup vs baseline: 6.4685x; 1.0000x over previous
//
#include <hip/hip_runtime.h>
#include <math.h>

typedef unsigned int u32;
typedef unsigned short u16;
typedef __attribute__((ext_vector_type(8))) short short8;   // 8 bf16 in 4 VGPRs
typedef __attribute__((ext_vector_type(4))) float f32x4;
typedef __attribute__((ext_vector_type(2))) u32 u32x2;

#define NN 256
#define CC 128
#define EPSV 1e-5f
#define LOG2E 1.44269504088896f
#define QSCL (0.17677669529663687f * 1.44269504088896f)   // 1/sqrt(32) * log2(e)
#define NEGBIG -1e30f

#define MFMA(a,b,c) __builtin_amdgcn_mfma_f32_16x16x32_bf16(a,b,c,0,0,0)
#define EXP2(x) __builtin_amdgcn_exp2f(x)

__device__ __forceinline__ float b2f(u16 u){ return __uint_as_float(((u32)u)<<16); }
__device__ __forceinline__ u16 f2b(float f){
  u32 x = __float_as_uint(f);
  return (u16)((x + 0x7fffu + ((x>>16)&1u)) >> 16);
}
__device__ __forceinline__ void unpk(u32 u, float&a, float&b){
  a = __uint_as_float(u<<16); b = __uint_as_float(u & 0xffff0000u);
}
__device__ __forceinline__ u32 cvtpk(float lo, float hi){
  u32 r;
  asm("v_cvt_pk_bf16_f32 %0, %1, %2" : "=v"(r) : "v"(lo), "v"(hi));
  return r;
}
__device__ __forceinline__ void gload16(const void* g, void* l){
  __builtin_amdgcn_global_load_lds((const __attribute__((address_space(1))) u32*)g,
                                   (__attribute__((address_space(3))) u32*)l, 16, 0, 0);
}

// redistribute 8 values (2 f32x4 tiles, idx = tile*16 + l4*4 + v at col l15) into
// A/B-frag short8 (lane l4 gets idx l4*8..l4*8+7 for its l15). Verified P-path algebra.
__device__ __forceinline__ short8 redist(f32x4 t0, f32x4 t1, int l4){
  u32 A0 = cvtpk(t0[0], t0[1]), A1 = cvtpk(t0[2], t0[3]);
  u32 B0 = cvtpk(t1[0], t1[1]), B1 = cvtpk(t1[2], t1[3]);
  asm volatile("v_permlane32_swap_b32 %0, %1" : "+v"(A0), "+v"(B0));
  asm volatile("v_permlane32_swap_b32 %0, %1" : "+v"(A1), "+v"(B1));
  u32 sA0 = __shfl_xor(A0, 16), sA1 = __shfl_xor(A1, 16);
  u32 sB0 = __shfl_xor(B0, 16), sB1 = __shfl_xor(B1, 16);
  bool eg = ((l4 & 1) == 0);
  union { u32 u[4]; short8 s; } pu;
  pu.u[0] = eg ? A0 : sB0;
  pu.u[1] = eg ? A1 : sB1;
  pu.u[2] = eg ? sA0 : B0;
  pu.u[3] = eg ? sA1 : B1;
  return pu.s;
}

// ---- LDS layout (bytes) ----
#define XS_OFF   0        // bf16 X[256][128] swizzled                  (65536)
#define WT_OFF   65536    // bf16 Wt[96][128] head slice, swizzled      (24576)
#define WO_OFF   90112    // bf16 Woh dbuf [2][128][40]                 (20480)
#define KB_OFF   110592   // bf16 K[256][40]                            (20480)
#define VT_OFF   131072   // bf16 Vt[32][264]                           (16896)
#define SV_OFF   147968   // f32 sv[128]                                (512)
#define GB_OFF   148480   // f32 g[128], b[128], bo[128]                (1536)
#define BQ_OFF   150016   // f32 bqkv[384]                              (1536)
#define RS_OFF   151552   // f32 red[16][128] (phase-0 scratch)         (8192)
#define SMEM_BYTES 159744

#define XBYTE(r,c) ((r)*256 + (((((c)>>3)) ^ ((r)&7))<<4) + ((c)&7)*2)

// ws layout (bytes)
#define WS_B0   0          // bias img phase0 (131072)
#define WS_B1   131072     // bias img phase1 (131072)
#define WS_W0   262144     // W img stage0 (139264 = 4 heads x (24576 WT + 10240 WO))
#define WS_W1   401408     // W img stage1 (139264)
#define WS_SIN  540672     // s_in f32 (131072)
#define WS_NEED 671744

// bias image, per-lane-consumed layout: u16 addr = q*256 + l4*64 + ch*8 + kt*4 + v
__global__ void prep_bias(const int* __restrict__ mask, const float* __restrict__ dist,
                          const float* __restrict__ rd, const float* __restrict__ cd,
                          u16* __restrict__ b0, u16* __restrict__ b1){
  int q = blockIdx.x, k = threadIdx.x;
  int l4 = (k >> 2) & 3, v = k & 3, kt = (k >> 4) & 1, ch = k >> 5;
  int addr = q*256 + l4*64 + ch*8 + kt*4 + v;
  float dv = dist[q*NN + k];
  b0[addr] = mask[q*NN + k] ? f2b(NEGBIG) : f2b(rd[0]*LOG2E*dv);
  b1[addr] = mask[k*NN + q] ? f2b(NEGBIG) : f2b(cd[0]*LOG2E*dv);
}

// weight images: byte-exact copies of the LDS layouts (WT swizzled, WO padded)
__global__ void prep_wimg(const float* __restrict__ rWqkv, const float* __restrict__ rWo,
                          const float* __restrict__ cWqkv, const float* __restrict__ cWo,
                          u16* __restrict__ img0, u16* __restrict__ img1){
  int h = blockIdx.x & 3, s = blockIdx.x >> 2;
  const float* Wq = s ? cWqkv : rWqkv;
  const float* Wom = s ? cWo : rWo;
  char* base = (char*)(s ? img1 : img0) + h*34816;
  for (int e = threadIdx.x; e < 96*128; e += 256){
    int t = e >> 7, c = e & 127;
    int col = (t < 32) ? (h*32 + t) : (t < 64) ? (CC + h*32 + (t-32)) : (2*CC + h*32 + (t-64));
    *(u16*)(base + t*256 + ((((c>>3) ^ (t&7)))<<4) + (c&7)*2) = f2b(Wq[c*384 + col]);
  }
  for (int e = threadIdx.x; e < 128*40; e += 256){
    int o = e / 40, d = e - o*40;
    *(u16*)(base + 24576 + (o*40 + d)*2) = (d < 32) ? f2b(Wom[(h*32 + d)*128 + o]) : (u16)0;
  }
}

template<int PHASE, int WSOK>
__launch_bounds__(1024)
__global__ void stage_kernel(const float* __restrict__ pin, const float* __restrict__ colmat,
                             const float* __restrict__ singlerow,
                             const int* __restrict__ mask, const float* __restrict__ dist,
                             const u16* __restrict__ biasimg,
                             const u16* __restrict__ wimg,
                             const float* __restrict__ Wqkv, const float* __restrict__ bqkv,
                             const float* __restrict__ Wo, const float* __restrict__ bo,
                             const float* __restrict__ dscale,
                             const float* __restrict__ lng, const float* __restrict__ lnb,
                             float* __restrict__ outp)
{
  extern __shared__ char smem[];
  char* Xs  = smem + XS_OFF;
  char* WTs = smem + WT_OFF;
  char* WOs = smem + WO_OFF;
  char* KBs = smem + KB_OFF;
  char* VTs = smem + VT_OFF;
  float* SVs = (float*)(smem + SV_OFF);
  float* GBs = (float*)(smem + GB_OFF);
  float* BQs = (float*)(smem + BQ_OFF);
  float* RSs = (float*)(smem + RS_OFF);

  const int i = blockIdx.x;
  const int tid = threadIdx.x;
  const int lid = tid & 63;
  const int w = tid >> 6;            // 16 waves; wave owns query rows w*16..w*16+15
  const int l15 = lid & 15;
  const int l4  = lid >> 4;
  const int h32 = lid >> 5;
  const int c4  = (lid & 31) * 4;
  const float* prow = pin + (size_t)i*NN*CC;
  float* orow = outp + (size_t)i*NN*CC;
  const int qglob = w*16 + l15;
  const float dsc = dscale[0] * LOG2E;

  // issue W(head 0) staging immediately (lands during LN phase)
  if (WSOK){
    const char* wb = (const char*)wimg;
    gload16(wb + tid*16, WTs + tid*16);
    if (tid < 512) gload16(wb + 16384 + tid*16, WTs + 16384 + tid*16);
    if (tid < 640) gload16(wb + 24576 + tid*16, WOs + tid*16);
  }
  if (tid < 128){ GBs[tid] = lng[tid]; GBs[128+tid] = lnb[tid]; GBs[256+tid] = bo[tid]; }
  if (tid >= 512 && tid < 896) BQs[tid-512] = bqkv[tid-512];

  // ---- LN1 -> X (bf16 swizzled); phase 0 fuses the s_out prefix ----
  if (PHASE == 0){
    f32x4 svp = {0.f,0.f,0.f,0.f};
    #pragma unroll 4
    for (int p = 0; p < 8; ++p){
      int r = w*16 + p*2 + h32;
      f32x4 pr4 = __builtin_nontemporal_load((const f32x4*)(prow + r*CC + c4));
      f32x4 sg4 = *(const f32x4*)(colmat + r*CC + c4);
      f32x4 t = pr4 + sg4;
      u32x2 pk2; pk2.x = cvtpk(t[0], t[1]); pk2.y = cvtpk(t[2], t[3]);
      *(u32x2*)(Xs + XBYTE(r, c4)) = pk2;
      if (r < i) svp += pr4;
    }
    #pragma unroll
    for (int q = 0; q < 4; ++q) svp[q] += __shfl_xor(svp[q], 32);
    if (h32 == 0) *(f32x4*)(RSs + w*128 + c4) = svp;
    __syncthreads();
    if (tid < 128){
      float s = 0.f;
      #pragma unroll
      for (int ww = 0; ww < 16; ++ww) s += RSs[ww*128 + tid];
      SVs[tid] = s;
    }
    __syncthreads();
    f32x4 sv4 = *(const f32x4*)(SVs + c4);
    f32x4 g4  = *(const f32x4*)(GBs + c4);
    f32x4 b4  = *(const f32x4*)(GBs + 128 + c4);
    #pragma unroll 2
    for (int p = 0; p < 8; ++p){
      int r = w*16 + p*2 + h32;
      u32x2 st = *(const u32x2*)(Xs + XBYTE(r, c4));
      float t0,t1,t2,t3;
      unpk(st.x, t0, t1); unpk(st.y, t2, t3);
      t0 += sv4[0]; t1 += sv4[1]; t2 += sv4[2]; t3 += sv4[3];
      float s = (t0+t1)+(t2+t3);
      float q2 = (t0*t0+t1*t1)+(t2*t2+t3*t3);
      #pragma unroll
      for (int ms = 1; ms < 32; ms <<= 1){ s += __shfl_xor(s, ms); q2 += __shfl_xor(q2, ms); }
      float mean = s*(1.f/CC);
      float var  = fmaxf(q2*(1.f/CC) - mean*mean, 0.f);
      float rstd = rsqrtf(var + EPSV);
      float y0 = (t0-mean)*rstd*g4[0] + b4[0];
      float y1 = (t1-mean)*rstd*g4[1] + b4[1];
      float y2 = (t2-mean)*rstd*g4[2] + b4[2];
      float y3 = (t3-mean)*rstd*g4[3] + b4[3];
      u32x2 pk2; pk2.x = cvtpk(y0, y1); pk2.y = cvtpk(y2, y3);
      *(u32x2*)(Xs + XBYTE(r, c4)) = pk2;
    }
  } else {
    if (tid < 128) SVs[tid] = singlerow[i*CC + tid];
    __syncthreads();
    f32x4 sv4 = *(const f32x4*)(SVs + c4);
    f32x4 g4  = *(const f32x4*)(GBs + c4);
    f32x4 b4  = *(const f32x4*)(GBs + 128 + c4);
    #pragma unroll 4
    for (int p = 0; p < 8; ++p){
      int r = w*16 + p*2 + h32;
      f32x4 pr4 = __builtin_nontemporal_load((const f32x4*)(prow + r*CC + c4));
      f32x4 cm4 = *(const f32x4*)(colmat + r*CC + c4);
      float t0 = pr4[0]+cm4[0]+sv4[0], t1 = pr4[1]+cm4[1]+sv4[1];
      float t2 = pr4[2]+cm4[2]+sv4[2], t3 = pr4[3]+cm4[3]+sv4[3];
      float s = (t0+t1)+(t2+t3);
      float q2 = (t0*t0+t1*t1)+(t2*t2+t3*t3);
      #pragma unroll
      for (int ms = 1; ms < 32; ms <<= 1){ s += __shfl_xor(s, ms); q2 += __shfl_xor(q2, ms); }
      float mean = s*(1.f/CC);
      float var  = fmaxf(q2*(1.f/CC) - mean*mean, 0.f);
      float rstd = rsqrtf(var + EPSV);
      float y0 = (t0-mean)*rstd*g4[0] + b4[0];
      float y1 = (t1-mean)*rstd*g4[1] + b4[1];
      float y2 = (t2-mean)*rstd*g4[2] + b4[2];
      float y3 = (t3-mean)*rstd*g4[3] + b4[3];
      u32x2 pk2; pk2.x = cvtpk(y0, y1); pk2.y = cvtpk(y2, y3);
      *(u32x2*)(Xs + XBYTE(r, c4)) = pk2;
    }
  }
  if (WSOK) asm volatile("s_waitcnt vmcnt(0)" ::: "memory");
  __syncthreads();   // X ready; W(0) staged

  f32x4 pa[8];
  #pragma unroll
  for (int ct = 0; ct < 8; ++ct) pa[ct] = f32x4{0.f,0.f,0.f,0.f};

  for (int h = 0; h < 4; ++h){
    if (!WSOK){
      #pragma unroll
      for (int it = 0; it < 12; ++it){
        int e = tid + it*1024;
        int c = e & 127, t = e >> 7;
        int col = (t < 32) ? (h*32 + t) : (t < 64) ? (CC + h*32 + (t-32)) : (2*CC + h*32 + (t-64));
        *(u16*)(WTs + t*256 + ((((c>>3) ^ (t&7)))<<4) + (c&7)*2) = f2b(Wqkv[c*384 + col]);
      }
      #pragma unroll
      for (int it = 0; it < 4; ++it){
        int e = tid + it*1024;
        int d = e >> 7, o = e & 127;
        *(u16*)(WOs + (h&1)*10240 + (o*40 + d)*2) = (d < 32) ? f2b(Wo[(h*32 + d)*128 + o]) : (u16)0;
      }
      __syncthreads();
    }

    // ---- QKV GEMM: Q^T and V^T via W-as-A (swapped); K direct ----
    f32x4 qa[2], ka[2], va[2];
    #pragma unroll
    for (int dt = 0; dt < 2; ++dt)
      #pragma unroll
      for (int v = 0; v < 4; ++v){
        qa[dt][v] = BQs[h*32 + dt*16 + l4*4 + v];
        va[dt][v] = BQs[256 + h*32 + dt*16 + l4*4 + v];
      }
    {
      float bk0 = BQs[128 + h*32 + l15], bk1 = BQs[128 + h*32 + 16 + l15];
      ka[0] = f32x4{bk0,bk0,bk0,bk0}; ka[1] = f32x4{bk1,bk1,bk1,bk1};
    }
    #pragma unroll
    for (int ks = 0; ks < 4; ++ks){
      int swb = (((ks*4 + l4) ^ (l15 & 7)) << 4);
      short8 a0  = *(const short8*)(Xs  + (w*16 + l15)*256 + swb);
      short8 wq0 = *(const short8*)(WTs + (l15)*256 + swb);
      short8 wq1 = *(const short8*)(WTs + (16 + l15)*256 + swb);
      short8 wk0 = *(const short8*)(WTs + (32 + l15)*256 + swb);
      short8 wk1 = *(const short8*)(WTs + (48 + l15)*256 + swb);
      short8 wv0 = *(const short8*)(WTs + (64 + l15)*256 + swb);
      short8 wv1 = *(const short8*)(WTs + (80 + l15)*256 + swb);
      qa[0] = MFMA(wq0, a0, qa[0]); qa[1] = MFMA(wq1, a0, qa[1]);
      ka[0] = MFMA(a0, wk0, ka[0]); ka[1] = MFMA(a0, wk1, ka[1]);
      va[0] = MFMA(wv0, a0, va[0]); va[1] = MFMA(wv1, a0, va[1]);
    }
    short8 qf = redist(qa[0]*QSCL, qa[1]*QSCL, l4);
    #pragma unroll
    for (int kt = 0; kt < 2; ++kt)
      #pragma unroll
      for (int v = 0; v < 4; ++v)
        *(u16*)(KBs + ((w*16 + l4*4 + v)*40 + kt*16 + l15)*2) = (u16)cvtpk(ka[kt][v], ka[kt][v]);
    #pragma unroll
    for (int dt = 0; dt < 2; ++dt)
      #pragma unroll
      for (int v = 0; v < 4; ++v)
        *(u16*)(VTs + ((dt*16 + l4*4 + v)*264 + w*16 + l15)*2) = (u16)cvtpk(va[dt][v], va[dt][v]);
    __syncthreads();   // K/VT visible; all WT reads done

    if (WSOK && h < 3){  // prefetch next head's weights under the flash phase
      const char* wb = (const char*)wimg + (h+1)*34816;
      gload16(wb + tid*16, WTs + tid*16);
      if (tid < 512) gload16(wb + 16384 + tid*16, WTs + 16384 + tid*16);
      if (tid < 640) gload16(wb + 24576 + tid*16, WOs + ((h+1)&1)*10240 + tid*16);
    }

    // ---- attention: full-row softmax in 2 halves of 128 keys ----
    float m = -3e38f, l = 0.f;
    f32x4 oacc0 = {0.f,0.f,0.f,0.f}, oacc1 = {0.f,0.f,0.f,0.f};
    #pragma unroll
    for (int hl = 0; hl < 2; ++hl){
      f32x4 sS[4][2];
      #pragma unroll
      for (int ci = 0; ci < 4; ++ci){
        int ch = hl*4 + ci;
        short8 kf0 = *(const short8*)(KBs + (ch*32 + l15)*80 + l4*16);
        short8 kf1 = *(const short8*)(KBs + (ch*32 + 16 + l15)*80 + l4*16);
        f32x4 z = {0.f,0.f,0.f,0.f};
        sS[ci][0] = MFMA(kf0, qf, z);
        sS[ci][1] = MFMA(kf1, qf, z);
      }
      if (WSOK){
        const u16* bb = biasimg + qglob*256 + l4*64 + hl*32;
        #pragma unroll
        for (int ci = 0; ci < 4; ++ci){
          uint4 bw = *(const uint4*)(bb + ci*8);
          float b00,b01,b02,b03,b10,b11,b12,b13;
          unpk(bw.x, b00, b01); unpk(bw.y, b02, b03);
          unpk(bw.z, b10, b11); unpk(bw.w, b12, b13);
          sS[ci][0][0]+=b00; sS[ci][0][1]+=b01; sS[ci][0][2]+=b02; sS[ci][0][3]+=b03;
          sS[ci][1][0]+=b10; sS[ci][1][1]+=b11; sS[ci][1][2]+=b12; sS[ci][1][3]+=b13;
        }
      } else {
        #pragma unroll
        for (int ci = 0; ci < 4; ++ci)
          #pragma unroll
          for (int kt = 0; kt < 2; ++kt)
            #pragma unroll
            for (int v = 0; v < 4; ++v){
              int key = (hl*4 + ci)*32 + kt*16 + l4*4 + v;
              int mq = (PHASE==0) ? mask[qglob*NN + key] : mask[key*NN + qglob];
              sS[ci][kt][v] += mq ? NEGBIG : dsc*dist[qglob*NN + key];
            }
      }
      float mc0 = fmaxf(fmaxf(fmaxf(sS[0][0][0],sS[0][0][1]),fmaxf(sS[0][0][2],sS[0][0][3])),
                        fmaxf(fmaxf(sS[0][1][0],sS[0][1][1]),fmaxf(sS[0][1][2],sS[0][1][3])));
      float mc1 = fmaxf(fmaxf(fmaxf(sS[1][0][0],sS[1][0][1]),fmaxf(sS[1][0][2],sS[1][0][3])),
                        fmaxf(fmaxf(sS[1][1][0],sS[1][1][1]),fmaxf(sS[1][1][2],sS[1][1][3])));
      float mc2 = fmaxf(fmaxf(fmaxf(sS[2][0][0],sS[2][0][1]),fmaxf(sS[2][0][2],sS[2][0][3])),
                        fmaxf(fmaxf(sS[2][1][0],sS[2][1][1]),fmaxf(sS[2][1][2],sS[2][1][3])));
      float mc3 = fmaxf(fmaxf(fmaxf(sS[3][0][0],sS[3][0][1]),fmaxf(sS[3][0][2],sS[3][0][3])),
                        fmaxf(fmaxf(sS[3][1][0],sS[3][1][1]),fmaxf(sS[3][1][2],sS[3][1][3])));
      float mx = fmaxf(fmaxf(mc0,mc1), fmaxf(mc2,mc3));
      mx = fmaxf(mx, __shfl_xor(mx, 16));
      mx = fmaxf(mx, __shfl_xor(mx, 32));
      float mn = fmaxf(m, mx);
      float corr = EXP2(m - mn);
      m = mn;
      float ps = 0.f;
      #pragma unroll
      for (int ci = 0; ci < 4; ++ci){
        float p0=0.f, p1=0.f;
        #pragma unroll
        for (int v = 0; v < 4; ++v){
          sS[ci][0][v] = EXP2(sS[ci][0][v] - m); p0 += sS[ci][0][v];
          sS[ci][1][v] = EXP2(sS[ci][1][v] - m); p1 += sS[ci][1][v];
        }
        ps += p0 + p1;
      }
      ps += __shfl_xor(ps, 16);
      ps += __shfl_xor(ps, 32);
      l = l*corr + ps;
      oacc0 *= corr; oacc1 *= corr;
      #pragma unroll
      for (int ci = 0; ci < 4; ++ci){
        int ch = hl*4 + ci;
        short8 pf = redist(sS[ci][0], sS[ci][1], l4);
        short8 vt0 = *(const short8*)(VTs + (l15)*528 + ch*64 + l4*16);
        short8 vt1 = *(const short8*)(VTs + (16 + l15)*528 + ch*64 + l4*16);
        oacc0 = MFMA(vt0, pf, oacc0);
        oacc1 = MFMA(vt1, pf, oacc1);
      }
    }
    // ---- O normalize + in-reg redistribute + fuse O_h @ Wo_h ----
    {
      float inv = 1.f / l;
      short8 oA = redist(oacc0*inv, oacc1*inv, l4);
      const char* wob = WOs + (h&1)*10240;
      #pragma unroll
      for (int ct = 0; ct < 8; ++ct){
        short8 wB = *(const short8*)(wob + (ct*16 + l15)*80 + l4*16);
        pa[ct] = MFMA(oA, wB, pa[ct]);
      }
    }
    if (WSOK && h < 3) asm volatile("s_waitcnt vmcnt(0)" ::: "memory");
    __syncthreads();   // flash reads of K/VT done; W(h+1) landed in all waves
  }

  // ---- epilogue: residual + bo + LN2 + plain coalesced write ----
  float mrs[4], mrq[4];
  #pragma unroll
  for (int v = 0; v < 4; ++v){ mrs[v] = 0.f; mrq[v] = 0.f; }
  #pragma unroll
  for (int ct = 0; ct < 8; ++ct)
    #pragma unroll
    for (int v = 0; v < 4; ++v){
      int o = ct*16 + l15;
      int r = w*16 + l4*4 + v;
      float xv = b2f(*(const u16*)(Xs + XBYTE(r, o)));
      float t = pa[ct][v] + GBs[256 + o] + xv;
      pa[ct][v] = t;
      mrs[v] += t; mrq[v] += t*t;
    }
  #pragma unroll
  for (int v = 0; v < 4; ++v){
    #pragma unroll
    for (int ms = 1; ms < 16; ms <<= 1){
      mrs[v] += __shfl_xor(mrs[v], ms);
      mrq[v] += __shfl_xor(mrq[v], ms);
    }
    float mean = mrs[v]*(1.f/CC);
    float var  = fmaxf(mrq[v]*(1.f/CC) - mean*mean, 0.f);
    mrs[v] = mean;
    mrq[v] = rsqrtf(var + EPSV);
  }
  #pragma unroll
  for (int ct = 0; ct < 8; ++ct)
    #pragma unroll
    for (int v = 0; v < 4; ++v){
      int o = ct*16 + l15;
      int r = w*16 + l4*4 + v;
      orow[r*CC + o] = (pa[ct][v] - mrs[v])*mrq[v]*GBs[o] + GBs[128+o];
    }
}

// s_in[j][c] = sum_{k<j} pr[k][j][c]
__launch_bounds__(1024)
__global__ void colprefix_kernel(const float* __restrict__ pr, float* __restrict__ s_in){
  __shared__ float red[1024];
  int j = blockIdx.x;
  int c = threadIdx.x & 127, part = threadIdx.x >> 7;
  float acc = 0.f;
  for (int k = part; k < j; k += 8)
    acc += __builtin_nontemporal_load(pr + (size_t)k*NN*CC + j*CC + c);
  red[threadIdx.x] = acc;
  __syncthreads();
  if (threadIdx.x < 128){
    float s = 0.f;
    #pragma unroll
    for (int p = 0; p < 8; ++p) s += red[p*128 + threadIdx.x];
    s_in[j*CC + threadIdx.x] = s;
  }
}

__launch_bounds__(128)
__global__ void single_kernel(const float* __restrict__ single,
                              const float* __restrict__ W1, const float* __restrict__ b1,
                              const float* __restrict__ W2, const float* __restrict__ b2,
                              const float* __restrict__ g, const float* __restrict__ bb,
                              float* __restrict__ sr){
  __shared__ float srow[128];
  __shared__ float sh1[256];
  __shared__ float red[4];
  int jr = blockIdx.x, t = threadIdx.x;
  srow[t] = single[jr*CC + t];
  __syncthreads();
  float a0 = b1[t], a1 = b1[t+128];
  for (int c = 0; c < 128; ++c){
    float s = srow[c];
    a0 += s * W1[c*256 + t];
    a1 += s * W1[c*256 + t + 128];
  }
  sh1[t] = fmaxf(a0, 0.f);
  sh1[t+128] = fmaxf(a1, 0.f);
  __syncthreads();
  float acc = b2[t];
  for (int o = 0; o < 256; ++o) acc += sh1[o] * W2[o*CC + t];
  acc = fmaxf(acc, 0.f);
  float tv = srow[t] + acc;
  float s = tv, q = tv*tv;
  #pragma unroll
  for (int mm = 32; mm; mm >>= 1){ s += __shfl_xor(s, mm); q += __shfl_xor(q, mm); }
  int w = t >> 6;
  if ((t & 63) == 0){ red[w] = s; red[2+w] = q; }
  __syncthreads();
  float S = red[0] + red[1], Q = red[2] + red[3];
  float mean = S*(1.f/CC);
  float var = fmaxf(Q*(1.f/CC) - mean*mean, 0.f);
  float rs = rsqrtf(var + EPSV);
  sr[jr*CC + t] = (tv - mean)*rs*g[t] + bb[t];
}

extern "C" void kernel_launch(void* const* d_in, const int* in_sizes, int n_in,
                              void* d_out, int out_size, void* d_ws, size_t ws_size,
                              hipStream_t stream) {
  const float* pair   = (const float*)d_in[0];
  const float* single = (const float*)d_in[1];
  const int*   mask   = (const int*)d_in[2];
  const float* dist   = (const float*)d_in[3];
  const float* rWqkv  = (const float*)d_in[4];
  const float* rbqkv  = (const float*)d_in[5];
  const float* rWo    = (const float*)d_in[6];
  const float* rbo    = (const float*)d_in[7];
  const float* rdsc   = (const float*)d_in[8];
  const float* cWqkv  = (const float*)d_in[9];
  const float* cbqkv  = (const float*)d_in[10];
  const float* cWo    = (const float*)d_in[11];
  const float* cbo    = (const float*)d_in[12];
  const float* cdsc   = (const float*)d_in[13];
  const float* pnr_g  = (const float*)d_in[14];
  const float* pnr_b  = (const float*)d_in[15];
  const float* pnc_g  = (const float*)d_in[16];
  const float* pnc_b  = (const float*)d_in[17];
  const float* sn_g   = (const float*)d_in[18];
  const float* sn_b   = (const float*)d_in[19];
  const float* W1     = (const float*)d_in[20];
  const float* b1     = (const float*)d_in[21];
  const float* W2     = (const float*)d_in[22];
  const float* b2     = (const float*)d_in[23];

  float* outp = (float*)d_out;
  float* pr   = outp;
  float* srr  = outp + (size_t)NN*NN*CC;

  const bool usews = ws_size >= (size_t)WS_NEED;
  char* wsb = (char*)d_ws;
  u16* bias0 = (u16*)(wsb + WS_B0);
  u16* bias1 = (u16*)(wsb + WS_B1);
  u16* wimg0 = (u16*)(wsb + WS_W0);
  u16* wimg1 = (u16*)(wsb + WS_W1);
  float* s_in = usews ? (float*)(wsb + WS_SIN) : srr;

  if (usews){
    (void)hipFuncSetAttribute(reinterpret_cast<const void*>(stage_kernel<0,1>),
                              hipFuncAttributeMaxDynamicSharedMemorySize, SMEM_BYTES);
    (void)hipFuncSetAttribute(reinterpret_cast<const void*>(stage_kernel<1,1>),
                              hipFuncAttributeMaxDynamicSharedMemorySize, SMEM_BYTES);
    prep_bias<<<NN, NN, 0, stream>>>(mask, dist, rdsc, cdsc, bias0, bias1);
    prep_wimg<<<8, 256, 0, stream>>>(rWqkv, rWo, cWqkv, cWo, wimg0, wimg1);
    stage_kernel<0,1><<<NN, 1024, SMEM_BYTES, stream>>>(pair, single, single, mask, dist,
        bias0, wimg0, rWqkv, rbqkv, rWo, rbo, rdsc, pnr_g, pnr_b, pr);
    colprefix_kernel<<<NN, 1024, 0, stream>>>(pr, s_in);
    stage_kernel<1,1><<<NN, 1024, SMEM_BYTES, stream>>>(pr, s_in, single, mask, dist,
        bias1, wimg1, cWqkv, cbqkv, cWo, cbo, cdsc, pnc_g, pnc_b, pr);
  } else {
    (void)hipFuncSetAttribute(reinterpret_cast<const void*>(stage_kernel<0,0>),
                              hipFuncAttributeMaxDynamicSharedMemorySize, SMEM_BYTES);
    (void)hipFuncSetAttribute(reinterpret_cast<const void*>(stage_kernel<1,0>),
                              hipFuncAttributeMaxDynamicSharedMemorySize, SMEM_BYTES);
    stage_kernel<0,0><<<NN, 1024, SMEM_BYTES, stream>>>(pair, single, single, mask, dist,
        nullptr, nullptr, rWqkv, rbqkv, rWo, rbo, rdsc, pnr_g, pnr_b, pr);
    colprefix_kernel<<<NN, 1024, 0, stream>>>(pr, s_in);
    stage_kernel<1,0><<<NN, 1024, SMEM_BYTES, stream>>>(pr, s_in, single, mask, dist,
        nullptr, nullptr, cWqkv, cbqkv, cWo, cbo, cdsc, pnc_g, pnc_b, pr);
  }
  single_kernel<<<NN, CC, 0, stream>>>(single, W1, b1, W2, b2, sn_g, sn_b, srr);
}

// Round 10
// 273.918 us; speedup vs baseline: 6.4964x; 1.0043x over previous
//
#include <hip/hip_runtime.h>
#include <math.h>

typedef unsigned int u32;
typedef unsigned short u16;
typedef __attribute__((ext_vector_type(8))) short short8;   // 8 bf16 in 4 VGPRs
typedef __attribute__((ext_vector_type(4))) float f32x4;
typedef __attribute__((ext_vector_type(2))) u32 u32x2;

#define NN 256
#define CC 128
#define EPSV 1e-5f
#define LOG2E 1.44269504088896f
#define QSCL (0.17677669529663687f * 1.44269504088896f)   // 1/sqrt(32) * log2(e)
#define NEGBIG -1e30f

#define MFMA(a,b,c) __builtin_amdgcn_mfma_f32_16x16x32_bf16(a,b,c,0,0,0)
#define EXP2(x) __builtin_amdgcn_exp2f(x)

__device__ __forceinline__ float b2f(u16 u){ return __uint_as_float(((u32)u)<<16); }
__device__ __forceinline__ u16 f2b(float f){
  u32 x = __float_as_uint(f);
  return (u16)((x + 0x7fffu + ((x>>16)&1u)) >> 16);
}
__device__ __forceinline__ void unpk(u32 u, float&a, float&b){
  a = __uint_as_float(u<<16); b = __uint_as_float(u & 0xffff0000u);
}
__device__ __forceinline__ u32 cvtpk(float lo, float hi){
  u32 r;
  asm("v_cvt_pk_bf16_f32 %0, %1, %2" : "=v"(r) : "v"(lo), "v"(hi));
  return r;
}
__device__ __forceinline__ void gload16(const void* g, void* l){
  __builtin_amdgcn_global_load_lds((const __attribute__((address_space(1))) u32*)g,
                                   (__attribute__((address_space(3))) u32*)l, 16, 0, 0);
}

// redistribute 8 values (2 f32x4 tiles, idx = tile*16 + l4*4 + v at col l15) into
// A/B-frag short8 (lane l4 gets idx l4*8..l4*8+7 for its l15). Verified P-path algebra.
__device__ __forceinline__ short8 redist(f32x4 t0, f32x4 t1, int l4){
  u32 A0 = cvtpk(t0[0], t0[1]), A1 = cvtpk(t0[2], t0[3]);
  u32 B0 = cvtpk(t1[0], t1[1]), B1 = cvtpk(t1[2], t1[3]);
  asm volatile("v_permlane32_swap_b32 %0, %1" : "+v"(A0), "+v"(B0));
  asm volatile("v_permlane32_swap_b32 %0, %1" : "+v"(A1), "+v"(B1));
  u32 sA0 = __shfl_xor(A0, 16), sA1 = __shfl_xor(A1, 16);
  u32 sB0 = __shfl_xor(B0, 16), sB1 = __shfl_xor(B1, 16);
  bool eg = ((l4 & 1) == 0);
  union { u32 u[4]; short8 s; } pu;
  pu.u[0] = eg ? A0 : sB0;
  pu.u[1] = eg ? A1 : sB1;
  pu.u[2] = eg ? sA0 : B0;
  pu.u[3] = eg ? sA1 : B1;
  return pu.s;
}

// ---- LDS layout (bytes) ----
#define XS_OFF   0        // bf16 X[256][128] swizzled                  (65536)
#define WT_OFF   65536    // bf16 Wt[96][128] head slice, swizzled      (24576)
#define WO_OFF   90112    // bf16 Woh dbuf [2][128][40]                 (20480)
#define KB_OFF   110592   // bf16 K[256][40]                            (20480)
#define VT_OFF   131072   // bf16 Vt[32][264]                           (16896)
#define SV_OFF   147968   // f32 sv[128]                                (512)
#define GB_OFF   148480   // f32 g[128], b[128], bo[128]                (1536)
#define BQ_OFF   150016   // f32 bqkv[384]                              (1536)
#define RS_OFF   151552   // f32 red[16][128] (phase-0 scratch)         (8192)
#define SMEM_BYTES 159744

#define XBYTE(r,c) ((r)*256 + (((((c)>>3)) ^ ((r)&7))<<4) + ((c)&7)*2)

// ws layout (bytes)
#define WS_B0   0          // bias img phase0 (131072)
#define WS_B1   131072     // bias img phase1 (131072)
#define WS_W0   262144     // W img stage0 (139264 = 4 heads x (24576 WT + 10240 WO))
#define WS_W1   401408     // W img stage1 (139264)
#define WS_SIN  540672     // s_in f32 (131072)
#define WS_NEED 671744

// bias image, per-lane-consumed layout: u16 addr = q*256 + l4*64 + ch*8 + kt*4 + v
__global__ void prep_bias(const int* __restrict__ mask, const float* __restrict__ dist,
                          const float* __restrict__ rd, const float* __restrict__ cd,
                          u16* __restrict__ b0, u16* __restrict__ b1){
  int q = blockIdx.x, k = threadIdx.x;
  int l4 = (k >> 2) & 3, v = k & 3, kt = (k >> 4) & 1, ch = k >> 5;
  int addr = q*256 + l4*64 + ch*8 + kt*4 + v;
  float dv = dist[q*NN + k];
  b0[addr] = mask[q*NN + k] ? f2b(NEGBIG) : f2b(rd[0]*LOG2E*dv);
  b1[addr] = mask[k*NN + q] ? f2b(NEGBIG) : f2b(cd[0]*LOG2E*dv);
}

// weight images: byte-exact copies of the LDS layouts (WT swizzled, WO padded)
__global__ void prep_wimg(const float* __restrict__ rWqkv, const float* __restrict__ rWo,
                          const float* __restrict__ cWqkv, const float* __restrict__ cWo,
                          u16* __restrict__ img0, u16* __restrict__ img1){
  int h = blockIdx.x & 3, s = blockIdx.x >> 2;
  const float* Wq = s ? cWqkv : rWqkv;
  const float* Wom = s ? cWo : rWo;
  char* base = (char*)(s ? img1 : img0) + h*34816;
  for (int e = threadIdx.x; e < 96*128; e += 256){
    int t = e >> 7, c = e & 127;
    int col = (t < 32) ? (h*32 + t) : (t < 64) ? (CC + h*32 + (t-32)) : (2*CC + h*32 + (t-64));
    *(u16*)(base + t*256 + ((((c>>3) ^ (t&7)))<<4) + (c&7)*2) = f2b(Wq[c*384 + col]);
  }
  for (int e = threadIdx.x; e < 128*40; e += 256){
    int o = e / 40, d = e - o*40;
    *(u16*)(base + 24576 + (o*40 + d)*2) = (d < 32) ? f2b(Wom[(h*32 + d)*128 + o]) : (u16)0;
  }
}

template<int PHASE, int WSOK>
__launch_bounds__(1024)
__global__ void stage_kernel(const float* __restrict__ pin, const float* __restrict__ colmat,
                             const float* __restrict__ singlerow,
                             const int* __restrict__ mask, const float* __restrict__ dist,
                             const u16* __restrict__ biasimg,
                             const u16* __restrict__ wimg,
                             const float* __restrict__ Wqkv, const float* __restrict__ bqkv,
                             const float* __restrict__ Wo, const float* __restrict__ bo,
                             const float* __restrict__ dscale,
                             const float* __restrict__ lng, const float* __restrict__ lnb,
                             float* __restrict__ outp)
{
  extern __shared__ char smem[];
  char* Xs  = smem + XS_OFF;
  char* WTs = smem + WT_OFF;
  char* WOs = smem + WO_OFF;
  char* KBs = smem + KB_OFF;
  char* VTs = smem + VT_OFF;
  float* SVs = (float*)(smem + SV_OFF);
  float* GBs = (float*)(smem + GB_OFF);
  float* BQs = (float*)(smem + BQ_OFF);
  float* RSs = (float*)(smem + RS_OFF);

  const int i = blockIdx.x;
  const int tid = threadIdx.x;
  const int lid = tid & 63;
  const int w = tid >> 6;            // 16 waves; wave owns query rows w*16..w*16+15
  const int l15 = lid & 15;
  const int l4  = lid >> 4;
  const int h32 = lid >> 5;
  const int c4  = (lid & 31) * 4;
  const float* prow = pin + (size_t)i*NN*CC;
  float* orow = outp + (size_t)i*NN*CC;
  const int qglob = w*16 + l15;
  const float dsc = dscale[0] * LOG2E;

  // issue W(head 0) staging immediately (lands during LN phase)
  if (WSOK){
    const char* wb = (const char*)wimg;
    gload16(wb + tid*16, WTs + tid*16);
    if (tid < 512) gload16(wb + 16384 + tid*16, WTs + 16384 + tid*16);
    if (tid < 640) gload16(wb + 24576 + tid*16, WOs + tid*16);
  }
  if (tid < 128){ GBs[tid] = lng[tid]; GBs[128+tid] = lnb[tid]; GBs[256+tid] = bo[tid]; }
  if (tid >= 512 && tid < 896) BQs[tid-512] = bqkv[tid-512];

  // ---- LN1 -> X (bf16 swizzled); phase 0 fuses the s_out prefix ----
  if (PHASE == 0){
    f32x4 svp = {0.f,0.f,0.f,0.f};
    #pragma unroll 4
    for (int p = 0; p < 8; ++p){
      int r = w*16 + p*2 + h32;
      f32x4 pr4 = *(const f32x4*)(prow + r*CC + c4);
      f32x4 sg4 = *(const f32x4*)(colmat + r*CC + c4);
      f32x4 t = pr4 + sg4;
      u32x2 pk2; pk2.x = cvtpk(t[0], t[1]); pk2.y = cvtpk(t[2], t[3]);
      *(u32x2*)(Xs + XBYTE(r, c4)) = pk2;
      if (r < i) svp += pr4;
    }
    #pragma unroll
    for (int q = 0; q < 4; ++q) svp[q] += __shfl_xor(svp[q], 32);
    if (h32 == 0) *(f32x4*)(RSs + w*128 + c4) = svp;
    __syncthreads();
    if (tid < 128){
      float s = 0.f;
      #pragma unroll
      for (int ww = 0; ww < 16; ++ww) s += RSs[ww*128 + tid];
      SVs[tid] = s;
    }
    __syncthreads();
    f32x4 sv4 = *(const f32x4*)(SVs + c4);
    f32x4 g4  = *(const f32x4*)(GBs + c4);
    f32x4 b4  = *(const f32x4*)(GBs + 128 + c4);
    #pragma unroll 2
    for (int p = 0; p < 8; ++p){
      int r = w*16 + p*2 + h32;
      u32x2 st = *(const u32x2*)(Xs + XBYTE(r, c4));
      float t0,t1,t2,t3;
      unpk(st.x, t0, t1); unpk(st.y, t2, t3);
      t0 += sv4[0]; t1 += sv4[1]; t2 += sv4[2]; t3 += sv4[3];
      float s = (t0+t1)+(t2+t3);
      float q2 = (t0*t0+t1*t1)+(t2*t2+t3*t3);
      #pragma unroll
      for (int ms = 1; ms < 32; ms <<= 1){ s += __shfl_xor(s, ms); q2 += __shfl_xor(q2, ms); }
      float mean = s*(1.f/CC);
      float var  = fmaxf(q2*(1.f/CC) - mean*mean, 0.f);
      float rstd = rsqrtf(var + EPSV);
      float y0 = (t0-mean)*rstd*g4[0] + b4[0];
      float y1 = (t1-mean)*rstd*g4[1] + b4[1];
      float y2 = (t2-mean)*rstd*g4[2] + b4[2];
      float y3 = (t3-mean)*rstd*g4[3] + b4[3];
      u32x2 pk2; pk2.x = cvtpk(y0, y1); pk2.y = cvtpk(y2, y3);
      *(u32x2*)(Xs + XBYTE(r, c4)) = pk2;
    }
  } else {
    if (tid < 128) SVs[tid] = singlerow[i*CC + tid];
    __syncthreads();
    f32x4 sv4 = *(const f32x4*)(SVs + c4);
    f32x4 g4  = *(const f32x4*)(GBs + c4);
    f32x4 b4  = *(const f32x4*)(GBs + 128 + c4);
    #pragma unroll 4
    for (int p = 0; p < 8; ++p){
      int r = w*16 + p*2 + h32;
      f32x4 pr4 = *(const f32x4*)(prow + r*CC + c4);
      f32x4 cm4 = *(const f32x4*)(colmat + r*CC + c4);
      float t0 = pr4[0]+cm4[0]+sv4[0], t1 = pr4[1]+cm4[1]+sv4[1];
      float t2 = pr4[2]+cm4[2]+sv4[2], t3 = pr4[3]+cm4[3]+sv4[3];
      float s = (t0+t1)+(t2+t3);
      float q2 = (t0*t0+t1*t1)+(t2*t2+t3*t3);
      #pragma unroll
      for (int ms = 1; ms < 32; ms <<= 1){ s += __shfl_xor(s, ms); q2 += __shfl_xor(q2, ms); }
      float mean = s*(1.f/CC);
      float var  = fmaxf(q2*(1.f/CC) - mean*mean, 0.f);
      float rstd = rsqrtf(var + EPSV);
      float y0 = (t0-mean)*rstd*g4[0] + b4[0];
      float y1 = (t1-mean)*rstd*g4[1] + b4[1];
      float y2 = (t2-mean)*rstd*g4[2] + b4[2];
      float y3 = (t3-mean)*rstd*g4[3] + b4[3];
      u32x2 pk2; pk2.x = cvtpk(y0, y1); pk2.y = cvtpk(y2, y3);
      *(u32x2*)(Xs + XBYTE(r, c4)) = pk2;
    }
  }
  if (WSOK) asm volatile("s_waitcnt vmcnt(0)" ::: "memory");
  __syncthreads();   // X ready; W(0) staged

  f32x4 pa[8];
  #pragma unroll
  for (int ct = 0; ct < 8; ++ct) pa[ct] = f32x4{0.f,0.f,0.f,0.f};

  for (int h = 0; h < 4; ++h){
    if (!WSOK){
      #pragma unroll
      for (int it = 0; it < 12; ++it){
        int e = tid + it*1024;
        int c = e & 127, t = e >> 7;
        int col = (t < 32) ? (h*32 + t) : (t < 64) ? (CC + h*32 + (t-32)) : (2*CC + h*32 + (t-64));
        *(u16*)(WTs + t*256 + ((((c>>3) ^ (t&7)))<<4) + (c&7)*2) = f2b(Wqkv[c*384 + col]);
      }
      #pragma unroll
      for (int it = 0; it < 4; ++it){
        int e = tid + it*1024;
        int d = e >> 7, o = e & 127;
        *(u16*)(WOs + (h&1)*10240 + (o*40 + d)*2) = (d < 32) ? f2b(Wo[(h*32 + d)*128 + o]) : (u16)0;
      }
      __syncthreads();
    }

    // ---- QKV GEMM: Q^T and V^T via W-as-A (swapped); K direct ----
    f32x4 qa[2], ka[2], va[2];
    #pragma unroll
    for (int dt = 0; dt < 2; ++dt)
      #pragma unroll
      for (int v = 0; v < 4; ++v){
        qa[dt][v] = BQs[h*32 + dt*16 + l4*4 + v];
        va[dt][v] = BQs[256 + h*32 + dt*16 + l4*4 + v];
      }
    {
      float bk0 = BQs[128 + h*32 + l15], bk1 = BQs[128 + h*32 + 16 + l15];
      ka[0] = f32x4{bk0,bk0,bk0,bk0}; ka[1] = f32x4{bk1,bk1,bk1,bk1};
    }
    #pragma unroll
    for (int ks = 0; ks < 4; ++ks){
      int swb = (((ks*4 + l4) ^ (l15 & 7)) << 4);
      short8 a0  = *(const short8*)(Xs  + (w*16 + l15)*256 + swb);
      short8 wq0 = *(const short8*)(WTs + (l15)*256 + swb);
      short8 wq1 = *(const short8*)(WTs + (16 + l15)*256 + swb);
      short8 wk0 = *(const short8*)(WTs + (32 + l15)*256 + swb);
      short8 wk1 = *(const short8*)(WTs + (48 + l15)*256 + swb);
      short8 wv0 = *(const short8*)(WTs + (64 + l15)*256 + swb);
      short8 wv1 = *(const short8*)(WTs + (80 + l15)*256 + swb);
      qa[0] = MFMA(wq0, a0, qa[0]); qa[1] = MFMA(wq1, a0, qa[1]);
      ka[0] = MFMA(a0, wk0, ka[0]); ka[1] = MFMA(a0, wk1, ka[1]);
      va[0] = MFMA(wv0, a0, va[0]); va[1] = MFMA(wv1, a0, va[1]);
    }
    short8 qf = redist(qa[0]*QSCL, qa[1]*QSCL, l4);
    #pragma unroll
    for (int kt = 0; kt < 2; ++kt)
      #pragma unroll
      for (int v = 0; v < 4; ++v)
        *(u16*)(KBs + ((w*16 + l4*4 + v)*40 + kt*16 + l15)*2) = (u16)cvtpk(ka[kt][v], ka[kt][v]);
    #pragma unroll
    for (int dt = 0; dt < 2; ++dt)
      #pragma unroll
      for (int v = 0; v < 4; ++v)
        *(u16*)(VTs + ((dt*16 + l4*4 + v)*264 + w*16 + l15)*2) = (u16)cvtpk(va[dt][v], va[dt][v]);
    __syncthreads();   // K/VT visible; all WT reads done

    if (WSOK && h < 3){  // prefetch next head's weights under the flash phase
      const char* wb = (const char*)wimg + (h+1)*34816;
      gload16(wb + tid*16, WTs + tid*16);
      if (tid < 512) gload16(wb + 16384 + tid*16, WTs + 16384 + tid*16);
      if (tid < 640) gload16(wb + 24576 + tid*16, WOs + ((h+1)&1)*10240 + tid*16);
    }

    __builtin_amdgcn_s_setprio(1);
    // ---- attention: full-row softmax in 2 halves of 128 keys ----
    float m = -3e38f, l = 0.f;
    f32x4 oacc0 = {0.f,0.f,0.f,0.f}, oacc1 = {0.f,0.f,0.f,0.f};
    #pragma unroll
    for (int hl = 0; hl < 2; ++hl){
      f32x4 sS[4][2];
      #pragma unroll
      for (int ci = 0; ci < 4; ++ci){
        int ch = hl*4 + ci;
        short8 kf0 = *(const short8*)(KBs + (ch*32 + l15)*80 + l4*16);
        short8 kf1 = *(const short8*)(KBs + (ch*32 + 16 + l15)*80 + l4*16);
        f32x4 z = {0.f,0.f,0.f,0.f};
        sS[ci][0] = MFMA(kf0, qf, z);
        sS[ci][1] = MFMA(kf1, qf, z);
      }
      if (WSOK){
        const u16* bb = biasimg + qglob*256 + l4*64 + hl*32;
        #pragma unroll
        for (int ci = 0; ci < 4; ++ci){
          uint4 bw = *(const uint4*)(bb + ci*8);
          float b00,b01,b02,b03,b10,b11,b12,b13;
          unpk(bw.x, b00, b01); unpk(bw.y, b02, b03);
          unpk(bw.z, b10, b11); unpk(bw.w, b12, b13);
          sS[ci][0][0]+=b00; sS[ci][0][1]+=b01; sS[ci][0][2]+=b02; sS[ci][0][3]+=b03;
          sS[ci][1][0]+=b10; sS[ci][1][1]+=b11; sS[ci][1][2]+=b12; sS[ci][1][3]+=b13;
        }
      } else {
        #pragma unroll
        for (int ci = 0; ci < 4; ++ci)
          #pragma unroll
          for (int kt = 0; kt < 2; ++kt)
            #pragma unroll
            for (int v = 0; v < 4; ++v){
              int key = (hl*4 + ci)*32 + kt*16 + l4*4 + v;
              int mq = (PHASE==0) ? mask[qglob*NN + key] : mask[key*NN + qglob];
              sS[ci][kt][v] += mq ? NEGBIG : dsc*dist[qglob*NN + key];
            }
      }
      float mc0 = fmaxf(fmaxf(fmaxf(sS[0][0][0],sS[0][0][1]),fmaxf(sS[0][0][2],sS[0][0][3])),
                        fmaxf(fmaxf(sS[0][1][0],sS[0][1][1]),fmaxf(sS[0][1][2],sS[0][1][3])));
      float mc1 = fmaxf(fmaxf(fmaxf(sS[1][0][0],sS[1][0][1]),fmaxf(sS[1][0][2],sS[1][0][3])),
                        fmaxf(fmaxf(sS[1][1][0],sS[1][1][1]),fmaxf(sS[1][1][2],sS[1][1][3])));
      float mc2 = fmaxf(fmaxf(fmaxf(sS[2][0][0],sS[2][0][1]),fmaxf(sS[2][0][2],sS[2][0][3])),
                        fmaxf(fmaxf(sS[2][1][0],sS[2][1][1]),fmaxf(sS[2][1][2],sS[2][1][3])));
      float mc3 = fmaxf(fmaxf(fmaxf(sS[3][0][0],sS[3][0][1]),fmaxf(sS[3][0][2],sS[3][0][3])),
                        fmaxf(fmaxf(sS[3][1][0],sS[3][1][1]),fmaxf(sS[3][1][2],sS[3][1][3])));
      float mx = fmaxf(fmaxf(mc0,mc1), fmaxf(mc2,mc3));
      mx = fmaxf(mx, __shfl_xor(mx, 16));
      mx = fmaxf(mx, __shfl_xor(mx, 32));
      float mn = fmaxf(m, mx);
      float corr = EXP2(m - mn);
      m = mn;
      float ps = 0.f;
      #pragma unroll
      for (int ci = 0; ci < 4; ++ci){
        float p0=0.f, p1=0.f;
        #pragma unroll
        for (int v = 0; v < 4; ++v){
          sS[ci][0][v] = EXP2(sS[ci][0][v] - m); p0 += sS[ci][0][v];
          sS[ci][1][v] = EXP2(sS[ci][1][v] - m); p1 += sS[ci][1][v];
        }
        ps += p0 + p1;
      }
      ps += __shfl_xor(ps, 16);
      ps += __shfl_xor(ps, 32);
      l = l*corr + ps;
      oacc0 *= corr; oacc1 *= corr;
      #pragma unroll
      for (int ci = 0; ci < 4; ++ci){
        int ch = hl*4 + ci;
        short8 pf = redist(sS[ci][0], sS[ci][1], l4);
        short8 vt0 = *(const short8*)(VTs + (l15)*528 + ch*64 + l4*16);
        short8 vt1 = *(const short8*)(VTs + (16 + l15)*528 + ch*64 + l4*16);
        oacc0 = MFMA(vt0, pf, oacc0);
        oacc1 = MFMA(vt1, pf, oacc1);
      }
    }
    // ---- O normalize + in-reg redistribute + fuse O_h @ Wo_h ----
    {
      float inv = 1.f / l;
      short8 oA = redist(oacc0*inv, oacc1*inv, l4);
      const char* wob = WOs + (h&1)*10240;
      #pragma unroll
      for (int ct = 0; ct < 8; ++ct){
        short8 wB = *(const short8*)(wob + (ct*16 + l15)*80 + l4*16);
        pa[ct] = MFMA(oA, wB, pa[ct]);
      }
    }
    __builtin_amdgcn_s_setprio(0);
    if (WSOK && h < 3) asm volatile("s_waitcnt vmcnt(0)" ::: "memory");
    __syncthreads();   // flash reads of K/VT done; W(h+1) landed in all waves
  }

  // ---- epilogue: residual + bo + LN2 + plain coalesced write ----
  float mrs[4], mrq[4];
  #pragma unroll
  for (int v = 0; v < 4; ++v){ mrs[v] = 0.f; mrq[v] = 0.f; }
  #pragma unroll
  for (int ct = 0; ct < 8; ++ct)
    #pragma unroll
    for (int v = 0; v < 4; ++v){
      int o = ct*16 + l15;
      int r = w*16 + l4*4 + v;
      float xv = b2f(*(const u16*)(Xs + XBYTE(r, o)));
      float t = pa[ct][v] + GBs[256 + o] + xv;
      pa[ct][v] = t;
      mrs[v] += t; mrq[v] += t*t;
    }
  #pragma unroll
  for (int v = 0; v < 4; ++v){
    #pragma unroll
    for (int ms = 1; ms < 16; ms <<= 1){
      mrs[v] += __shfl_xor(mrs[v], ms);
      mrq[v] += __shfl_xor(mrq[v], ms);
    }
    float mean = mrs[v]*(1.f/CC);
    float var  = fmaxf(mrq[v]*(1.f/CC) - mean*mean, 0.f);
    mrs[v] = mean;
    mrq[v] = rsqrtf(var + EPSV);
  }
  #pragma unroll
  for (int ct = 0; ct < 8; ++ct)
    #pragma unroll
    for (int v = 0; v < 4; ++v){
      int o = ct*16 + l15;
      int r = w*16 + l4*4 + v;
      orow[r*CC + o] = (pa[ct][v] - mrs[v])*mrq[v]*GBs[o] + GBs[128+o];
    }
}

// s_in[j][c] = sum_{k<j} pr[k][j][c]
__launch_bounds__(1024)
__global__ void colprefix_kernel(const float* __restrict__ pr, float* __restrict__ s_in){
  __shared__ float red[1024];
  int j = blockIdx.x;
  int c = threadIdx.x & 127, part = threadIdx.x >> 7;
  float acc = 0.f;
  for (int k = part; k < j; k += 8)
    acc += pr[(size_t)k*NN*CC + j*CC + c];
  red[threadIdx.x] = acc;
  __syncthreads();
  if (threadIdx.x < 128){
    float s = 0.f;
    #pragma unroll
    for (int p = 0; p < 8; ++p) s += red[p*128 + threadIdx.x];
    s_in[j*CC + threadIdx.x] = s;
  }
}

__launch_bounds__(128)
__global__ void single_kernel(const float* __restrict__ single,
                              const float* __restrict__ W1, const float* __restrict__ b1,
                              const float* __restrict__ W2, const float* __restrict__ b2,
                              const float* __restrict__ g, const float* __restrict__ bb,
                              float* __restrict__ sr){
  __shared__ float srow[128];
  __shared__ float sh1[256];
  __shared__ float red[4];
  int jr = blockIdx.x, t = threadIdx.x;
  srow[t] = single[jr*CC + t];
  __syncthreads();
  float a0 = b1[t], a1 = b1[t+128];
  for (int c = 0; c < 128; ++c){
    float s = srow[c];
    a0 += s * W1[c*256 + t];
    a1 += s * W1[c*256 + t + 128];
  }
  sh1[t] = fmaxf(a0, 0.f);
  sh1[t+128] = fmaxf(a1, 0.f);
  __syncthreads();
  float acc = b2[t];
  for (int o = 0; o < 256; ++o) acc += sh1[o] * W2[o*CC + t];
  acc = fmaxf(acc, 0.f);
  float tv = srow[t] + acc;
  float s = tv, q = tv*tv;
  #pragma unroll
  for (int mm = 32; mm; mm >>= 1){ s += __shfl_xor(s, mm); q += __shfl_xor(q, mm); }
  int w = t >> 6;
  if ((t & 63) == 0){ red[w] = s; red[2+w] = q; }
  __syncthreads();
  float S = red[0] + red[1], Q = red[2] + red[3];
  float mean = S*(1.f/CC);
  float var = fmaxf(Q*(1.f/CC) - mean*mean, 0.f);
  float rs = rsqrtf(var + EPSV);
  sr[jr*CC + t] = (tv - mean)*rs*g[t] + bb[t];
}

extern "C" void kernel_launch(void* const* d_in, const int* in_sizes, int n_in,
                              void* d_out, int out_size, void* d_ws, size_t ws_size,
                              hipStream_t stream) {
  const float* pair   = (const float*)d_in[0];
  const float* single = (const float*)d_in[1];
  const int*   mask   = (const int*)d_in[2];
  const float* dist   = (const float*)d_in[3];
  const float* rWqkv  = (const float*)d_in[4];
  const float* rbqkv  = (const float*)d_in[5];
  const float* rWo    = (const float*)d_in[6];
  const float* rbo    = (const float*)d_in[7];
  const float* rdsc   = (const float*)d_in[8];
  const float* cWqkv  = (const float*)d_in[9];
  const float* cbqkv  = (const float*)d_in[10];
  const float* cWo    = (const float*)d_in[11];
  const float* cbo    = (const float*)d_in[12];
  const float* cdsc   = (const float*)d_in[13];
  const float* pnr_g  = (const float*)d_in[14];
  const float* pnr_b  = (const float*)d_in[15];
  const float* pnc_g  = (const float*)d_in[16];
  const float* pnc_b  = (const float*)d_in[17];
  const float* sn_g   = (const float*)d_in[18];
  const float* sn_b   = (const float*)d_in[19];
  const float* W1     = (const float*)d_in[20];
  const float* b1     = (const float*)d_in[21];
  const float* W2     = (const float*)d_in[22];
  const float* b2     = (const float*)d_in[23];

  float* outp = (float*)d_out;
  float* pr   = outp;
  float* srr  = outp + (size_t)NN*NN*CC;

  const bool usews = ws_size >= (size_t)WS_NEED;
  char* wsb = (char*)d_ws;
  u16* bias0 = (u16*)(wsb + WS_B0);
  u16* bias1 = (u16*)(wsb + WS_B1);
  u16* wimg0 = (u16*)(wsb + WS_W0);
  u16* wimg1 = (u16*)(wsb + WS_W1);
  float* s_in = usews ? (float*)(wsb + WS_SIN) : srr;

  if (usews){
    (void)hipFuncSetAttribute(reinterpret_cast<const void*>(stage_kernel<0,1>),
                              hipFuncAttributeMaxDynamicSharedMemorySize, SMEM_BYTES);
    (void)hipFuncSetAttribute(reinterpret_cast<const void*>(stage_kernel<1,1>),
                              hipFuncAttributeMaxDynamicSharedMemorySize, SMEM_BYTES);
    prep_bias<<<NN, NN, 0, stream>>>(mask, dist, rdsc, cdsc, bias0, bias1);
    prep_wimg<<<8, 256, 0, stream>>>(rWqkv, rWo, cWqkv, cWo, wimg0, wimg1);
    stage_kernel<0,1><<<NN, 1024, SMEM_BYTES, stream>>>(pair, single, single, mask, dist,
        bias0, wimg0, rWqkv, rbqkv, rWo, rbo, rdsc, pnr_g, pnr_b, pr);
    colprefix_kernel<<<NN, 1024, 0, stream>>>(pr, s_in);
    stage_kernel<1,1><<<NN, 1024, SMEM_BYTES, stream>>>(pr, s_in, single, mask, dist,
        bias1, wimg1, cWqkv, cbqkv, cWo, cbo, cdsc, pnc_g, pnc_b, pr);
  } else {
    (void)hipFuncSetAttribute(reinterpret_cast<const void*>(stage_kernel<0,0>),
                              hipFuncAttributeMaxDynamicSharedMemorySize, SMEM_BYTES);
    (void)hipFuncSetAttribute(reinterpret_cast<const void*>(stage_kernel<1,0>),
                              hipFuncAttributeMaxDynamicSharedMemorySize, SMEM_BYTES);
    stage_kernel<0,0><<<NN, 1024, SMEM_BYTES, stream>>>(pair, single, single, mask, dist,
        nullptr, nullptr, rWqkv, rbqkv, rWo, rbo, rdsc, pnr_g, pnr_b, pr);
    colprefix_kernel<<<NN, 1024, 0, stream>>>(pr, s_in);
    stage_kernel<1,0><<<NN, 1024, SMEM_BYTES, stream>>>(pr, s_in, single, mask, dist,
        nullptr, nullptr, cWqkv, cbqkv, cWo, cbo, cdsc, pnc_g, pnc_b, pr);
  }
  single_kernel<<<NN, CC, 0, stream>>>(single, W1, b1, W2, b2, sn_g, sn_b, srr);
}

// Round 12
// 260.378 us; speedup vs baseline: 6.8342x; 1.0520x over previous
//
#include <hip/hip_runtime.h>
#include <math.h>

typedef unsigned int u32;
typedef unsigned short u16;
typedef __attribute__((ext_vector_type(8))) short short8;   // 8 bf16 in 4 VGPRs
typedef __attribute__((ext_vector_type(4))) float f32x4;
typedef __attribute__((ext_vector_type(2))) u32 u32x2;

#define NN 256
#define CC 128
#define EPSV 1e-5f
#define LOG2E 1.44269504088896f
#define QSCL (0.17677669529663687f * 1.44269504088896f)   // 1/sqrt(32) * log2(e)
#define NEGBIG -1e30f

#define MFMA(a,b,c) __builtin_amdgcn_mfma_f32_16x16x32_bf16(a,b,c,0,0,0)
#define EXP2(x) __builtin_amdgcn_exp2f(x)

__device__ __forceinline__ float b2f(u16 u){ return __uint_as_float(((u32)u)<<16); }
__device__ __forceinline__ u16 f2b(float f){
  u32 x = __float_as_uint(f);
  return (u16)((x + 0x7fffu + ((x>>16)&1u)) >> 16);
}
__device__ __forceinline__ void unpk(u32 u, float&a, float&b){
  a = __uint_as_float(u<<16); b = __uint_as_float(u & 0xffff0000u);
}
__device__ __forceinline__ u32 cvtpk(float lo, float hi){
  u32 r;
  asm("v_cvt_pk_bf16_f32 %0, %1, %2" : "=v"(r) : "v"(lo), "v"(hi));
  return r;
}
__device__ __forceinline__ void gload16(const void* g, void* l){
  __builtin_amdgcn_global_load_lds((const __attribute__((address_space(1))) u32*)g,
                                   (__attribute__((address_space(3))) u32*)l, 16, 0, 0);
}

// redistribute 8 values (2 f32x4 tiles, idx = tile*16 + l4*4 + v at col l15) into
// A/B-frag short8 (lane l4 gets idx l4*8..l4*8+7 for its l15). Verified P-path algebra.
__device__ __forceinline__ short8 redist(f32x4 t0, f32x4 t1, int l4){
  u32 A0 = cvtpk(t0[0], t0[1]), A1 = cvtpk(t0[2], t0[3]);
  u32 B0 = cvtpk(t1[0], t1[1]), B1 = cvtpk(t1[2], t1[3]);
  asm volatile("v_permlane32_swap_b32 %0, %1" : "+v"(A0), "+v"(B0));
  asm volatile("v_permlane32_swap_b32 %0, %1" : "+v"(A1), "+v"(B1));
  u32 sA0 = __shfl_xor(A0, 16), sA1 = __shfl_xor(A1, 16);
  u32 sB0 = __shfl_xor(B0, 16), sB1 = __shfl_xor(B1, 16);
  bool eg = ((l4 & 1) == 0);
  union { u32 u[4]; short8 s; } pu;
  pu.u[0] = eg ? A0 : sB0;
  pu.u[1] = eg ? A1 : sB1;
  pu.u[2] = eg ? sA0 : B0;
  pu.u[3] = eg ? sA1 : B1;
  return pu.s;
}

// ---- LDS layout (bytes) ----
#define XS_OFF   0        // bf16 X[256][128] swizzled                  (65536)
#define WT_OFF   65536    // bf16 Wt[96][128] head slice, swizzled      (24576)
#define WO_OFF   90112    // bf16 Woh dbuf [2][128][40]                 (20480)
#define KB_OFF   110592   // bf16 K[256][40]                            (20480)
#define VT_OFF   131072   // bf16 Vt[32][264]                           (16896)
#define SV_OFF   147968   // f32 sv[128]                                (512)
#define GB_OFF   148480   // f32 g[128], b[128], bo[128]                (1536)
#define BQ_OFF   150016   // f32 bqkv[384]                              (1536)
#define RS_OFF   151552   // f32 red[16][128] (phase-0 scratch)         (8192)
#define SMEM_BYTES 159744

#define XBYTE(r,c) ((r)*256 + (((((c)>>3)) ^ ((r)&7))<<4) + ((c)&7)*2)

// ws layout (bytes)
#define WS_B0   0          // bias img phase0 (131072)
#define WS_B1   131072     // bias img phase1 (131072)
#define WS_W0   262144     // W img stage0 (139264 = 4 heads x (24576 WT + 10240 WO))
#define WS_W1   401408     // W img stage1 (139264)
#define WS_SIN  540672     // s_in f32 (131072)
#define WS_NEED 671744

// bias image, per-lane-consumed layout: u16 addr = q*256 + l4*64 + ch*8 + kt*4 + v
__global__ void prep_bias(const int* __restrict__ mask, const float* __restrict__ dist,
                          const float* __restrict__ rd, const float* __restrict__ cd,
                          u16* __restrict__ b0, u16* __restrict__ b1){
  int q = blockIdx.x, k = threadIdx.x;
  int l4 = (k >> 2) & 3, v = k & 3, kt = (k >> 4) & 1, ch = k >> 5;
  int addr = q*256 + l4*64 + ch*8 + kt*4 + v;
  float dv = dist[q*NN + k];
  b0[addr] = mask[q*NN + k] ? f2b(NEGBIG) : f2b(rd[0]*LOG2E*dv);
  b1[addr] = mask[k*NN + q] ? f2b(NEGBIG) : f2b(cd[0]*LOG2E*dv);
}

// weight images: byte-exact copies of the LDS layouts (WT swizzled, WO padded)
__global__ void prep_wimg(const float* __restrict__ rWqkv, const float* __restrict__ rWo,
                          const float* __restrict__ cWqkv, const float* __restrict__ cWo,
                          u16* __restrict__ img0, u16* __restrict__ img1){
  int h = blockIdx.x & 3, s = blockIdx.x >> 2;
  const float* Wq = s ? cWqkv : rWqkv;
  const float* Wom = s ? cWo : rWo;
  char* base = (char*)(s ? img1 : img0) + h*34816;
  for (int e = threadIdx.x; e < 96*128; e += 256){
    int t = e >> 7, c = e & 127;
    int col = (t < 32) ? (h*32 + t) : (t < 64) ? (CC + h*32 + (t-32)) : (2*CC + h*32 + (t-64));
    *(u16*)(base + t*256 + ((((c>>3) ^ (t&7)))<<4) + (c&7)*2) = f2b(Wq[c*384 + col]);
  }
  for (int e = threadIdx.x; e < 128*40; e += 256){
    int o = e / 40, d = e - o*40;
    *(u16*)(base + 24576 + (o*40 + d)*2) = (d < 32) ? f2b(Wom[(h*32 + d)*128 + o]) : (u16)0;
  }
}

template<int PHASE, int WSOK>
__launch_bounds__(1024)
__global__ void stage_kernel(const float* __restrict__ pin, const float* __restrict__ colmat,
                             const float* __restrict__ singlerow,
                             const int* __restrict__ mask, const float* __restrict__ dist,
                             const u16* __restrict__ biasimg,
                             const u16* __restrict__ wimg,
                             const float* __restrict__ Wqkv, const float* __restrict__ bqkv,
                             const float* __restrict__ Wo, const float* __restrict__ bo,
                             const float* __restrict__ dscale,
                             const float* __restrict__ lng, const float* __restrict__ lnb,
                             float* __restrict__ outp)
{
  extern __shared__ char smem[];
  char* Xs  = smem + XS_OFF;
  char* WTs = smem + WT_OFF;
  char* WOs = smem + WO_OFF;
  char* KBs = smem + KB_OFF;
  char* VTs = smem + VT_OFF;
  float* SVs = (float*)(smem + SV_OFF);
  float* GBs = (float*)(smem + GB_OFF);
  float* BQs = (float*)(smem + BQ_OFF);
  float* RSs = (float*)(smem + RS_OFF);

  const int i = blockIdx.x;
  const int tid = threadIdx.x;
  const int lid = tid & 63;
  const int w = tid >> 6;            // 16 waves; wave owns query rows w*16..w*16+15
  const int l15 = lid & 15;
  const int l4  = lid >> 4;
  const int h32 = lid >> 5;
  const int c4  = (lid & 31) * 4;
  const float* prow = pin + (size_t)i*NN*CC;
  float* orow = outp + (size_t)i*NN*CC;
  const int qglob = w*16 + l15;
  const float dsc = dscale[0] * LOG2E;

  // issue W(head 0) staging immediately (lands during LN phase)
  if (WSOK){
    const char* wb = (const char*)wimg;
    gload16(wb + tid*16, WTs + tid*16);
    if (tid < 512) gload16(wb + 16384 + tid*16, WTs + 16384 + tid*16);
    if (tid < 640) gload16(wb + 24576 + tid*16, WOs + tid*16);
  }
  if (tid < 128){ GBs[tid] = lng[tid]; GBs[128+tid] = lnb[tid]; GBs[256+tid] = bo[tid]; }
  if (tid >= 512 && tid < 896) BQs[tid-512] = bqkv[tid-512];

  // ---- LN1 -> X (bf16 swizzled); phase 0 fuses the s_out prefix ----
  if (PHASE == 0){
    f32x4 svp = {0.f,0.f,0.f,0.f};
    #pragma unroll 4
    for (int p = 0; p < 8; ++p){
      int r = w*16 + p*2 + h32;
      f32x4 pr4 = *(const f32x4*)(prow + r*CC + c4);
      f32x4 sg4 = *(const f32x4*)(colmat + r*CC + c4);
      f32x4 t = pr4 + sg4;
      u32x2 pk2; pk2.x = cvtpk(t[0], t[1]); pk2.y = cvtpk(t[2], t[3]);
      *(u32x2*)(Xs + XBYTE(r, c4)) = pk2;
      if (r < i) svp += pr4;
    }
    #pragma unroll
    for (int q = 0; q < 4; ++q) svp[q] += __shfl_xor(svp[q], 32);
    if (h32 == 0) *(f32x4*)(RSs + w*128 + c4) = svp;
    __syncthreads();
    if (tid < 128){
      float s = 0.f;
      #pragma unroll
      for (int ww = 0; ww < 16; ++ww) s += RSs[ww*128 + tid];
      SVs[tid] = s;
    }
    __syncthreads();
    f32x4 sv4 = *(const f32x4*)(SVs + c4);
    f32x4 g4  = *(const f32x4*)(GBs + c4);
    f32x4 b4  = *(const f32x4*)(GBs + 128 + c4);
    #pragma unroll 2
    for (int p = 0; p < 8; ++p){
      int r = w*16 + p*2 + h32;
      u32x2 st = *(const u32x2*)(Xs + XBYTE(r, c4));
      float t0,t1,t2,t3;
      unpk(st.x, t0, t1); unpk(st.y, t2, t3);
      t0 += sv4[0]; t1 += sv4[1]; t2 += sv4[2]; t3 += sv4[3];
      float s = (t0+t1)+(t2+t3);
      float q2 = (t0*t0+t1*t1)+(t2*t2+t3*t3);
      #pragma unroll
      for (int ms = 1; ms < 32; ms <<= 1){ s += __shfl_xor(s, ms); q2 += __shfl_xor(q2, ms); }
      float mean = s*(1.f/CC);
      float var  = fmaxf(q2*(1.f/CC) - mean*mean, 0.f);
      float rstd = rsqrtf(var + EPSV);
      float y0 = (t0-mean)*rstd*g4[0] + b4[0];
      float y1 = (t1-mean)*rstd*g4[1] + b4[1];
      float y2 = (t2-mean)*rstd*g4[2] + b4[2];
      float y3 = (t3-mean)*rstd*g4[3] + b4[3];
      u32x2 pk2; pk2.x = cvtpk(y0, y1); pk2.y = cvtpk(y2, y3);
      *(u32x2*)(Xs + XBYTE(r, c4)) = pk2;
    }
  } else {
    if (tid < 128) SVs[tid] = singlerow[i*CC + tid];
    __syncthreads();
    f32x4 sv4 = *(const f32x4*)(SVs + c4);
    f32x4 g4  = *(const f32x4*)(GBs + c4);
    f32x4 b4  = *(const f32x4*)(GBs + 128 + c4);
    #pragma unroll 4
    for (int p = 0; p < 8; ++p){
      int r = w*16 + p*2 + h32;
      f32x4 pr4 = *(const f32x4*)(prow + r*CC + c4);
      f32x4 cm4 = *(const f32x4*)(colmat + r*CC + c4);
      float t0 = pr4[0]+cm4[0]+sv4[0], t1 = pr4[1]+cm4[1]+sv4[1];
      float t2 = pr4[2]+cm4[2]+sv4[2], t3 = pr4[3]+cm4[3]+sv4[3];
      float s = (t0+t1)+(t2+t3);
      float q2 = (t0*t0+t1*t1)+(t2*t2+t3*t3);
      #pragma unroll
      for (int ms = 1; ms < 32; ms <<= 1){ s += __shfl_xor(s, ms); q2 += __shfl_xor(q2, ms); }
      float mean = s*(1.f/CC);
      float var  = fmaxf(q2*(1.f/CC) - mean*mean, 0.f);
      float rstd = rsqrtf(var + EPSV);
      float y0 = (t0-mean)*rstd*g4[0] + b4[0];
      float y1 = (t1-mean)*rstd*g4[1] + b4[1];
      float y2 = (t2-mean)*rstd*g4[2] + b4[2];
      float y3 = (t3-mean)*rstd*g4[3] + b4[3];
      u32x2 pk2; pk2.x = cvtpk(y0, y1); pk2.y = cvtpk(y2, y3);
      *(u32x2*)(Xs + XBYTE(r, c4)) = pk2;
    }
  }
  if (WSOK) asm volatile("s_waitcnt vmcnt(0)" ::: "memory");
  __syncthreads();   // X ready; W(0) staged

  f32x4 pa[8];
  #pragma unroll
  for (int ct = 0; ct < 8; ++ct) pa[ct] = f32x4{0.f,0.f,0.f,0.f};

  for (int h = 0; h < 4; ++h){
    if (!WSOK){
      #pragma unroll
      for (int it = 0; it < 12; ++it){
        int e = tid + it*1024;
        int c = e & 127, t = e >> 7;
        int col = (t < 32) ? (h*32 + t) : (t < 64) ? (CC + h*32 + (t-32)) : (2*CC + h*32 + (t-64));
        *(u16*)(WTs + t*256 + ((((c>>3) ^ (t&7)))<<4) + (c&7)*2) = f2b(Wqkv[c*384 + col]);
      }
      #pragma unroll
      for (int it = 0; it < 4; ++it){
        int e = tid + it*1024;
        int d = e >> 7, o = e & 127;
        *(u16*)(WOs + (h&1)*10240 + (o*40 + d)*2) = (d < 32) ? f2b(Wo[(h*32 + d)*128 + o]) : (u16)0;
      }
      __syncthreads();
    }

    // ---- QKV GEMM: Q^T and V^T via W-as-A (swapped); K direct ----
    f32x4 qa[2], ka[2], va[2];
    #pragma unroll
    for (int dt = 0; dt < 2; ++dt)
      #pragma unroll
      for (int v = 0; v < 4; ++v){
        qa[dt][v] = BQs[h*32 + dt*16 + l4*4 + v];
        va[dt][v] = BQs[256 + h*32 + dt*16 + l4*4 + v];
      }
    {
      float bk0 = BQs[128 + h*32 + l15], bk1 = BQs[128 + h*32 + 16 + l15];
      ka[0] = f32x4{bk0,bk0,bk0,bk0}; ka[1] = f32x4{bk1,bk1,bk1,bk1};
    }
    #pragma unroll
    for (int ks = 0; ks < 4; ++ks){
      int swb = (((ks*4 + l4) ^ (l15 & 7)) << 4);
      short8 a0  = *(const short8*)(Xs  + (w*16 + l15)*256 + swb);
      short8 wq0 = *(const short8*)(WTs + (l15)*256 + swb);
      short8 wq1 = *(const short8*)(WTs + (16 + l15)*256 + swb);
      short8 wk0 = *(const short8*)(WTs + (32 + l15)*256 + swb);
      short8 wk1 = *(const short8*)(WTs + (48 + l15)*256 + swb);
      short8 wv0 = *(const short8*)(WTs + (64 + l15)*256 + swb);
      short8 wv1 = *(const short8*)(WTs + (80 + l15)*256 + swb);
      qa[0] = MFMA(wq0, a0, qa[0]); qa[1] = MFMA(wq1, a0, qa[1]);
      ka[0] = MFMA(a0, wk0, ka[0]); ka[1] = MFMA(a0, wk1, ka[1]);
      va[0] = MFMA(wv0, a0, va[0]); va[1] = MFMA(wv1, a0, va[1]);
    }
    short8 qf = redist(qa[0]*QSCL, qa[1]*QSCL, l4);
    #pragma unroll
    for (int kt = 0; kt < 2; ++kt)
      #pragma unroll
      for (int v = 0; v < 4; ++v)
        *(u16*)(KBs + ((w*16 + l4*4 + v)*40 + kt*16 + l15)*2) = (u16)cvtpk(ka[kt][v], ka[kt][v]);
    #pragma unroll
    for (int dt = 0; dt < 2; ++dt)
      #pragma unroll
      for (int v = 0; v < 4; ++v)
        *(u16*)(VTs + ((dt*16 + l4*4 + v)*264 + w*16 + l15)*2) = (u16)cvtpk(va[dt][v], va[dt][v]);
    __syncthreads();   // K/VT visible; all WT reads done

    if (WSOK && h < 3){  // prefetch next head's weights under the flash phase
      const char* wb = (const char*)wimg + (h+1)*34816;
      gload16(wb + tid*16, WTs + tid*16);
      if (tid < 512) gload16(wb + 16384 + tid*16, WTs + 16384 + tid*16);
      if (tid < 640) gload16(wb + 24576 + tid*16, WOs + ((h+1)&1)*10240 + tid*16);
    }

    __builtin_amdgcn_s_setprio(1);
    // ---- attention: full-row softmax in 2 halves of 128 keys ----
    float m = -3e38f, l = 0.f;
    f32x4 oacc0 = {0.f,0.f,0.f,0.f}, oacc1 = {0.f,0.f,0.f,0.f};
    #pragma unroll
    for (int hl = 0; hl < 2; ++hl){
      f32x4 sS[4][2];
      if (WSOK){
        // bias rides in as the MFMA C-operand (identical math, no post-add)
        const u16* bb = biasimg + qglob*256 + l4*64 + hl*32;
        #pragma unroll
        for (int ci = 0; ci < 4; ++ci){
          uint4 bw = *(const uint4*)(bb + ci*8);
          float c00,c01,c02,c03,c10,c11,c12,c13;
          unpk(bw.x, c00, c01); unpk(bw.y, c02, c03);
          unpk(bw.z, c10, c11); unpk(bw.w, c12, c13);
          f32x4 cb0 = {c00, c01, c02, c03};
          f32x4 cb1 = {c10, c11, c12, c13};
          int ch = hl*4 + ci;
          short8 kf0 = *(const short8*)(KBs + (ch*32 + l15)*80 + l4*16);
          short8 kf1 = *(const short8*)(KBs + (ch*32 + 16 + l15)*80 + l4*16);
          sS[ci][0] = MFMA(kf0, qf, cb0);
          sS[ci][1] = MFMA(kf1, qf, cb1);
        }
      } else {
        #pragma unroll
        for (int ci = 0; ci < 4; ++ci){
          int ch = hl*4 + ci;
          short8 kf0 = *(const short8*)(KBs + (ch*32 + l15)*80 + l4*16);
          short8 kf1 = *(const short8*)(KBs + (ch*32 + 16 + l15)*80 + l4*16);
          f32x4 z = {0.f,0.f,0.f,0.f};
          sS[ci][0] = MFMA(kf0, qf, z);
          sS[ci][1] = MFMA(kf1, qf, z);
        }
        #pragma unroll
        for (int ci = 0; ci < 4; ++ci)
          #pragma unroll
          for (int kt = 0; kt < 2; ++kt)
            #pragma unroll
            for (int v = 0; v < 4; ++v){
              int key = (hl*4 + ci)*32 + kt*16 + l4*4 + v;
              int mq = (PHASE==0) ? mask[qglob*NN + key] : mask[key*NN + qglob];
              sS[ci][kt][v] += mq ? NEGBIG : dsc*dist[qglob*NN + key];
            }
      }
      float mc0 = fmaxf(fmaxf(fmaxf(sS[0][0][0],sS[0][0][1]),fmaxf(sS[0][0][2],sS[0][0][3])),
                        fmaxf(fmaxf(sS[0][1][0],sS[0][1][1]),fmaxf(sS[0][1][2],sS[0][1][3])));
      float mc1 = fmaxf(fmaxf(fmaxf(sS[1][0][0],sS[1][0][1]),fmaxf(sS[1][0][2],sS[1][0][3])),
                        fmaxf(fmaxf(sS[1][1][0],sS[1][1][1]),fmaxf(sS[1][1][2],sS[1][1][3])));
      float mc2 = fmaxf(fmaxf(fmaxf(sS[2][0][0],sS[2][0][1]),fmaxf(sS[2][0][2],sS[2][0][3])),
                        fmaxf(fmaxf(sS[2][1][0],sS[2][1][1]),fmaxf(sS[2][1][2],sS[2][1][3])));
      float mc3 = fmaxf(fmaxf(fmaxf(sS[3][0][0],sS[3][0][1]),fmaxf(sS[3][0][2],sS[3][0][3])),
                        fmaxf(fmaxf(sS[3][1][0],sS[3][1][1]),fmaxf(sS[3][1][2],sS[3][1][3])));
      float mx = fmaxf(fmaxf(mc0,mc1), fmaxf(mc2,mc3));
      mx = fmaxf(mx, __shfl_xor(mx, 16));
      mx = fmaxf(mx, __shfl_xor(mx, 32));
      float mn = fmaxf(m, mx);
      float corr = EXP2(m - mn);
      m = mn;
      float ps = 0.f;
      #pragma unroll
      for (int ci = 0; ci < 4; ++ci){
        float p0=0.f, p1=0.f;
        #pragma unroll
        for (int v = 0; v < 4; ++v){
          sS[ci][0][v] = EXP2(sS[ci][0][v] - m); p0 += sS[ci][0][v];
          sS[ci][1][v] = EXP2(sS[ci][1][v] - m); p1 += sS[ci][1][v];
        }
        ps += p0 + p1;
      }
      ps += __shfl_xor(ps, 16);
      ps += __shfl_xor(ps, 32);
      l = l*corr + ps;
      oacc0 *= corr; oacc1 *= corr;
      #pragma unroll
      for (int ci = 0; ci < 4; ++ci){
        int ch = hl*4 + ci;
        short8 pf = redist(sS[ci][0], sS[ci][1], l4);
        short8 vt0 = *(const short8*)(VTs + (l15)*528 + ch*64 + l4*16);
        short8 vt1 = *(const short8*)(VTs + (16 + l15)*528 + ch*64 + l4*16);
        oacc0 = MFMA(vt0, pf, oacc0);
        oacc1 = MFMA(vt1, pf, oacc1);
      }
    }
    // ---- O normalize + in-reg redistribute + fuse O_h @ Wo_h ----
    {
      float inv = 1.f / l;
      short8 oA = redist(oacc0*inv, oacc1*inv, l4);
      const char* wob = WOs + (h&1)*10240;
      #pragma unroll
      for (int ct = 0; ct < 8; ++ct){
        short8 wB = *(const short8*)(wob + (ct*16 + l15)*80 + l4*16);
        pa[ct] = MFMA(oA, wB, pa[ct]);
      }
    }
    __builtin_amdgcn_s_setprio(0);
    if (WSOK && h < 3) asm volatile("s_waitcnt vmcnt(0)" ::: "memory");
    __syncthreads();   // flash reads of K/VT done; W(h+1) landed in all waves
  }

  // ---- epilogue: residual + bo + LN2 + plain coalesced write ----
  float mrs[4], mrq[4];
  #pragma unroll
  for (int v = 0; v < 4; ++v){ mrs[v] = 0.f; mrq[v] = 0.f; }
  #pragma unroll
  for (int ct = 0; ct < 8; ++ct)
    #pragma unroll
    for (int v = 0; v < 4; ++v){
      int o = ct*16 + l15;
      int r = w*16 + l4*4 + v;
      float xv = b2f(*(const u16*)(Xs + XBYTE(r, o)));
      float t = pa[ct][v] + GBs[256 + o] + xv;
      pa[ct][v] = t;
      mrs[v] += t; mrq[v] += t*t;
    }
  #pragma unroll
  for (int v = 0; v < 4; ++v){
    #pragma unroll
    for (int ms = 1; ms < 16; ms <<= 1){
      mrs[v] += __shfl_xor(mrs[v], ms);
      mrq[v] += __shfl_xor(mrq[v], ms);
    }
    float mean = mrs[v]*(1.f/CC);
    float var  = fmaxf(mrq[v]*(1.f/CC) - mean*mean, 0.f);
    mrs[v] = mean;
    mrq[v] = rsqrtf(var + EPSV);
  }
  #pragma unroll
  for (int ct = 0; ct < 8; ++ct)
    #pragma unroll
    for (int v = 0; v < 4; ++v){
      int o = ct*16 + l15;
      int r = w*16 + l4*4 + v;
      orow[r*CC + o] = (pa[ct][v] - mrs[v])*mrq[v]*GBs[o] + GBs[128+o];
    }
}

// s_in[j][c] = sum_{k<j} pr[k][j][c]
__launch_bounds__(1024)
__global__ void colprefix_kernel(const float* __restrict__ pr, float* __restrict__ s_in){
  __shared__ float red[1024];
  int j = blockIdx.x;
  int c = threadIdx.x & 127, part = threadIdx.x >> 7;
  float a0 = 0.f, a1 = 0.f;
  for (int k = part; k < j; k += 16){
    a0 += pr[(size_t)k*NN*CC + j*CC + c];
    int k2 = k + 8;
    if (k2 < j) a1 += pr[(size_t)k2*NN*CC + j*CC + c];
  }
  red[threadIdx.x] = a0 + a1;
  __syncthreads();
  if (threadIdx.x < 128){
    float s = 0.f;
    #pragma unroll
    for (int p = 0; p < 8; ++p) s += red[p*128 + threadIdx.x];
    s_in[j*CC + threadIdx.x] = s;
  }
}

__launch_bounds__(128)
__global__ void single_kernel(const float* __restrict__ single,
                              const float* __restrict__ W1, const float* __restrict__ b1,
                              const float* __restrict__ W2, const float* __restrict__ b2,
                              const float* __restrict__ g, const float* __restrict__ bb,
                              float* __restrict__ sr){
  __shared__ float srow[128];
  __shared__ float sh1[256];
  __shared__ float red[4];
  int jr = blockIdx.x, t = threadIdx.x;
  srow[t] = single[jr*CC + t];
  __syncthreads();
  float a0 = b1[t], a1 = b1[t+128];
  for (int c = 0; c < 128; ++c){
    float s = srow[c];
    a0 += s * W1[c*256 + t];
    a1 += s * W1[c*256 + t + 128];
  }
  sh1[t] = fmaxf(a0, 0.f);
  sh1[t+128] = fmaxf(a1, 0.f);
  __syncthreads();
  float acc = b2[t];
  for (int o = 0; o < 256; ++o) acc += sh1[o] * W2[o*CC + t];
  acc = fmaxf(acc, 0.f);
  float tv = srow[t] + acc;
  float s = tv, q = tv*tv;
  #pragma unroll
  for (int mm = 32; mm; mm >>= 1){ s += __shfl_xor(s, mm); q += __shfl_xor(q, mm); }
  int w = t >> 6;
  if ((t & 63) == 0){ red[w] = s; red[2+w] = q; }
  __syncthreads();
  float S = red[0] + red[1], Q = red[2] + red[3];
  float mean = S*(1.f/CC);
  float var = fmaxf(Q*(1.f/CC) - mean*mean, 0.f);
  float rs = rsqrtf(var + EPSV);
  sr[jr*CC + t] = (tv - mean)*rs*g[t] + bb[t];
}

extern "C" void kernel_launch(void* const* d_in, const int* in_sizes, int n_in,
                              void* d_out, int out_size, void* d_ws, size_t ws_size,
                              hipStream_t stream) {
  const float* pair   = (const float*)d_in[0];
  const float* single = (const float*)d_in[1];
  const int*   mask   = (const int*)d_in[2];
  const float* dist   = (const float*)d_in[3];
  const float* rWqkv  = (const float*)d_in[4];
  const float* rbqkv  = (const float*)d_in[5];
  const float* rWo    = (const float*)d_in[6];
  const float* rbo    = (const float*)d_in[7];
  const float* rdsc   = (const float*)d_in[8];
  const float* cWqkv  = (const float*)d_in[9];
  const float* cbqkv  = (const float*)d_in[10];
  const float* cWo    = (const float*)d_in[11];
  const float* cbo    = (const float*)d_in[12];
  const float* cdsc   = (const float*)d_in[13];
  const float* pnr_g  = (const float*)d_in[14];
  const float* pnr_b  = (const float*)d_in[15];
  const float* pnc_g  = (const float*)d_in[16];
  const float* pnc_b  = (const float*)d_in[17];
  const float* sn_g   = (const float*)d_in[18];
  const float* sn_b   = (const float*)d_in[19];
  const float* W1     = (const float*)d_in[20];
  const float* b1     = (const float*)d_in[21];
  const float* W2     = (const float*)d_in[22];
  const float* b2     = (const float*)d_in[23];

  float* outp = (float*)d_out;
  float* pr   = outp;
  float* srr  = outp + (size_t)NN*NN*CC;

  const bool usews = ws_size >= (size_t)WS_NEED;
  char* wsb = (char*)d_ws;
  u16* bias0 = (u16*)(wsb + WS_B0);
  u16* bias1 = (u16*)(wsb + WS_B1);
  u16* wimg0 = (u16*)(wsb + WS_W0);
  u16* wimg1 = (u16*)(wsb + WS_W1);
  float* s_in = usews ? (float*)(wsb + WS_SIN) : srr;

  if (usews){
    (void)hipFuncSetAttribute(reinterpret_cast<const void*>(stage_kernel<0,1>),
                              hipFuncAttributeMaxDynamicSharedMemorySize, SMEM_BYTES);
    (void)hipFuncSetAttribute(reinterpret_cast<const void*>(stage_kernel<1,1>),
                              hipFuncAttributeMaxDynamicSharedMemorySize, SMEM_BYTES);
    single_kernel<<<NN, CC, 0, stream>>>(single, W1, b1, W2, b2, sn_g, sn_b, srr);
    prep_bias<<<NN, NN, 0, stream>>>(mask, dist, rdsc, cdsc, bias0, bias1);
    prep_wimg<<<8, 256, 0, stream>>>(rWqkv, rWo, cWqkv, cWo, wimg0, wimg1);
    stage_kernel<0,1><<<NN, 1024, SMEM_BYTES, stream>>>(pair, single, single, mask, dist,
        bias0, wimg0, rWqkv, rbqkv, rWo, rbo, rdsc, pnr_g, pnr_b, pr);
    colprefix_kernel<<<NN, 1024, 0, stream>>>(pr, s_in);
    stage_kernel<1,1><<<NN, 1024, SMEM_BYTES, stream>>>(pr, s_in, single, mask, dist,
        bias1, wimg1, cWqkv, cbqkv, cWo, cbo, cdsc, pnc_g, pnc_b, pr);
  } else {
    (void)hipFuncSetAttribute(reinterpret_cast<const void*>(stage_kernel<0,0>),
                              hipFuncAttributeMaxDynamicSharedMemorySize, SMEM_BYTES);
    (void)hipFuncSetAttribute(reinterpret_cast<const void*>(stage_kernel<1,0>),
                              hipFuncAttributeMaxDynamicSharedMemorySize, SMEM_BYTES);
    stage_kernel<0,0><<<NN, 1024, SMEM_BYTES, stream>>>(pair, single, single, mask, dist,
        nullptr, nullptr, rWqkv, rbqkv, rWo, rbo, rdsc, pnr_g, pnr_b, pr);
    colprefix_kernel<<<NN, 1024, 0, stream>>>(pr, s_in);
    stage_kernel<1,0><<<NN, 1024, SMEM_BYTES, stream>>>(pr, s_in, single, mask, dist,
        nullptr, nullptr, cWqkv, cbqkv, cWo, cbo, cdsc, pnc_g, pnc_b, pr);
    single_kernel<<<NN, CC, 0, stream>>>(single, W1, b1, W2, b2, sn_g, sn_b, srr);
  }
}